// Round 4
// baseline (1635.934 us; speedup 1.0000x reference)
//
#include <hip/hip_runtime.h>
#include <hip/hip_bf16.h>
#include <stdint.h>

#define N_NODES 6144
#define FDIM    128
#define EEDGES  16384
#define KTOP    32
#define KSEL    48
#define MAXNBR  64

typedef short bf16x8 __attribute__((ext_vector_type(8)));
typedef float f32x4  __attribute__((ext_vector_type(4)));

__device__ __forceinline__ float elu_f(float x){ return x > 0.f ? x : expm1f(x); }

__device__ __forceinline__ unsigned short f2bf(float f){
  unsigned int u = __float_as_uint(f);
  u += 0x7FFFu + ((u >> 16) & 1u);   // RNE
  return (unsigned short)(u >> 16);
}

// ---------------------------------------------------------------- adj scan
// adj is binary (0/1). Extract per-row neighbor lists + row/col counts.
__global__ __launch_bounds__(256) void adj_scan(const float* __restrict__ adj,
    int* __restrict__ nbr, int* __restrict__ nbrcnt, int* __restrict__ colcnt){
  const int i = blockIdx.x, t = threadIdx.x;
  __shared__ int s_cnt;
  if (t == 0) s_cnt = 0;
  __syncthreads();
  const float4* row = (const float4*)(adj + (size_t)i * N_NODES);
  for (int v = t; v < N_NODES/4; v += 256){
    float4 f = row[v];
    int b = v * 4;
    if (f.x != 0.f){ int s = atomicAdd(&s_cnt,1); if (s < MAXNBR) nbr[i*MAXNBR+s] = b;   atomicAdd(&colcnt[b],1); }
    if (f.y != 0.f){ int s = atomicAdd(&s_cnt,1); if (s < MAXNBR) nbr[i*MAXNBR+s] = b+1; atomicAdd(&colcnt[b+1],1); }
    if (f.z != 0.f){ int s = atomicAdd(&s_cnt,1); if (s < MAXNBR) nbr[i*MAXNBR+s] = b+2; atomicAdd(&colcnt[b+2],1); }
    if (f.w != 0.f){ int s = atomicAdd(&s_cnt,1); if (s < MAXNBR) nbr[i*MAXNBR+s] = b+3; atomicAdd(&colcnt[b+3],1); }
  }
  __syncthreads();
  if (t == 0) nbrcnt[i] = min(s_cnt, MAXNBR);
}

// ---------------------------------------------------------------- x prep: bf16 copy + 1/||x_i||
__global__ __launch_bounds__(128) void xprep(const float* __restrict__ x,
    unsigned short* __restrict__ xbf, float* __restrict__ xninv){
  const int i = blockIdx.x, t = threadIdx.x;
  float v = x[(size_t)i*FDIM + t];
  xbf[(size_t)i*FDIM + t] = f2bf(v);
  float s = v * v;
  for (int o = 32; o > 0; o >>= 1) s += __shfl_down(s, o, 64);
  __shared__ float ws[2];
  if ((t & 63) == 0) ws[t >> 6] = s;
  __syncthreads();
  if (t == 0) xninv[i] = rsqrtf(ws[0] + ws[1]);
}

__global__ __launch_bounds__(256) void node_norms(const int* __restrict__ nbrcnt,
    const int* __restrict__ colcnt, float* __restrict__ d1inv, float* __restrict__ d2inv){
  int i = blockIdx.x*256 + threadIdx.x;
  if (i < N_NODES){
    d1inv[i] = rsqrtf((float)(nbrcnt[i] + 1));
    d2inv[i] = rsqrtf((float)(colcnt[i] + 1));
  }
}

// ---------------------------------------------------------------- bf16 cosine-sim CANDIDATE FILTER: per-row top-48
// 32 rows/block, col tiles of 64, bf16 MFMA 16x16x32, threshold top-k in LDS.
__global__ __launch_bounds__(256) void simtopk(const unsigned short* __restrict__ xbf,
    const float* __restrict__ xninv, int* __restrict__ tidx48){
  const int t    = threadIdx.x;
  const int R0   = blockIdx.x * 32;
  const int lane = t & 63, w = t >> 6;
  const int lr   = lane & 15, q8 = (lane >> 4) * 8;

  __shared__ unsigned short Abf[32][136];   // +8 pad keeps b128 reads 2-way max
  __shared__ unsigned short Bbf[64][136];
  __shared__ float Stile[32][68];
  __shared__ float tv[32][KSEL];
  __shared__ int   ti[32][KSEL];
  __shared__ float thrmin[32];
  __shared__ float nrow[32];
  __shared__ float ncol[64];
  __shared__ unsigned char cand[32][64];
  __shared__ int ccnt[32];

  for (int e = t; e < 32*16; e += 256){      // A rows as uint4 (8 bf16)
    int r = e >> 4, c8 = e & 15;
    *(uint4*)&Abf[r][c8*8] = ((const uint4*)(xbf + (size_t)(R0 + r)*FDIM))[c8];
  }
  if (t < 32){ nrow[t] = xninv[R0 + t]; thrmin[t] = -3.4e38f; }
  for (int e = t; e < 32*KSEL; e += 256){ tv[e/KSEL][e%KSEL] = -3.4e38f; ti[e/KSEL][e%KSEL] = 0; }

  for (int tb = 0; tb < N_NODES/64; ++tb){
    __syncthreads();                          // prev leader done; init visible
    for (int e = t; e < 64*16; e += 256){
      int r = e >> 4, c8 = e & 15;
      *(uint4*)&Bbf[r][c8*8] = ((const uint4*)(xbf + (size_t)(tb*64 + r)*FDIM))[c8];
    }
    if (t < 64) ncol[t] = xninv[tb*64 + t];
    if (t < 32) ccnt[t] = 0;
    __syncthreads();

    // wave w owns cols [w*16, w*16+16); acc[0]=rows 0-15, acc[1]=rows 16-31
    f32x4 acc[2] = {};
#pragma unroll
    for (int kb = 0; kb < 4; ++kb){
      bf16x8 a0 = *(const bf16x8*)&Abf[lr     ][kb*32 + q8];
      bf16x8 a1 = *(const bf16x8*)&Abf[16 + lr][kb*32 + q8];
      bf16x8 b0 = *(const bf16x8*)&Bbf[w*16 + lr][kb*32 + q8];
      acc[0] = __builtin_amdgcn_mfma_f32_16x16x32_bf16(a0, b0, acc[0], 0, 0, 0);
      acc[1] = __builtin_amdgcn_mfma_f32_16x16x32_bf16(a1, b0, acc[1], 0, 0, 0);
    }
    {
      int col  = w*16 + lr;                   // m89 C/D layout: col=lane&15
      int gcol = tb*64 + col;
      float nc = ncol[col];
#pragma unroll
      for (int rf = 0; rf < 2; ++rf)
#pragma unroll
        for (int rg = 0; rg < 4; ++rg){
          int rrow = rf*16 + (lane >> 4)*4 + rg;   // row=(lane>>4)*4+reg
          float v = acc[rf][rg] * nrow[rrow] * nc;
          if (R0 + rrow == gcol) v = -3.4e38f;     // mask diagonal
          Stile[rrow][col] = v;
        }
    }
    __syncthreads();

    { // scan: 8 threads/row, 8 cols each, push candidates above threshold
      int r = t >> 3, c0 = (t & 7) * 8;
      float thr = thrmin[r];
      for (int k = 0; k < 8; ++k){
        float v = Stile[r][c0 + k];
        if (v > thr){ int s = atomicAdd(&ccnt[r], 1); cand[r][s] = (unsigned char)(c0 + k); }
      }
    }
    __syncthreads();

    if (t < 32){ // leader: serialized insertion into per-row top-KSEL list
      int r = t, cnt = ccnt[r];
      if (cnt > 0){
        float m = tv[r][0]; int am = 0;
        for (int q = 1; q < KSEL; ++q){ float u = tv[r][q]; if (u < m){ m = u; am = q; } }
        for (int s = 0; s < cnt; ++s){
          int c = cand[r][s];
          float v = Stile[r][c];
          if (v > m){
            tv[r][am] = v; ti[r][am] = tb*64 + c;
            m = tv[r][0]; am = 0;
            for (int q = 1; q < KSEL; ++q){ float u = tv[r][q]; if (u < m){ m = u; am = q; } }
          }
        }
        thrmin[r] = m;
      }
    }
  }
  __syncthreads();
  for (int e = t; e < 32*KSEL; e += 256)
    tidx48[(size_t)(R0 + e/KSEL)*KSEL + (e%KSEL)] = ti[e/KSEL][e%KSEL];
}

// ---------------------------------------------------------------- fp32 exact top-32 among 48 candidates
// One block (192 thr) per row; 4 lanes per candidate dot, then rank-select.
__global__ __launch_bounds__(192) void refine48(const float* __restrict__ x,
    const float* __restrict__ xninv, const int* __restrict__ tidx48,
    float* __restrict__ tval, int* __restrict__ tidx, float* __restrict__ deginv){
  const int i = blockIdx.x, t = threadIdx.x;
  __shared__ float xi[128];
  __shared__ float cv[KSEL];
  __shared__ int   ci[KSEL];
  __shared__ float sel[KTOP];
  if (t < 32) *(float4*)&xi[t*4] = *(const float4*)(x + (size_t)i*FDIM + t*4);
  if (t < KSEL) ci[t] = tidx48[(size_t)i*KSEL + t];
  __syncthreads();
  const int k = t >> 2, part = t & 3;
  const int c = ci[k];
  const float* xc = x + (size_t)c*FDIM + part*32;
  float acc = 0.f;
#pragma unroll
  for (int q = 0; q < 8; ++q){
    float4 f = *(const float4*)(xc + q*4);
    const float* a = &xi[part*32 + q*4];
    acc += a[0]*f.x + a[1]*f.y + a[2]*f.z + a[3]*f.w;
  }
  acc += __shfl_xor(acc, 1, 64);
  acc += __shfl_xor(acc, 2, 64);
  if (part == 0) cv[k] = acc * xninv[i] * xninv[c];
  __syncthreads();
  if (t < KSEL){
    float v = cv[t]; int c0 = ci[t];
    int rank = 0;
    for (int j = 0; j < KSEL; ++j){
      float u = cv[j];
      if (u > v || (u == v && ci[j] < c0)) rank++;   // top_k tie-break: lower index first
    }
    if (rank < KTOP){
      tval[(size_t)i*KTOP + rank] = v;
      tidx[(size_t)i*KTOP + rank] = c0;
      sel[rank] = v;
    }
  }
  __syncthreads();
  if (t == 0){
    float s = 0.f;
    for (int q = 0; q < KTOP; ++q) s += sel[q];
    deginv[i] = 1.0f / fmaxf(s, 1e-5f);   // clip(deg, 1e-5)
  }
}

// ---------------------------------------------------------------- fp32 GEMM  C[N x M] = act(A@B + bias)
template<int M>
__global__ __launch_bounds__(256) void gemm_k(const float* __restrict__ A, int lda,
    const float* __restrict__ B, const float* __restrict__ bias,
    float* __restrict__ C, int ldc, int K, int act){
  constexpr int CW = M / 16;
  const int t = threadIdx.x;
  const int R0 = blockIdx.x * 32;
  const int rg = t >> 4, cg = t & 15;
  __shared__ float Alds[32][34];     // [k][r] transposed
  __shared__ float Blds[32][M + 4];
  float acc0[CW] = {}, acc1[CW] = {};
  for (int kc = 0; kc < K; kc += 32){
    __syncthreads();
    { int r = t >> 3, k0 = (t & 7) * 4;
      float4 f = *(const float4*)(A + (size_t)(R0 + r)*lda + kc + k0);
      Alds[k0+0][r] = f.x; Alds[k0+1][r] = f.y; Alds[k0+2][r] = f.z; Alds[k0+3][r] = f.w; }
    for (int e = t; e < 32*M/4; e += 256){
      int k = e / (M/4), m4 = e % (M/4);
      *(float4*)&Blds[k][m4*4] = *(const float4*)(B + (size_t)(kc + k)*M + m4*4);
    }
    __syncthreads();
    for (int k = 0; k < 32; ++k){
      float a0 = Alds[k][rg*2], a1 = Alds[k][rg*2 + 1];
#pragma unroll
      for (int j = 0; j < CW; ++j){
        float b = Blds[k][cg*CW + j];
        acc0[j] += a0 * b; acc1[j] += a1 * b;
      }
    }
  }
  const int r0 = R0 + rg*2;
#pragma unroll
  for (int j = 0; j < CW; ++j){
    int c = cg*CW + j;
    float v0 = acc0[j], v1 = acc1[j];
    if (bias){ float bb = bias[c]; v0 += bb; v1 += bb; }
    if (act){ v0 = elu_f(v0); v1 = elu_f(v1); }
    C[(size_t)r0*ldc + c] = v0;
    C[(size_t)(r0+1)*ldc + c] = v1;
  }
}

// ---------------------------------------------------------------- GCN SpMM: y = elu(d1inv_i*(Ts_i + sum_nbr Ts_j)), Ts_j = T_j*d2inv_j
__global__ __launch_bounds__(128) void spmm_gcn(const float* __restrict__ T,
    const int* __restrict__ nbr, const int* __restrict__ nbrcnt,
    const float* __restrict__ d1inv, const float* __restrict__ d2inv,
    float* __restrict__ C, int ldc){
  const int i = blockIdx.x, t = threadIdx.x;
  float acc = T[(size_t)i*FDIM + t] * d2inv[i];     // +I diagonal term
  const int cnt = nbrcnt[i];
  const int* nb = nbr + (size_t)i*MAXNBR;
  for (int s = 0; s < cnt; ++s){
    int j = nb[s];
    acc += T[(size_t)j*FDIM + t] * d2inv[j];
  }
  C[(size_t)i*ldc + t] = elu_f(acc * d1inv[i]);
}

// ---------------------------------------------------------------- SAGE SpMM: y = deginv_i * sum_k val_k * P[idx_k]
__global__ __launch_bounds__(128) void spmm_sage(const float* __restrict__ P,
    const float* __restrict__ tval, const int* __restrict__ tidx,
    const float* __restrict__ deginv, float* __restrict__ C, int ldc){
  const int i = blockIdx.x, t = threadIdx.x;
  float acc = 0.f;
  const float* vv = tval + (size_t)i*KTOP;
  const int*   ii = tidx + (size_t)i*KTOP;
  for (int s = 0; s < KTOP; ++s)
    acc += vv[s] * P[(size_t)ii[s]*FDIM + t];
  C[(size_t)i*ldc + t] = acc * deginv[i];
}

__global__ __launch_bounds__(128) void copy128(const float* __restrict__ X,
    float* __restrict__ C, int ldc){
  const int i = blockIdx.x, t = threadIdx.x;
  C[(size_t)i*ldc + t] = X[(size_t)i*FDIM + t];
}

// ---------------------------------------------------------------- edges: logits + BCE loss
__global__ __launch_bounds__(256) void edge_loss(const int* __restrict__ src,
    const int* __restrict__ dst, const float* __restrict__ labels,
    const float* __restrict__ HP, const float* __restrict__ hcat,
    const float* __restrict__ predB, float* __restrict__ out){
  const int t = threadIdx.x;
  const int e = blockIdx.x*4 + (t >> 6);
  const int lane = t & 63;
  const int s = src[e], d = dst[e];
  const float* hp = HP   + (size_t)s*256;
  const float* hc = hcat + (size_t)d*256;
  float acc = 0.f;
  for (int k = lane; k < 256; k += 64) acc += hp[k] * hc[k];
  for (int o = 32; o > 0; o >>= 1) acc += __shfl_down(acc, o, 64);
  if (lane == 0){
    float l = acc + predB[0];
    out[1 + e] = l;
    float y = labels[e];
    float term = fmaxf(l, 0.f) - l*y + log1pf(expf(-fabsf(l)));
    atomicAdd(out, term * (1.0f / EEDGES));
  }
}

// ---------------------------------------------------------------- launcher
extern "C" void kernel_launch(void* const* d_in, const int* in_sizes, int n_in,
                              void* d_out, int out_size, void* d_ws, size_t ws_size,
                              hipStream_t stream){
  (void)in_sizes; (void)n_in; (void)out_size; (void)ws_size;
  const int*   src    = (const int*)d_in[0];
  const int*   dst    = (const int*)d_in[1];
  const float* labels = (const float*)d_in[2];
  const float* adj    = (const float*)d_in[3];
  const float* x      = (const float*)d_in[4];
  const float* Wg1    = (const float*)d_in[5];
  const float* Wg2    = (const float*)d_in[6];
  const float* Wp1    = (const float*)d_in[7];
  const float* b1     = (const float*)d_in[8];
  const float* Ws1    = (const float*)d_in[9];
  const float* Wp2    = (const float*)d_in[10];
  const float* b2     = (const float*)d_in[11];
  const float* Ws2    = (const float*)d_in[12];
  const float* PredW  = (const float*)d_in[13];
  const float* PredB  = (const float*)d_in[14];

  char* ws = (char*)d_ws;
  size_t off = 0;
  auto alloc = [&](size_t bytes)->void*{
    void* p = ws + off; off += (bytes + 255) & ~(size_t)255; return p; };

  int*   colcnt = (int*)  alloc((size_t)N_NODES*4);
  int*   nbrcnt = (int*)  alloc((size_t)N_NODES*4);
  int*   nbr    = (int*)  alloc((size_t)N_NODES*MAXNBR*4);
  float* d1inv  = (float*)alloc((size_t)N_NODES*4);
  float* d2inv  = (float*)alloc((size_t)N_NODES*4);
  float* xninv  = (float*)alloc((size_t)N_NODES*4);
  unsigned short* xbf = (unsigned short*)alloc((size_t)N_NODES*FDIM*2);
  int*   tidx48 = (int*)  alloc((size_t)N_NODES*KSEL*4);
  float* tval   = (float*)alloc((size_t)N_NODES*KTOP*4);
  int*   tidx   = (int*)  alloc((size_t)N_NODES*KTOP*4);
  float* dginv  = (float*)alloc((size_t)N_NODES*4);
  float* T      = (float*)alloc((size_t)N_NODES*FDIM*4);
  float* z1     = (float*)alloc((size_t)N_NODES*FDIM*4);
  float* cat1   = (float*)alloc((size_t)N_NODES*256*4);
  float* cat2   = (float*)alloc((size_t)N_NODES*256*4);
  float* hcat   = (float*)alloc((size_t)N_NODES*256*4);
  float* out    = (float*)d_out;

  hipMemsetAsync(colcnt, 0, (size_t)N_NODES*4, stream);
  hipMemsetAsync(d_out, 0, 4, stream);   // loss accumulator

  adj_scan   <<<N_NODES, 256, 0, stream>>>(adj, nbr, nbrcnt, colcnt);
  xprep      <<<N_NODES, 128, 0, stream>>>(x, xbf, xninv);
  node_norms <<<(N_NODES+255)/256, 256, 0, stream>>>(nbrcnt, colcnt, d1inv, d2inv);
  simtopk    <<<N_NODES/32, 256, 0, stream>>>(xbf, xninv, tidx48);
  refine48   <<<N_NODES, 192, 0, stream>>>(x, xninv, tidx48, tval, tidx, dginv);

  // GCN branch -> hcat[:, 0:128]
  gemm_k<128><<<N_NODES/32, 256, 0, stream>>>(x,  FDIM, Wg1, nullptr, T, FDIM, 128, 0);
  spmm_gcn   <<<N_NODES, 128, 0, stream>>>(T, nbr, nbrcnt, d1inv, d2inv, z1, FDIM);
  gemm_k<128><<<N_NODES/32, 256, 0, stream>>>(z1, FDIM, Wg2, nullptr, T, FDIM, 128, 0);
  spmm_gcn   <<<N_NODES, 128, 0, stream>>>(T, nbr, nbrcnt, d1inv, d2inv, hcat, 256);

  // SAGE layer 1: cat1 = [x | a_sim @ elu(x@Wp1+b1)], cat2[:,0:128] = elu(cat1@Ws1)
  copy128    <<<N_NODES, 128, 0, stream>>>(x, cat1, 256);
  gemm_k<128><<<N_NODES/32, 256, 0, stream>>>(x, FDIM, Wp1, b1, T, FDIM, 128, 1);
  spmm_sage  <<<N_NODES, 128, 0, stream>>>(T, tval, tidx, dginv, cat1 + 128, 256);
  gemm_k<128><<<N_NODES/32, 256, 0, stream>>>(cat1, 256, Ws1, nullptr, cat2, 256, 256, 1);

  // SAGE layer 2: cat2 = [z | a_sim @ elu(z@Wp2+b2)], hcat[:,128:256] = elu(cat2@Ws2)
  gemm_k<128><<<N_NODES/32, 256, 0, stream>>>(cat2, 256, Wp2, b2, T, FDIM, 128, 1);
  spmm_sage  <<<N_NODES, 128, 0, stream>>>(T, tval, tidx, dginv, cat2 + 128, 256);
  gemm_k<128><<<N_NODES/32, 256, 0, stream>>>(cat2, 256, Ws2, nullptr, hcat + 128, 256, 256, 1);

  // predictor: HP = hcat @ PredW (reuse cat1), then per-edge dot + BCE
  gemm_k<256><<<N_NODES/32, 256, 0, stream>>>(hcat, 256, PredW, nullptr, cat1, 256, 256, 0);
  edge_loss  <<<EEDGES/4, 256, 0, stream>>>(src, dst, labels, cat1, hcat, PredB, out);
}

// Round 6
// 1123.348 us; speedup vs baseline: 1.4563x; 1.4563x over previous
//
#include <hip/hip_runtime.h>
#include <hip/hip_bf16.h>
#include <stdint.h>

#define N_NODES 6144
#define FDIM    128
#define EEDGES  16384
#define KTOP    32
#define KSEL    48
#define MAXNBR  64
#define MAXCAND 256
#define NBINS   128

typedef short bf16x8 __attribute__((ext_vector_type(8)));
typedef float f32x4  __attribute__((ext_vector_type(4)));

__device__ __forceinline__ float elu_f(float x){ return x > 0.f ? x : expm1f(x); }

__device__ __forceinline__ unsigned short f2bf(float f){
  unsigned int u = __float_as_uint(f);
  u += 0x7FFFu + ((u >> 16) & 1u);   // RNE
  return (unsigned short)(u >> 16);
}

// ---------------------------------------------------------------- adj scan
__global__ __launch_bounds__(256) void adj_scan(const float* __restrict__ adj,
    int* __restrict__ nbr, int* __restrict__ nbrcnt, int* __restrict__ colcnt){
  const int i = blockIdx.x, t = threadIdx.x;
  __shared__ int s_cnt;
  if (t == 0) s_cnt = 0;
  __syncthreads();
  const float4* row = (const float4*)(adj + (size_t)i * N_NODES);
  for (int v = t; v < N_NODES/4; v += 256){
    float4 f = row[v];
    int b = v * 4;
    if (f.x != 0.f){ int s = atomicAdd(&s_cnt,1); if (s < MAXNBR) nbr[i*MAXNBR+s] = b;   atomicAdd(&colcnt[b],1); }
    if (f.y != 0.f){ int s = atomicAdd(&s_cnt,1); if (s < MAXNBR) nbr[i*MAXNBR+s] = b+1; atomicAdd(&colcnt[b+1],1); }
    if (f.z != 0.f){ int s = atomicAdd(&s_cnt,1); if (s < MAXNBR) nbr[i*MAXNBR+s] = b+2; atomicAdd(&colcnt[b+2],1); }
    if (f.w != 0.f){ int s = atomicAdd(&s_cnt,1); if (s < MAXNBR) nbr[i*MAXNBR+s] = b+3; atomicAdd(&colcnt[b+3],1); }
  }
  __syncthreads();
  if (t == 0) nbrcnt[i] = min(s_cnt, MAXNBR);
}

// ---------------------------------------------------------------- x prep: bf16 copy + 1/||x_i||
__global__ __launch_bounds__(128) void xprep(const float* __restrict__ x,
    unsigned short* __restrict__ xbf, float* __restrict__ xninv){
  const int i = blockIdx.x, t = threadIdx.x;
  float v = x[(size_t)i*FDIM + t];
  xbf[(size_t)i*FDIM + t] = f2bf(v);
  float s = v * v;
  for (int o = 32; o > 0; o >>= 1) s += __shfl_down(s, o, 64);
  __shared__ float ws[2];
  if ((t & 63) == 0) ws[t >> 6] = s;
  __syncthreads();
  if (t == 0) xninv[i] = rsqrtf(ws[0] + ws[1]);
}

__global__ __launch_bounds__(256) void node_norms(const int* __restrict__ nbrcnt,
    const int* __restrict__ colcnt, float* __restrict__ d1inv, float* __restrict__ d2inv){
  int i = blockIdx.x*256 + threadIdx.x;
  if (i < N_NODES){
    d1inv[i] = rsqrtf((float)(nbrcnt[i] + 1));
    d2inv[i] = rsqrtf((float)(colcnt[i] + 1));
  }
}

// ---------------------------------------------------------------- fused sim + candidate selection, 2 sweeps
// 32 rows/block. Sweep 1: per-row 128-bin histogram of bf16 cosines.
// Cut: rank-48 bin. Sweep 2: recompute (deterministic), emit cols >= cut bin.
__global__ __launch_bounds__(256) void simsel(const unsigned short* __restrict__ xbf,
    const float* __restrict__ xninv, int* __restrict__ cand, int* __restrict__ ccnt){
  const int t    = threadIdx.x;
  const int R0   = blockIdx.x * 32;
  const int lane = t & 63, w = t >> 6;
  const int lr   = lane & 15, q8 = (lane >> 4) * 8;

  __shared__ unsigned short Abf[32][136];
  __shared__ unsigned short Bbf[64][136];
  __shared__ int   hist[32][NBINS];
  __shared__ int   cutb[32];
  __shared__ float nrow[32];
  __shared__ float ncol[64];

  for (int e = t; e < 32*16; e += 256){
    int r = e >> 4, c8 = e & 15;
    *(uint4*)&Abf[r][c8*8] = ((const uint4*)(xbf + (size_t)(R0 + r)*FDIM))[c8];
  }
  if (t < 32) nrow[t] = xninv[R0 + t];
  for (int e = t; e < 32*NBINS; e += 256) hist[e >> 7][e & (NBINS-1)] = 0;

  // ---- sweep 1: histogram
  for (int tb = 0; tb < N_NODES/64; ++tb){
    __syncthreads();
    for (int e = t; e < 64*16; e += 256){
      int r = e >> 4, c8 = e & 15;
      *(uint4*)&Bbf[r][c8*8] = ((const uint4*)(xbf + (size_t)(tb*64 + r)*FDIM))[c8];
    }
    if (t < 64) ncol[t] = xninv[tb*64 + t];
    __syncthreads();

    f32x4 acc[2] = {};
#pragma unroll
    for (int kb = 0; kb < 4; ++kb){
      bf16x8 a0 = *(const bf16x8*)&Abf[lr     ][kb*32 + q8];
      bf16x8 a1 = *(const bf16x8*)&Abf[16 + lr][kb*32 + q8];
      bf16x8 b0 = *(const bf16x8*)&Bbf[w*16 + lr][kb*32 + q8];
      acc[0] = __builtin_amdgcn_mfma_f32_16x16x32_bf16(a0, b0, acc[0], 0, 0, 0);
      acc[1] = __builtin_amdgcn_mfma_f32_16x16x32_bf16(a1, b0, acc[1], 0, 0, 0);
    }
    const int col  = w*16 + lr;             // m89 C/D layout
    const int gcol = tb*64 + col;
    const float nc = ncol[col];
#pragma unroll
    for (int rf = 0; rf < 2; ++rf)
#pragma unroll
      for (int rg = 0; rg < 4; ++rg){
        int rrow = rf*16 + (lane >> 4)*4 + rg;
        float v = acc[rf][rg] * nrow[rrow] * nc;
        if (R0 + rrow == gcol) v = -2.0f;   // diag -> bin 0
        int b = (int)((v + 1.0f) * 64.0f);
        b = b < 0 ? 0 : (b > NBINS-1 ? NBINS-1 : b);
        atomicAdd(&hist[rrow][b], 1);
      }
  }
  __syncthreads();
  if (t < 32){                               // per-row rank-48 cutoff bin
    int c = 0, b = NBINS-1;
    for (; b >= 0; --b){ c += hist[t][b]; if (c >= KSEL) break; }
    cutb[t] = b < 0 ? 0 : b;
  }

  // ---- sweep 2: collect candidates
  for (int tb = 0; tb < N_NODES/64; ++tb){
    __syncthreads();
    for (int e = t; e < 64*16; e += 256){
      int r = e >> 4, c8 = e & 15;
      *(uint4*)&Bbf[r][c8*8] = ((const uint4*)(xbf + (size_t)(tb*64 + r)*FDIM))[c8];
    }
    if (t < 64) ncol[t] = xninv[tb*64 + t];
    __syncthreads();

    f32x4 acc[2] = {};
#pragma unroll
    for (int kb = 0; kb < 4; ++kb){
      bf16x8 a0 = *(const bf16x8*)&Abf[lr     ][kb*32 + q8];
      bf16x8 a1 = *(const bf16x8*)&Abf[16 + lr][kb*32 + q8];
      bf16x8 b0 = *(const bf16x8*)&Bbf[w*16 + lr][kb*32 + q8];
      acc[0] = __builtin_amdgcn_mfma_f32_16x16x32_bf16(a0, b0, acc[0], 0, 0, 0);
      acc[1] = __builtin_amdgcn_mfma_f32_16x16x32_bf16(a1, b0, acc[1], 0, 0, 0);
    }
    const int col  = w*16 + lr;
    const int gcol = tb*64 + col;
    const float nc = ncol[col];
#pragma unroll
    for (int rf = 0; rf < 2; ++rf)
#pragma unroll
      for (int rg = 0; rg < 4; ++rg){
        int rrow = rf*16 + (lane >> 4)*4 + rg;
        float v = acc[rf][rg] * nrow[rrow] * nc;
        if (R0 + rrow == gcol) v = -2.0f;
        int b = (int)((v + 1.0f) * 64.0f);
        b = b < 0 ? 0 : (b > NBINS-1 ? NBINS-1 : b);
        if (b >= cutb[rrow]){
          int s = atomicAdd(&ccnt[R0 + rrow], 1);
          if (s < MAXCAND) cand[(size_t)(R0 + rrow)*MAXCAND + s] = gcol;
        }
      }
  }
}

// ---------------------------------------------------------------- fp32 exact top-32 among candidates
__global__ __launch_bounds__(256) void refine(const float* __restrict__ x,
    const float* __restrict__ xninv, const int* __restrict__ cand,
    const int* __restrict__ ccnt, float* __restrict__ tval, int* __restrict__ tidx,
    float* __restrict__ deginv){
  const int i = blockIdx.x, t = threadIdx.x;
  __shared__ float xi[128];
  __shared__ float cv[MAXCAND];
  __shared__ int   ci[MAXCAND];
  __shared__ float sel[KTOP];
  if (t < 32) *(float4*)&xi[t*4] = *(const float4*)(x + (size_t)i*FDIM + t*4);
  __syncthreads();
  int n = ccnt[i]; if (n > MAXCAND) n = MAXCAND;
  const float ni = xninv[i];
  for (int c = t; c < n; c += 256){
    int idx = cand[(size_t)i*MAXCAND + c];
    const float* xc = x + (size_t)idx*FDIM;
    float acc = 0.f;
#pragma unroll
    for (int q = 0; q < 32; ++q){
      float4 f = *(const float4*)(xc + q*4);
      acc += xi[q*4+0]*f.x + xi[q*4+1]*f.y + xi[q*4+2]*f.z + xi[q*4+3]*f.w;
    }
    cv[c] = acc * ni * xninv[idx];
    ci[c] = idx;
  }
  __syncthreads();
  for (int c = t; c < n; c += 256){
    float v = cv[c]; int id = ci[c];
    int rank = 0;
    for (int j = 0; j < n; ++j){
      float u = cv[j];
      if (u > v || (u == v && ci[j] < id)) rank++;   // top_k tie-break: lower index
    }
    if (rank < KTOP){
      tval[(size_t)i*KTOP + rank] = v;
      tidx[(size_t)i*KTOP + rank] = id;
      sel[rank] = v;
    }
  }
  __syncthreads();
  if (t == 0){
    float s = 0.f;
    for (int q = 0; q < KTOP; ++q) s += sel[q];
    deginv[i] = 1.0f / fmaxf(s, 1e-5f);
  }
}

// ---------------------------------------------------------------- fp32 GEMM  C[N x M] = act(A@B + bias)
// 32 rows x 64 cols per block; grid (N/32, M/64). B pitch = M.
template<int M>
__global__ __launch_bounds__(256) void gemm_k(const float* __restrict__ A, int lda,
    const float* __restrict__ B, const float* __restrict__ bias,
    float* __restrict__ C, int ldc, int K, int act){
  const int t = threadIdx.x;
  const int R0 = blockIdx.x * 32, C0 = blockIdx.y * 64;
  const int rg = t >> 4, cg = t & 15;
  __shared__ float Alds[32][34];     // [k][r] transposed
  __shared__ float Blds[32][68];
  float4 acc0 = {0,0,0,0}, acc1 = {0,0,0,0};
  for (int kc = 0; kc < K; kc += 32){
    __syncthreads();
    { int r = t >> 3, k0 = (t & 7) * 4;
      float4 f = *(const float4*)(A + (size_t)(R0 + r)*lda + kc + k0);
      Alds[k0+0][r] = f.x; Alds[k0+1][r] = f.y; Alds[k0+2][r] = f.z; Alds[k0+3][r] = f.w; }
#pragma unroll
    for (int e = 0; e < 2; ++e){
      int idx = t + e*256;
      int k = idx >> 4, m4 = idx & 15;
      *(float4*)&Blds[k][m4*4] = *(const float4*)(B + (size_t)(kc + k)*M + C0 + m4*4);
    }
    __syncthreads();
#pragma unroll
    for (int k = 0; k < 32; ++k){
      float2 a = *(const float2*)&Alds[k][rg*2];
      float4 b = *(const float4*)&Blds[k][cg*4];
      acc0.x += a.x*b.x; acc0.y += a.x*b.y; acc0.z += a.x*b.z; acc0.w += a.x*b.w;
      acc1.x += a.y*b.x; acc1.y += a.y*b.y; acc1.z += a.y*b.z; acc1.w += a.y*b.w;
    }
  }
  const int r0 = R0 + rg*2, c0 = C0 + cg*4;
  float4 bb = {0,0,0,0};
  if (bias) bb = *(const float4*)&bias[c0];
  acc0.x += bb.x; acc0.y += bb.y; acc0.z += bb.z; acc0.w += bb.w;
  acc1.x += bb.x; acc1.y += bb.y; acc1.z += bb.z; acc1.w += bb.w;
  if (act){
    acc0.x = elu_f(acc0.x); acc0.y = elu_f(acc0.y); acc0.z = elu_f(acc0.z); acc0.w = elu_f(acc0.w);
    acc1.x = elu_f(acc1.x); acc1.y = elu_f(acc1.y); acc1.z = elu_f(acc1.z); acc1.w = elu_f(acc1.w);
  }
  *(float4*)&C[(size_t)r0*ldc + c0] = acc0;
  *(float4*)&C[(size_t)(r0+1)*ldc + c0] = acc1;
}

// ---------------------------------------------------------------- GCN SpMM
__global__ __launch_bounds__(128) void spmm_gcn(const float* __restrict__ T,
    const int* __restrict__ nbr, const int* __restrict__ nbrcnt,
    const float* __restrict__ d1inv, const float* __restrict__ d2inv,
    float* __restrict__ C, int ldc){
  const int i = blockIdx.x, t = threadIdx.x;
  float acc = T[(size_t)i*FDIM + t] * d2inv[i];     // +I diagonal term
  const int cnt = nbrcnt[i];
  const int* nb = nbr + (size_t)i*MAXNBR;
  for (int s = 0; s < cnt; ++s){
    int j = nb[s];
    acc += T[(size_t)j*FDIM + t] * d2inv[j];
  }
  C[(size_t)i*ldc + t] = elu_f(acc * d1inv[i]);
}

// ---------------------------------------------------------------- SAGE SpMM
__global__ __launch_bounds__(128) void spmm_sage(const float* __restrict__ P,
    const float* __restrict__ tval, const int* __restrict__ tidx,
    const float* __restrict__ deginv, float* __restrict__ C, int ldc){
  const int i = blockIdx.x, t = threadIdx.x;
  float acc = 0.f;
  const float* vv = tval + (size_t)i*KTOP;
  const int*   ii = tidx + (size_t)i*KTOP;
  for (int s = 0; s < KTOP; ++s)
    acc += vv[s] * P[(size_t)ii[s]*FDIM + t];
  C[(size_t)i*ldc + t] = acc * deginv[i];
}

__global__ __launch_bounds__(128) void copy128(const float* __restrict__ X,
    float* __restrict__ C, int ldc){
  const int i = blockIdx.x, t = threadIdx.x;
  C[(size_t)i*ldc + t] = X[(size_t)i*FDIM + t];
}

// ---------------------------------------------------------------- edges: logits + BCE loss
__global__ __launch_bounds__(256) void edge_loss(const int* __restrict__ src,
    const int* __restrict__ dst, const float* __restrict__ labels,
    const float* __restrict__ HP, const float* __restrict__ hcat,
    const float* __restrict__ predB, float* __restrict__ out){
  const int t = threadIdx.x;
  const int e = blockIdx.x*4 + (t >> 6);
  const int lane = t & 63;
  const int s = src[e], d = dst[e];
  const float* hp = HP   + (size_t)s*256;
  const float* hc = hcat + (size_t)d*256;
  float acc = 0.f;
  for (int k = lane; k < 256; k += 64) acc += hp[k] * hc[k];
  for (int o = 32; o > 0; o >>= 1) acc += __shfl_down(acc, o, 64);
  if (lane == 0){
    float l = acc + predB[0];
    out[1 + e] = l;
    float y = labels[e];
    float term = fmaxf(l, 0.f) - l*y + log1pf(expf(-fabsf(l)));
    atomicAdd(out, term * (1.0f / EEDGES));
  }
}

// ---------------------------------------------------------------- launcher
extern "C" void kernel_launch(void* const* d_in, const int* in_sizes, int n_in,
                              void* d_out, int out_size, void* d_ws, size_t ws_size,
                              hipStream_t stream){
  (void)in_sizes; (void)n_in; (void)out_size; (void)ws_size;
  const int*   src    = (const int*)d_in[0];
  const int*   dst    = (const int*)d_in[1];
  const float* labels = (const float*)d_in[2];
  const float* adj    = (const float*)d_in[3];
  const float* x      = (const float*)d_in[4];
  const float* Wg1    = (const float*)d_in[5];
  const float* Wg2    = (const float*)d_in[6];
  const float* Wp1    = (const float*)d_in[7];
  const float* b1     = (const float*)d_in[8];
  const float* Ws1    = (const float*)d_in[9];
  const float* Wp2    = (const float*)d_in[10];
  const float* b2     = (const float*)d_in[11];
  const float* Ws2    = (const float*)d_in[12];
  const float* PredW  = (const float*)d_in[13];
  const float* PredB  = (const float*)d_in[14];

  char* ws = (char*)d_ws;
  size_t off = 0;
  auto alloc = [&](size_t bytes)->void*{
    void* p = ws + off; off += (bytes + 255) & ~(size_t)255; return p; };

  int*   colcnt = (int*)  alloc((size_t)N_NODES*4);
  int*   nbrcnt = (int*)  alloc((size_t)N_NODES*4);
  int*   nbr    = (int*)  alloc((size_t)N_NODES*MAXNBR*4);
  float* d1inv  = (float*)alloc((size_t)N_NODES*4);
  float* d2inv  = (float*)alloc((size_t)N_NODES*4);
  float* xninv  = (float*)alloc((size_t)N_NODES*4);
  unsigned short* xbf = (unsigned short*)alloc((size_t)N_NODES*FDIM*2);
  int*   ccnt   = (int*)  alloc((size_t)N_NODES*4);
  float* tval   = (float*)alloc((size_t)N_NODES*KTOP*4);
  int*   tidx   = (int*)  alloc((size_t)N_NODES*KTOP*4);
  float* dginv  = (float*)alloc((size_t)N_NODES*4);
  float* T      = (float*)alloc((size_t)N_NODES*FDIM*4);
  float* z1     = (float*)alloc((size_t)N_NODES*FDIM*4);
  float* cat1   = (float*)alloc((size_t)N_NODES*256*4);
  float* cat2   = (float*)alloc((size_t)N_NODES*256*4);
  float* hcat   = (float*)alloc((size_t)N_NODES*256*4);
  int*   cand   = (int*)cat2;   // alias: cand lifetime (simsel->refine) ends before cat2 is written
  float* out    = (float*)d_out;

  hipMemsetAsync(colcnt, 0, (size_t)N_NODES*4, stream);
  hipMemsetAsync(ccnt,   0, (size_t)N_NODES*4, stream);
  hipMemsetAsync(d_out,  0, 4, stream);   // loss accumulator

  adj_scan   <<<N_NODES, 256, 0, stream>>>(adj, nbr, nbrcnt, colcnt);
  xprep      <<<N_NODES, 128, 0, stream>>>(x, xbf, xninv);
  node_norms <<<(N_NODES+255)/256, 256, 0, stream>>>(nbrcnt, colcnt, d1inv, d2inv);
  simsel     <<<N_NODES/32, 256, 0, stream>>>(xbf, xninv, cand, ccnt);
  refine     <<<N_NODES, 256, 0, stream>>>(x, xninv, cand, ccnt, tval, tidx, dginv);

  // GCN branch -> hcat[:, 0:128]
  gemm_k<128><<<dim3(N_NODES/32, 2), 256, 0, stream>>>(x,  FDIM, Wg1, nullptr, T, FDIM, 128, 0);
  spmm_gcn   <<<N_NODES, 128, 0, stream>>>(T, nbr, nbrcnt, d1inv, d2inv, z1, FDIM);
  gemm_k<128><<<dim3(N_NODES/32, 2), 256, 0, stream>>>(z1, FDIM, Wg2, nullptr, T, FDIM, 128, 0);
  spmm_gcn   <<<N_NODES, 128, 0, stream>>>(T, nbr, nbrcnt, d1inv, d2inv, hcat, 256);

  // SAGE layer 1
  copy128    <<<N_NODES, 128, 0, stream>>>(x, cat1, 256);
  gemm_k<128><<<dim3(N_NODES/32, 2), 256, 0, stream>>>(x, FDIM, Wp1, b1, T, FDIM, 128, 1);
  spmm_sage  <<<N_NODES, 128, 0, stream>>>(T, tval, tidx, dginv, cat1 + 128, 256);
  gemm_k<128><<<dim3(N_NODES/32, 2), 256, 0, stream>>>(cat1, 256, Ws1, nullptr, cat2, 256, 256, 1);

  // SAGE layer 2
  gemm_k<128><<<dim3(N_NODES/32, 2), 256, 0, stream>>>(cat2, 256, Wp2, b2, T, FDIM, 128, 1);
  spmm_sage  <<<N_NODES, 128, 0, stream>>>(T, tval, tidx, dginv, cat2 + 128, 256);
  gemm_k<128><<<dim3(N_NODES/32, 2), 256, 0, stream>>>(cat2, 256, Ws2, nullptr, hcat + 128, 256, 256, 1);

  // predictor
  gemm_k<256><<<dim3(N_NODES/32, 4), 256, 0, stream>>>(hcat, 256, PredW, nullptr, cat1, 256, 256, 0);
  edge_loss  <<<EEDGES/4, 256, 0, stream>>>(src, dst, labels, cat1, hcat, PredB, out);
}

// Round 8
// 902.264 us; speedup vs baseline: 1.8131x; 1.2450x over previous
//
#include <hip/hip_runtime.h>
#include <hip/hip_bf16.h>
#include <stdint.h>

#define N_NODES 6144
#define FDIM    128
#define EEDGES  16384
#define KTOP    32
#define KSEL    48
#define MAXNBR  64
#define MAXCAND 512
#define NTILES  96     // N_NODES/64
#define TPB     12     // tiles per block (NTILES / 8 grid.y)

typedef short bf16x8 __attribute__((ext_vector_type(8)));
typedef float f32x4  __attribute__((ext_vector_type(4)));

__device__ __forceinline__ float elu_f(float x){ return x > 0.f ? x : expm1f(x); }

__device__ __forceinline__ unsigned short f2bf(float f){
  unsigned int u = __float_as_uint(f);
  u += 0x7FFFu + ((u >> 16) & 1u);   // RNE
  return (unsigned short)(u >> 16);
}

// ---------------------------------------------------------------- adj scan
__global__ __launch_bounds__(256) void adj_scan(const float* __restrict__ adj,
    int* __restrict__ nbr, int* __restrict__ nbrcnt, int* __restrict__ colcnt){
  const int i = blockIdx.x, t = threadIdx.x;
  __shared__ int s_cnt;
  if (t == 0) s_cnt = 0;
  __syncthreads();
  const float4* row = (const float4*)(adj + (size_t)i * N_NODES);
  for (int v = t; v < N_NODES/4; v += 256){
    float4 f = row[v];
    int b = v * 4;
    if (f.x != 0.f){ int s = atomicAdd(&s_cnt,1); if (s < MAXNBR) nbr[i*MAXNBR+s] = b;   atomicAdd(&colcnt[b],1); }
    if (f.y != 0.f){ int s = atomicAdd(&s_cnt,1); if (s < MAXNBR) nbr[i*MAXNBR+s] = b+1; atomicAdd(&colcnt[b+1],1); }
    if (f.z != 0.f){ int s = atomicAdd(&s_cnt,1); if (s < MAXNBR) nbr[i*MAXNBR+s] = b+2; atomicAdd(&colcnt[b+2],1); }
    if (f.w != 0.f){ int s = atomicAdd(&s_cnt,1); if (s < MAXNBR) nbr[i*MAXNBR+s] = b+3; atomicAdd(&colcnt[b+3],1); }
  }
  __syncthreads();
  if (t == 0) nbrcnt[i] = min(s_cnt, MAXNBR);
}

// ---------------------------------------------------------------- x prep: bf16 copy + 1/||x_i||
__global__ __launch_bounds__(128) void xprep(const float* __restrict__ x,
    unsigned short* __restrict__ xbf, float* __restrict__ xninv){
  const int i = blockIdx.x, t = threadIdx.x;
  float v = x[(size_t)i*FDIM + t];
  xbf[(size_t)i*FDIM + t] = f2bf(v);
  float s = v * v;
  for (int o = 32; o > 0; o >>= 1) s += __shfl_down(s, o, 64);
  __shared__ float ws[2];
  if ((t & 63) == 0) ws[t >> 6] = s;
  __syncthreads();
  if (t == 0) xninv[i] = rsqrtf(ws[0] + ws[1]);
}

__global__ __launch_bounds__(256) void node_norms(const int* __restrict__ nbrcnt,
    const int* __restrict__ colcnt, float* __restrict__ d1inv, float* __restrict__ d2inv){
  int i = blockIdx.x*256 + threadIdx.x;
  if (i < N_NODES){
    d1inv[i] = rsqrtf((float)(nbrcnt[i] + 1));
    d2inv[i] = rsqrtf((float)(colcnt[i] + 1));
  }
}

// ---------------------------------------------------------------- tilemax: per (row, 64-col tile) max of bf16 cosine
// grid (192, 8): 32 rows x 12 tiles per block. Straight-line, no atomics.
__global__ __launch_bounds__(256) void tilemax(const unsigned short* __restrict__ xbf,
    const float* __restrict__ xninv, float* __restrict__ gmax){
  const int t    = threadIdx.x;
  const int R0   = blockIdx.x * 32;
  const int tb0  = blockIdx.y * TPB;
  const int lane = t & 63, w = t >> 6;
  const int lr   = lane & 15, q8 = (lane >> 4) * 8, quad = lane >> 4;

  __shared__ unsigned short Abf[32][136];
  __shared__ unsigned short Bbf[64][136];
  __shared__ float nrow[32];
  __shared__ float ncol[64];
  __shared__ float wmax[4][32];

  for (int e = t; e < 32*16; e += 256){
    int r = e >> 4, c8 = e & 15;
    *(uint4*)&Abf[r][c8*8] = ((const uint4*)(xbf + (size_t)(R0 + r)*FDIM))[c8];
  }
  if (t < 32) nrow[t] = xninv[R0 + t];

  for (int tb = tb0; tb < tb0 + TPB; ++tb){
    __syncthreads();                            // Bbf/wmax free
    for (int e = t; e < 64*16; e += 256){
      int r = e >> 4, c8 = e & 15;
      *(uint4*)&Bbf[r][c8*8] = ((const uint4*)(xbf + (size_t)(tb*64 + r)*FDIM))[c8];
    }
    if (t < 64) ncol[t] = xninv[tb*64 + t];
    __syncthreads();

    f32x4 acc[2] = {};
#pragma unroll
    for (int kb = 0; kb < 4; ++kb){
      bf16x8 a0 = *(const bf16x8*)&Abf[lr     ][kb*32 + q8];
      bf16x8 a1 = *(const bf16x8*)&Abf[16 + lr][kb*32 + q8];
      bf16x8 b0 = *(const bf16x8*)&Bbf[w*16 + lr][kb*32 + q8];
      acc[0] = __builtin_amdgcn_mfma_f32_16x16x32_bf16(a0, b0, acc[0], 0, 0, 0);
      acc[1] = __builtin_amdgcn_mfma_f32_16x16x32_bf16(a1, b0, acc[1], 0, 0, 0);
    }
    const int col  = w*16 + lr;                 // m89 C/D layout
    const int gcol = tb*64 + col;
    const float nc = ncol[col];
#pragma unroll
    for (int rf = 0; rf < 2; ++rf)
#pragma unroll
      for (int rg = 0; rg < 4; ++rg){
        int rrow = rf*16 + quad*4 + rg;
        float v = acc[rf][rg] * nrow[rrow] * nc;
        if (R0 + rrow == gcol) v = -2.0f;       // diag excluded
        v = fmaxf(v, __shfl_xor(v, 1, 64));     // max over the 16 cols in this quad
        v = fmaxf(v, __shfl_xor(v, 2, 64));
        v = fmaxf(v, __shfl_xor(v, 4, 64));
        v = fmaxf(v, __shfl_xor(v, 8, 64));
        if (lr == 0) wmax[w][rrow] = v;
      }
    __syncthreads();
    if (t < 32){
      float g = fmaxf(fmaxf(wmax[0][t], wmax[1][t]), fmaxf(wmax[2][t], wmax[3][t]));
      gmax[(size_t)(R0 + t)*NTILES + tb] = g;
    }
  }
}

// ---------------------------------------------------------------- tau: per row, 48th-largest tile-max
__global__ __launch_bounds__(256) void taukern(const float* __restrict__ gmax,
    float* __restrict__ tau){
  const int R0 = blockIdx.x * 32, t = threadIdx.x;
  __shared__ float tm[32][97];
  for (int e = t; e < 32*NTILES; e += 256){
    int r = e / NTILES, j = e % NTILES;
    tm[r][j] = gmax[(size_t)(R0 + r)*NTILES + j];
  }
  __syncthreads();
  if (t < 32){
    float m = 0.f;
    for (int k = 0; k < KSEL; ++k){             // 48 extraction passes
      m = -3.4e38f; int am = 0;
      for (int j = 0; j < NTILES; ++j){
        float u = tm[t][j];
        if (u > m){ m = u; am = j; }
      }
      tm[t][am] = -3.4e38f;
    }
    tau[R0 + t] = m;                            // 48th largest tile-max
  }
}

// ---------------------------------------------------------------- collect: emit cols with v >= tau[row]
__global__ __launch_bounds__(256) void collect(const unsigned short* __restrict__ xbf,
    const float* __restrict__ xninv, const float* __restrict__ tau,
    int* __restrict__ cand, int* __restrict__ ccnt){
  const int t    = threadIdx.x;
  const int R0   = blockIdx.x * 32;
  const int tb0  = blockIdx.y * TPB;
  const int lane = t & 63, w = t >> 6;
  const int lr   = lane & 15, q8 = (lane >> 4) * 8, quad = lane >> 4;

  __shared__ unsigned short Abf[32][136];
  __shared__ unsigned short Bbf[64][136];
  __shared__ float nrow[32];
  __shared__ float ncol[64];
  __shared__ float taus[32];

  for (int e = t; e < 32*16; e += 256){
    int r = e >> 4, c8 = e & 15;
    *(uint4*)&Abf[r][c8*8] = ((const uint4*)(xbf + (size_t)(R0 + r)*FDIM))[c8];
  }
  if (t < 32){ nrow[t] = xninv[R0 + t]; taus[t] = tau[R0 + t]; }

  for (int tb = tb0; tb < tb0 + TPB; ++tb){
    __syncthreads();
    for (int e = t; e < 64*16; e += 256){
      int r = e >> 4, c8 = e & 15;
      *(uint4*)&Bbf[r][c8*8] = ((const uint4*)(xbf + (size_t)(tb*64 + r)*FDIM))[c8];
    }
    if (t < 64) ncol[t] = xninv[tb*64 + t];
    __syncthreads();

    f32x4 acc[2] = {};
#pragma unroll
    for (int kb = 0; kb < 4; ++kb){
      bf16x8 a0 = *(const bf16x8*)&Abf[lr     ][kb*32 + q8];
      bf16x8 a1 = *(const bf16x8*)&Abf[16 + lr][kb*32 + q8];
      bf16x8 b0 = *(const bf16x8*)&Bbf[w*16 + lr][kb*32 + q8];
      acc[0] = __builtin_amdgcn_mfma_f32_16x16x32_bf16(a0, b0, acc[0], 0, 0, 0);
      acc[1] = __builtin_amdgcn_mfma_f32_16x16x32_bf16(a1, b0, acc[1], 0, 0, 0);
    }
    const int col  = w*16 + lr;
    const int gcol = tb*64 + col;
    const float nc = ncol[col];
#pragma unroll
    for (int rf = 0; rf < 2; ++rf)
#pragma unroll
      for (int rg = 0; rg < 4; ++rg){
        int rrow = rf*16 + quad*4 + rg;
        float v = acc[rf][rg] * nrow[rrow] * nc;
        if (R0 + rrow == gcol) v = -2.0f;
        if (v >= taus[rrow]){
          int s = atomicAdd(&ccnt[R0 + rrow], 1);
          if (s < MAXCAND) cand[(size_t)(R0 + rrow)*MAXCAND + s] = gcol;
        }
      }
  }
}

// ---------------------------------------------------------------- fp32 exact top-32 among candidates
__global__ __launch_bounds__(256) void refine(const float* __restrict__ x,
    const float* __restrict__ xninv, const int* __restrict__ cand,
    const int* __restrict__ ccnt, float* __restrict__ tval, int* __restrict__ tidx,
    float* __restrict__ deginv){
  const int i = blockIdx.x, t = threadIdx.x;
  __shared__ float xi[128];
  __shared__ float cv[MAXCAND];
  __shared__ int   ci[MAXCAND];
  __shared__ float sel[KTOP];
  if (t < 32) *(float4*)&xi[t*4] = *(const float4*)(x + (size_t)i*FDIM + t*4);
  __syncthreads();
  int n = ccnt[i]; if (n > MAXCAND) n = MAXCAND;
  const float ni = xninv[i];
  for (int c = t; c < n; c += 256){
    int idx = cand[(size_t)i*MAXCAND + c];
    const float* xc = x + (size_t)idx*FDIM;
    float acc = 0.f;
#pragma unroll
    for (int q = 0; q < 32; ++q){
      float4 f = *(const float4*)(xc + q*4);
      acc += xi[q*4+0]*f.x + xi[q*4+1]*f.y + xi[q*4+2]*f.z + xi[q*4+3]*f.w;
    }
    cv[c] = acc * ni * xninv[idx];
    ci[c] = idx;
  }
  __syncthreads();
  for (int c = t; c < n; c += 256){
    float v = cv[c]; int id = ci[c];
    int rank = 0;
    for (int j = 0; j < n; ++j){
      float u = cv[j];
      if (u > v || (u == v && ci[j] < id)) rank++;   // top_k tie-break: lower index
    }
    if (rank < KTOP){
      tval[(size_t)i*KTOP + rank] = v;
      tidx[(size_t)i*KTOP + rank] = id;
      sel[rank] = v;
    }
  }
  __syncthreads();
  if (t == 0){
    float s = 0.f;
    for (int q = 0; q < KTOP; ++q) s += sel[q];
    deginv[i] = 1.0f / fmaxf(s, 1e-5f);
  }
}

// ---------------------------------------------------------------- fp32 GEMM  C[N x M] = act(A@B + bias)
template<int M>
__global__ __launch_bounds__(256) void gemm_k(const float* __restrict__ A, int lda,
    const float* __restrict__ B, const float* __restrict__ bias,
    float* __restrict__ C, int ldc, int K, int act){
  const int t = threadIdx.x;
  const int R0 = blockIdx.x * 32, C0 = blockIdx.y * 64;
  const int rg = t >> 4, cg = t & 15;
  __shared__ float Alds[32][34];     // [k][r] transposed
  __shared__ float Blds[32][68];
  float4 acc0 = {0,0,0,0}, acc1 = {0,0,0,0};
  for (int kc = 0; kc < K; kc += 32){
    __syncthreads();
    { int r = t >> 3, k0 = (t & 7) * 4;
      float4 f = *(const float4*)(A + (size_t)(R0 + r)*lda + kc + k0);
      Alds[k0+0][r] = f.x; Alds[k0+1][r] = f.y; Alds[k0+2][r] = f.z; Alds[k0+3][r] = f.w; }
#pragma unroll
    for (int e = 0; e < 2; ++e){
      int idx = t + e*256;
      int k = idx >> 4, m4 = idx & 15;
      *(float4*)&Blds[k][m4*4] = *(const float4*)(B + (size_t)(kc + k)*M + C0 + m4*4);
    }
    __syncthreads();
#pragma unroll
    for (int k = 0; k < 32; ++k){
      float2 a = *(const float2*)&Alds[k][rg*2];
      float4 b = *(const float4*)&Blds[k][cg*4];
      acc0.x += a.x*b.x; acc0.y += a.x*b.y; acc0.z += a.x*b.z; acc0.w += a.x*b.w;
      acc1.x += a.y*b.x; acc1.y += a.y*b.y; acc1.z += a.y*b.z; acc1.w += a.y*b.w;
    }
  }
  const int r0 = R0 + rg*2, c0 = C0 + cg*4;
  float4 bb = {0,0,0,0};
  if (bias) bb = *(const float4*)&bias[c0];
  acc0.x += bb.x; acc0.y += bb.y; acc0.z += bb.z; acc0.w += bb.w;
  acc1.x += bb.x; acc1.y += bb.y; acc1.z += bb.z; acc1.w += bb.w;
  if (act){
    acc0.x = elu_f(acc0.x); acc0.y = elu_f(acc0.y); acc0.z = elu_f(acc0.z); acc0.w = elu_f(acc0.w);
    acc1.x = elu_f(acc1.x); acc1.y = elu_f(acc1.y); acc1.z = elu_f(acc1.z); acc1.w = elu_f(acc1.w);
  }
  *(float4*)&C[(size_t)r0*ldc + c0] = acc0;
  *(float4*)&C[(size_t)(r0+1)*ldc + c0] = acc1;
}

// ---------------------------------------------------------------- GCN SpMM
__global__ __launch_bounds__(128) void spmm_gcn(const float* __restrict__ T,
    const int* __restrict__ nbr, const int* __restrict__ nbrcnt,
    const float* __restrict__ d1inv, const float* __restrict__ d2inv,
    float* __restrict__ C, int ldc){
  const int i = blockIdx.x, t = threadIdx.x;
  float acc = T[(size_t)i*FDIM + t] * d2inv[i];     // +I diagonal term
  const int cnt = nbrcnt[i];
  const int* nb = nbr + (size_t)i*MAXNBR;
  for (int s = 0; s < cnt; ++s){
    int j = nb[s];
    acc += T[(size_t)j*FDIM + t] * d2inv[j];
  }
  C[(size_t)i*ldc + t] = elu_f(acc * d1inv[i]);
}

// ---------------------------------------------------------------- SAGE SpMM
__global__ __launch_bounds__(128) void spmm_sage(const float* __restrict__ P,
    const float* __restrict__ tval, const int* __restrict__ tidx,
    const float* __restrict__ deginv, float* __restrict__ C, int ldc){
  const int i = blockIdx.x, t = threadIdx.x;
  float acc = 0.f;
  const float* vv = tval + (size_t)i*KTOP;
  const int*   ii = tidx + (size_t)i*KTOP;
  for (int s = 0; s < KTOP; ++s)
    acc += vv[s] * P[(size_t)ii[s]*FDIM + t];
  C[(size_t)i*ldc + t] = acc * deginv[i];
}

__global__ __launch_bounds__(128) void copy128(const float* __restrict__ X,
    float* __restrict__ C, int ldc){
  const int i = blockIdx.x, t = threadIdx.x;
  C[(size_t)i*ldc + t] = X[(size_t)i*FDIM + t];
}

// ---------------------------------------------------------------- edges: logits + BCE loss
__global__ __launch_bounds__(256) void edge_loss(const int* __restrict__ src,
    const int* __restrict__ dst, const float* __restrict__ labels,
    const float* __restrict__ HP, const float* __restrict__ hcat,
    const float* __restrict__ predB, float* __restrict__ out){
  const int t = threadIdx.x;
  const int e = blockIdx.x*4 + (t >> 6);
  const int lane = t & 63;
  const int s = src[e], d = dst[e];
  const float* hp = HP   + (size_t)s*256;
  const float* hc = hcat + (size_t)d*256;
  float acc = 0.f;
  for (int k = lane; k < 256; k += 64) acc += hp[k] * hc[k];
  for (int o = 32; o > 0; o >>= 1) acc += __shfl_down(acc, o, 64);
  if (lane == 0){
    float l = acc + predB[0];
    out[1 + e] = l;
    float y = labels[e];
    float term = fmaxf(l, 0.f) - l*y + log1pf(expf(-fabsf(l)));
    atomicAdd(out, term * (1.0f / EEDGES));
  }
}

// ---------------------------------------------------------------- launcher
extern "C" void kernel_launch(void* const* d_in, const int* in_sizes, int n_in,
                              void* d_out, int out_size, void* d_ws, size_t ws_size,
                              hipStream_t stream){
  (void)in_sizes; (void)n_in; (void)out_size; (void)ws_size;
  const int*   src    = (const int*)d_in[0];
  const int*   dst    = (const int*)d_in[1];
  const float* labels = (const float*)d_in[2];
  const float* adj    = (const float*)d_in[3];
  const float* x      = (const float*)d_in[4];
  const float* Wg1    = (const float*)d_in[5];
  const float* Wg2    = (const float*)d_in[6];
  const float* Wp1    = (const float*)d_in[7];
  const float* b1     = (const float*)d_in[8];
  const float* Ws1    = (const float*)d_in[9];
  const float* Wp2    = (const float*)d_in[10];
  const float* b2     = (const float*)d_in[11];
  const float* Ws2    = (const float*)d_in[12];
  const float* PredW  = (const float*)d_in[13];
  const float* PredB  = (const float*)d_in[14];

  char* ws = (char*)d_ws;
  size_t off = 0;
  auto alloc = [&](size_t bytes)->void*{
    void* p = ws + off; off += (bytes + 255) & ~(size_t)255; return p; };

  // total ws footprint ~29.3 MB (kept below the ~31 MB proven-safe line)
  int*   colcnt = (int*)  alloc((size_t)N_NODES*4);
  int*   nbrcnt = (int*)  alloc((size_t)N_NODES*4);
  int*   nbr    = (int*)  alloc((size_t)N_NODES*MAXNBR*4);
  float* d1inv  = (float*)alloc((size_t)N_NODES*4);
  float* d2inv  = (float*)alloc((size_t)N_NODES*4);
  float* xninv  = (float*)alloc((size_t)N_NODES*4);
  unsigned short* xbf = (unsigned short*)alloc((size_t)N_NODES*FDIM*2);
  int*   ccnt   = (int*)  alloc((size_t)N_NODES*4);
  float* tval   = (float*)alloc((size_t)N_NODES*KTOP*4);
  int*   tidx   = (int*)  alloc((size_t)N_NODES*KTOP*4);
  float* dginv  = (float*)alloc((size_t)N_NODES*4);
  float* gmax   = (float*)alloc((size_t)N_NODES*NTILES*4);
  float* tau    = (float*)alloc((size_t)N_NODES*4);
  float* T      = (float*)alloc((size_t)N_NODES*FDIM*4);
  float* cat1   = (float*)alloc((size_t)N_NODES*256*4);
  float* cat2   = (float*)alloc((size_t)N_NODES*256*4);
  float* hcat   = (float*)alloc((size_t)N_NODES*256*4);
  int*   cand   = (int*)cat1;    // alias cat1+cat2 (12.58 MB); dead before cat1/cat2 written
  float* z1     = cat2;          // alias: z1 dead (after Wg2 GEMM) before cat2 first written
  float* out    = (float*)d_out;

  hipMemsetAsync(colcnt, 0, (size_t)N_NODES*4, stream);
  hipMemsetAsync(ccnt,   0, (size_t)N_NODES*4, stream);
  hipMemsetAsync(d_out,  0, 4, stream);   // loss accumulator

  adj_scan   <<<N_NODES, 256, 0, stream>>>(adj, nbr, nbrcnt, colcnt);
  xprep      <<<N_NODES, 128, 0, stream>>>(x, xbf, xninv);
  node_norms <<<(N_NODES+255)/256, 256, 0, stream>>>(nbrcnt, colcnt, d1inv, d2inv);
  tilemax    <<<dim3(N_NODES/32, 8), 256, 0, stream>>>(xbf, xninv, gmax);
  taukern    <<<N_NODES/32, 256, 0, stream>>>(gmax, tau);
  collect    <<<dim3(N_NODES/32, 8), 256, 0, stream>>>(xbf, xninv, tau, cand, ccnt);
  refine     <<<N_NODES, 256, 0, stream>>>(x, xninv, cand, ccnt, tval, tidx, dginv);

  // GCN branch -> hcat[:, 0:128]
  gemm_k<128><<<dim3(N_NODES/32, 2), 256, 0, stream>>>(x,  FDIM, Wg1, nullptr, T, FDIM, 128, 0);
  spmm_gcn   <<<N_NODES, 128, 0, stream>>>(T, nbr, nbrcnt, d1inv, d2inv, z1, FDIM);
  gemm_k<128><<<dim3(N_NODES/32, 2), 256, 0, stream>>>(z1, FDIM, Wg2, nullptr, T, FDIM, 128, 0);
  spmm_gcn   <<<N_NODES, 128, 0, stream>>>(T, nbr, nbrcnt, d1inv, d2inv, hcat, 256);

  // SAGE layer 1
  copy128    <<<N_NODES, 128, 0, stream>>>(x, cat1, 256);
  gemm_k<128><<<dim3(N_NODES/32, 2), 256, 0, stream>>>(x, FDIM, Wp1, b1, T, FDIM, 128, 1);
  spmm_sage  <<<N_NODES, 128, 0, stream>>>(T, tval, tidx, dginv, cat1 + 128, 256);
  gemm_k<128><<<dim3(N_NODES/32, 2), 256, 0, stream>>>(cat1, 256, Ws1, nullptr, cat2, 256, 256, 1);

  // SAGE layer 2
  gemm_k<128><<<dim3(N_NODES/32, 2), 256, 0, stream>>>(cat2, 256, Wp2, b2, T, FDIM, 128, 1);
  spmm_sage  <<<N_NODES, 128, 0, stream>>>(T, tval, tidx, dginv, cat2 + 128, 256);
  gemm_k<128><<<dim3(N_NODES/32, 2), 256, 0, stream>>>(cat2, 256, Ws2, nullptr, hcat + 128, 256, 256, 1);

  // predictor
  gemm_k<256><<<dim3(N_NODES/32, 4), 256, 0, stream>>>(hcat, 256, PredW, nullptr, cat1, 256, 256, 0);
  edge_loss  <<<EEDGES/4, 256, 0, stream>>>(src, dst, labels, cat1, hcat, PredB, out);
}

// Round 9
// 699.862 us; speedup vs baseline: 2.3375x; 1.2892x over previous
//
#include <hip/hip_runtime.h>
#include <hip/hip_bf16.h>
#include <stdint.h>

#define N_NODES 6144
#define FDIM    128
#define EEDGES  16384
#define KTOP    32
#define KSEL    48
#define MAXNBR  64
#define MAXCAND 512
#define NTILES  96     // N_NODES/64
#define TPB     12     // tiles per block (NTILES / 8 grid.y)

typedef short bf16x8 __attribute__((ext_vector_type(8)));
typedef float f32x4  __attribute__((ext_vector_type(4)));

__device__ __forceinline__ float elu_f(float x){ return x > 0.f ? x : expm1f(x); }

__device__ __forceinline__ unsigned short f2bf(float f){
  unsigned int u = __float_as_uint(f);
  u += 0x7FFFu + ((u >> 16) & 1u);   // RNE
  return (unsigned short)(u >> 16);
}

// ---------------------------------------------------------------- adj scan
__global__ __launch_bounds__(256) void adj_scan(const float* __restrict__ adj,
    int* __restrict__ nbr, int* __restrict__ nbrcnt, int* __restrict__ colcnt){
  const int i = blockIdx.x, t = threadIdx.x;
  __shared__ int s_cnt;
  if (t == 0) s_cnt = 0;
  __syncthreads();
  const float4* row = (const float4*)(adj + (size_t)i * N_NODES);
  for (int v = t; v < N_NODES/4; v += 256){
    float4 f = row[v];
    int b = v * 4;
    if (f.x != 0.f){ int s = atomicAdd(&s_cnt,1); if (s < MAXNBR) nbr[i*MAXNBR+s] = b;   atomicAdd(&colcnt[b],1); }
    if (f.y != 0.f){ int s = atomicAdd(&s_cnt,1); if (s < MAXNBR) nbr[i*MAXNBR+s] = b+1; atomicAdd(&colcnt[b+1],1); }
    if (f.z != 0.f){ int s = atomicAdd(&s_cnt,1); if (s < MAXNBR) nbr[i*MAXNBR+s] = b+2; atomicAdd(&colcnt[b+2],1); }
    if (f.w != 0.f){ int s = atomicAdd(&s_cnt,1); if (s < MAXNBR) nbr[i*MAXNBR+s] = b+3; atomicAdd(&colcnt[b+3],1); }
  }
  __syncthreads();
  if (t == 0) nbrcnt[i] = min(s_cnt, MAXNBR);
}

// ---------------------------------------------------------------- x prep: bf16 copy + 1/||x_i||
__global__ __launch_bounds__(128) void xprep(const float* __restrict__ x,
    unsigned short* __restrict__ xbf, float* __restrict__ xninv){
  const int i = blockIdx.x, t = threadIdx.x;
  float v = x[(size_t)i*FDIM + t];
  xbf[(size_t)i*FDIM + t] = f2bf(v);
  float s = v * v;
  for (int o = 32; o > 0; o >>= 1) s += __shfl_down(s, o, 64);
  __shared__ float ws[2];
  if ((t & 63) == 0) ws[t >> 6] = s;
  __syncthreads();
  if (t == 0) xninv[i] = rsqrtf(ws[0] + ws[1]);
}

__global__ __launch_bounds__(256) void node_norms(const int* __restrict__ nbrcnt,
    const int* __restrict__ colcnt, float* __restrict__ d1inv, float* __restrict__ d2inv){
  int i = blockIdx.x*256 + threadIdx.x;
  if (i < N_NODES){
    d1inv[i] = rsqrtf((float)(nbrcnt[i] + 1));
    d2inv[i] = rsqrtf((float)(colcnt[i] + 1));
  }
}

// ---------------------------------------------------------------- tilemax: per (row, 64-col tile) max of bf16 cosine
// grid (192, 8): 32 rows x 12 tiles per block. Straight-line, no atomics.
__global__ __launch_bounds__(256) void tilemax(const unsigned short* __restrict__ xbf,
    const float* __restrict__ xninv, float* __restrict__ gmax){
  const int t    = threadIdx.x;
  const int R0   = blockIdx.x * 32;
  const int tb0  = blockIdx.y * TPB;
  const int lane = t & 63, w = t >> 6;
  const int lr   = lane & 15, q8 = (lane >> 4) * 8, quad = lane >> 4;

  __shared__ unsigned short Abf[32][136];
  __shared__ unsigned short Bbf[64][136];
  __shared__ float nrow[32];
  __shared__ float ncol[64];
  __shared__ float wmax[4][32];

  for (int e = t; e < 32*16; e += 256){
    int r = e >> 4, c8 = e & 15;
    *(uint4*)&Abf[r][c8*8] = ((const uint4*)(xbf + (size_t)(R0 + r)*FDIM))[c8];
  }
  if (t < 32) nrow[t] = xninv[R0 + t];

  for (int tb = tb0; tb < tb0 + TPB; ++tb){
    __syncthreads();                            // Bbf/wmax free
    for (int e = t; e < 64*16; e += 256){
      int r = e >> 4, c8 = e & 15;
      *(uint4*)&Bbf[r][c8*8] = ((const uint4*)(xbf + (size_t)(tb*64 + r)*FDIM))[c8];
    }
    if (t < 64) ncol[t] = xninv[tb*64 + t];
    __syncthreads();

    f32x4 acc[2] = {};
#pragma unroll
    for (int kb = 0; kb < 4; ++kb){
      bf16x8 a0 = *(const bf16x8*)&Abf[lr     ][kb*32 + q8];
      bf16x8 a1 = *(const bf16x8*)&Abf[16 + lr][kb*32 + q8];
      bf16x8 b0 = *(const bf16x8*)&Bbf[w*16 + lr][kb*32 + q8];
      acc[0] = __builtin_amdgcn_mfma_f32_16x16x32_bf16(a0, b0, acc[0], 0, 0, 0);
      acc[1] = __builtin_amdgcn_mfma_f32_16x16x32_bf16(a1, b0, acc[1], 0, 0, 0);
    }
    const int col  = w*16 + lr;                 // m89 C/D layout
    const int gcol = tb*64 + col;
    const float nc = ncol[col];
#pragma unroll
    for (int rf = 0; rf < 2; ++rf)
#pragma unroll
      for (int rg = 0; rg < 4; ++rg){
        int rrow = rf*16 + quad*4 + rg;
        float v = acc[rf][rg] * nrow[rrow] * nc;
        if (R0 + rrow == gcol) v = -2.0f;       // diag excluded
        v = fmaxf(v, __shfl_xor(v, 1, 64));     // max over the 16 cols in this quad
        v = fmaxf(v, __shfl_xor(v, 2, 64));
        v = fmaxf(v, __shfl_xor(v, 4, 64));
        v = fmaxf(v, __shfl_xor(v, 8, 64));
        if (lr == 0) wmax[w][rrow] = v;
      }
    __syncthreads();
    if (t < 32){
      float g = fmaxf(fmaxf(wmax[0][t], wmax[1][t]), fmaxf(wmax[2][t], wmax[3][t]));
      gmax[(size_t)(R0 + t)*NTILES + tb] = g;
    }
  }
}

// ---------------------------------------------------------------- tau: per row, 48th-largest tile-max
__global__ __launch_bounds__(256) void taukern(const float* __restrict__ gmax,
    float* __restrict__ tau){
  const int R0 = blockIdx.x * 32, t = threadIdx.x;
  __shared__ float tm[32][97];
  for (int e = t; e < 32*NTILES; e += 256){
    int r = e / NTILES, j = e % NTILES;
    tm[r][j] = gmax[(size_t)(R0 + r)*NTILES + j];
  }
  __syncthreads();
  if (t < 32){
    float m = 0.f;
    for (int k = 0; k < KSEL; ++k){             // 48 extraction passes
      m = -3.4e38f; int am = 0;
      for (int j = 0; j < NTILES; ++j){
        float u = tm[t][j];
        if (u > m){ m = u; am = j; }
      }
      tm[t][am] = -3.4e38f;
    }
    tau[R0 + t] = m;                            // 48th largest tile-max
  }
}

// ---------------------------------------------------------------- collect: emit cols with v >= tau[row]
__global__ __launch_bounds__(256) void collect(const unsigned short* __restrict__ xbf,
    const float* __restrict__ xninv, const float* __restrict__ tau,
    int* __restrict__ cand, int* __restrict__ ccnt){
  const int t    = threadIdx.x;
  const int R0   = blockIdx.x * 32;
  const int tb0  = blockIdx.y * TPB;
  const int lane = t & 63, w = t >> 6;
  const int lr   = lane & 15, q8 = (lane >> 4) * 8, quad = lane >> 4;

  __shared__ unsigned short Abf[32][136];
  __shared__ unsigned short Bbf[64][136];
  __shared__ float nrow[32];
  __shared__ float ncol[64];
  __shared__ float taus[32];

  for (int e = t; e < 32*16; e += 256){
    int r = e >> 4, c8 = e & 15;
    *(uint4*)&Abf[r][c8*8] = ((const uint4*)(xbf + (size_t)(R0 + r)*FDIM))[c8];
  }
  if (t < 32){ nrow[t] = xninv[R0 + t]; taus[t] = tau[R0 + t]; }

  for (int tb = tb0; tb < tb0 + TPB; ++tb){
    __syncthreads();
    for (int e = t; e < 64*16; e += 256){
      int r = e >> 4, c8 = e & 15;
      *(uint4*)&Bbf[r][c8*8] = ((const uint4*)(xbf + (size_t)(tb*64 + r)*FDIM))[c8];
    }
    if (t < 64) ncol[t] = xninv[tb*64 + t];
    __syncthreads();

    f32x4 acc[2] = {};
#pragma unroll
    for (int kb = 0; kb < 4; ++kb){
      bf16x8 a0 = *(const bf16x8*)&Abf[lr     ][kb*32 + q8];
      bf16x8 a1 = *(const bf16x8*)&Abf[16 + lr][kb*32 + q8];
      bf16x8 b0 = *(const bf16x8*)&Bbf[w*16 + lr][kb*32 + q8];
      acc[0] = __builtin_amdgcn_mfma_f32_16x16x32_bf16(a0, b0, acc[0], 0, 0, 0);
      acc[1] = __builtin_amdgcn_mfma_f32_16x16x32_bf16(a1, b0, acc[1], 0, 0, 0);
    }
    const int col  = w*16 + lr;
    const int gcol = tb*64 + col;
    const float nc = ncol[col];
#pragma unroll
    for (int rf = 0; rf < 2; ++rf)
#pragma unroll
      for (int rg = 0; rg < 4; ++rg){
        int rrow = rf*16 + quad*4 + rg;
        float v = acc[rf][rg] * nrow[rrow] * nc;
        if (R0 + rrow == gcol) v = -2.0f;
        if (v >= taus[rrow]){
          int s = atomicAdd(&ccnt[R0 + rrow], 1);
          if (s < MAXCAND) cand[(size_t)(R0 + rrow)*MAXCAND + s] = gcol;
        }
      }
  }
}

// ---------------------------------------------------------------- fp32 exact top-32 among candidates
__global__ __launch_bounds__(256) void refine(const float* __restrict__ x,
    const float* __restrict__ xninv, const int* __restrict__ cand,
    const int* __restrict__ ccnt, float* __restrict__ tval, int* __restrict__ tidx,
    float* __restrict__ deginv){
  const int i = blockIdx.x, t = threadIdx.x;
  __shared__ float xi[128];
  __shared__ float cv[MAXCAND];
  __shared__ int   ci[MAXCAND];
  __shared__ float sel[KTOP];
  if (t < 32) *(float4*)&xi[t*4] = *(const float4*)(x + (size_t)i*FDIM + t*4);
  __syncthreads();
  int n = ccnt[i]; if (n > MAXCAND) n = MAXCAND;
  const float ni = xninv[i];
  for (int c = t; c < n; c += 256){
    int idx = cand[(size_t)i*MAXCAND + c];
    const float* xc = x + (size_t)idx*FDIM;
    float acc = 0.f;
#pragma unroll
    for (int q = 0; q < 32; ++q){
      float4 f = *(const float4*)(xc + q*4);
      acc += xi[q*4+0]*f.x + xi[q*4+1]*f.y + xi[q*4+2]*f.z + xi[q*4+3]*f.w;
    }
    cv[c] = acc * ni * xninv[idx];
    ci[c] = idx;
  }
  __syncthreads();
  for (int c = t; c < n; c += 256){
    float v = cv[c]; int id = ci[c];
    int rank = 0;
    for (int j = 0; j < n; ++j){
      float u = cv[j];
      if (u > v || (u == v && ci[j] < id)) rank++;   // top_k tie-break: lower index
    }
    if (rank < KTOP){
      tval[(size_t)i*KTOP + rank] = v;
      tidx[(size_t)i*KTOP + rank] = id;
      sel[rank] = v;
    }
  }
  __syncthreads();
  if (t == 0){
    float s = 0.f;
    for (int q = 0; q < KTOP; ++q) s += sel[q];
    deginv[i] = 1.0f / fmaxf(s, 1e-5f);
  }
}

// ---------------------------------------------------------------- fp32 GEMM  C[N x M] = act(A@B + bias)
template<int M>
__global__ __launch_bounds__(256) void gemm_k(const float* __restrict__ A, int lda,
    const float* __restrict__ B, const float* __restrict__ bias,
    float* __restrict__ C, int ldc, int K, int act){
  const int t = threadIdx.x;
  const int R0 = blockIdx.x * 32, C0 = blockIdx.y * 64;
  const int rg = t >> 4, cg = t & 15;
  __shared__ float Alds[32][34];     // [k][r] transposed
  __shared__ float Blds[32][68];
  float4 acc0 = {0,0,0,0}, acc1 = {0,0,0,0};
  for (int kc = 0; kc < K; kc += 32){
    __syncthreads();
    { int r = t >> 3, k0 = (t & 7) * 4;
      float4 f = *(const float4*)(A + (size_t)(R0 + r)*lda + kc + k0);
      Alds[k0+0][r] = f.x; Alds[k0+1][r] = f.y; Alds[k0+2][r] = f.z; Alds[k0+3][r] = f.w; }
#pragma unroll
    for (int e = 0; e < 2; ++e){
      int idx = t + e*256;
      int k = idx >> 4, m4 = idx & 15;
      *(float4*)&Blds[k][m4*4] = *(const float4*)(B + (size_t)(kc + k)*M + C0 + m4*4);
    }
    __syncthreads();
#pragma unroll
    for (int k = 0; k < 32; ++k){
      float2 a = *(const float2*)&Alds[k][rg*2];
      float4 b = *(const float4*)&Blds[k][cg*4];
      acc0.x += a.x*b.x; acc0.y += a.x*b.y; acc0.z += a.x*b.z; acc0.w += a.x*b.w;
      acc1.x += a.y*b.x; acc1.y += a.y*b.y; acc1.z += a.y*b.z; acc1.w += a.y*b.w;
    }
  }
  const int r0 = R0 + rg*2, c0 = C0 + cg*4;
  float4 bb = {0,0,0,0};
  if (bias) bb = *(const float4*)&bias[c0];
  acc0.x += bb.x; acc0.y += bb.y; acc0.z += bb.z; acc0.w += bb.w;
  acc1.x += bb.x; acc1.y += bb.y; acc1.z += bb.z; acc1.w += bb.w;
  if (act){
    acc0.x = elu_f(acc0.x); acc0.y = elu_f(acc0.y); acc0.z = elu_f(acc0.z); acc0.w = elu_f(acc0.w);
    acc1.x = elu_f(acc1.x); acc1.y = elu_f(acc1.y); acc1.z = elu_f(acc1.z); acc1.w = elu_f(acc1.w);
  }
  *(float4*)&C[(size_t)r0*ldc + c0] = acc0;
  *(float4*)&C[(size_t)(r0+1)*ldc + c0] = acc1;
}

// ---------------------------------------------------------------- GCN SpMM
__global__ __launch_bounds__(128) void spmm_gcn(const float* __restrict__ T,
    const int* __restrict__ nbr, const int* __restrict__ nbrcnt,
    const float* __restrict__ d1inv, const float* __restrict__ d2inv,
    float* __restrict__ C, int ldc){
  const int i = blockIdx.x, t = threadIdx.x;
  float acc = T[(size_t)i*FDIM + t] * d2inv[i];     // +I diagonal term
  const int cnt = nbrcnt[i];
  const int* nb = nbr + (size_t)i*MAXNBR;
  for (int s = 0; s < cnt; ++s){
    int j = nb[s];
    acc += T[(size_t)j*FDIM + t] * d2inv[j];
  }
  C[(size_t)i*ldc + t] = elu_f(acc * d1inv[i]);
}

// ---------------------------------------------------------------- SAGE SpMM
__global__ __launch_bounds__(128) void spmm_sage(const float* __restrict__ P,
    const float* __restrict__ tval, const int* __restrict__ tidx,
    const float* __restrict__ deginv, float* __restrict__ C, int ldc){
  const int i = blockIdx.x, t = threadIdx.x;
  float acc = 0.f;
  const float* vv = tval + (size_t)i*KTOP;
  const int*   ii = tidx + (size_t)i*KTOP;
  for (int s = 0; s < KTOP; ++s)
    acc += vv[s] * P[(size_t)ii[s]*FDIM + t];
  C[(size_t)i*ldc + t] = acc * deginv[i];
}

__global__ __launch_bounds__(128) void copy128(const float* __restrict__ X,
    float* __restrict__ C, int ldc){
  const int i = blockIdx.x, t = threadIdx.x;
  C[(size_t)i*ldc + t] = X[(size_t)i*FDIM + t];
}

// ---------------------------------------------------------------- edges: logits + per-block partial BCE (no global atomics)
__global__ __launch_bounds__(256) void edge_loss(const int* __restrict__ src,
    const int* __restrict__ dst, const float* __restrict__ labels,
    const float* __restrict__ HP, const float* __restrict__ hcat,
    const float* __restrict__ predB, float* __restrict__ out,
    float* __restrict__ partial){
  const int t = threadIdx.x;
  const int e = blockIdx.x*4 + (t >> 6);
  const int lane = t & 63;
  const int s = src[e], d = dst[e];
  const float* hp = HP   + (size_t)s*256;
  const float* hc = hcat + (size_t)d*256;
  float acc = 0.f;
  for (int k = lane; k < 256; k += 64) acc += hp[k] * hc[k];
  for (int o = 32; o > 0; o >>= 1) acc += __shfl_down(acc, o, 64);
  __shared__ float terms[4];
  if (lane == 0){
    float l = acc + predB[0];
    out[1 + e] = l;
    float y = labels[e];
    terms[t >> 6] = fmaxf(l, 0.f) - l*y + log1pf(expf(-fabsf(l)));
  }
  __syncthreads();
  if (t == 0) partial[blockIdx.x] = terms[0] + terms[1] + terms[2] + terms[3];
}

__global__ __launch_bounds__(256) void reduce_loss(const float* __restrict__ partial,
    float* __restrict__ out){
  const int t = threadIdx.x, lane = t & 63, w = t >> 6;
  float s = 0.f;
  for (int i = t; i < EEDGES/4; i += 256) s += partial[i];
  for (int o = 32; o > 0; o >>= 1) s += __shfl_down(s, o, 64);
  __shared__ float ws[4];
  if (lane == 0) ws[w] = s;
  __syncthreads();
  if (t == 0) out[0] = (ws[0] + ws[1] + ws[2] + ws[3]) * (1.0f / EEDGES);
}

// ---------------------------------------------------------------- launcher
extern "C" void kernel_launch(void* const* d_in, const int* in_sizes, int n_in,
                              void* d_out, int out_size, void* d_ws, size_t ws_size,
                              hipStream_t stream){
  (void)in_sizes; (void)n_in; (void)out_size; (void)ws_size;
  const int*   src    = (const int*)d_in[0];
  const int*   dst    = (const int*)d_in[1];
  const float* labels = (const float*)d_in[2];
  const float* adj    = (const float*)d_in[3];
  const float* x      = (const float*)d_in[4];
  const float* Wg1    = (const float*)d_in[5];
  const float* Wg2    = (const float*)d_in[6];
  const float* Wp1    = (const float*)d_in[7];
  const float* b1     = (const float*)d_in[8];
  const float* Ws1    = (const float*)d_in[9];
  const float* Wp2    = (const float*)d_in[10];
  const float* b2     = (const float*)d_in[11];
  const float* Ws2    = (const float*)d_in[12];
  const float* PredW  = (const float*)d_in[13];
  const float* PredB  = (const float*)d_in[14];

  char* ws = (char*)d_ws;
  size_t off = 0;
  auto alloc = [&](size_t bytes)->void*{
    void* p = ws + off; off += (bytes + 255) & ~(size_t)255; return p; };

  // total ws footprint ~29.3 MB (kept below the ~31 MB proven-safe line)
  int*   colcnt = (int*)  alloc((size_t)N_NODES*4);
  int*   nbrcnt = (int*)  alloc((size_t)N_NODES*4);
  int*   nbr    = (int*)  alloc((size_t)N_NODES*MAXNBR*4);
  float* d1inv  = (float*)alloc((size_t)N_NODES*4);
  float* d2inv  = (float*)alloc((size_t)N_NODES*4);
  float* xninv  = (float*)alloc((size_t)N_NODES*4);
  unsigned short* xbf = (unsigned short*)alloc((size_t)N_NODES*FDIM*2);
  int*   ccnt   = (int*)  alloc((size_t)N_NODES*4);
  float* tval   = (float*)alloc((size_t)N_NODES*KTOP*4);
  int*   tidx   = (int*)  alloc((size_t)N_NODES*KTOP*4);
  float* dginv  = (float*)alloc((size_t)N_NODES*4);
  float* gmax   = (float*)alloc((size_t)N_NODES*NTILES*4);
  float* tau    = (float*)alloc((size_t)N_NODES*4);
  float* partial= (float*)alloc((size_t)(EEDGES/4)*4);
  float* T      = (float*)alloc((size_t)N_NODES*FDIM*4);
  float* cat1   = (float*)alloc((size_t)N_NODES*256*4);
  float* cat2   = (float*)alloc((size_t)N_NODES*256*4);
  float* hcat   = (float*)alloc((size_t)N_NODES*256*4);
  int*   cand   = (int*)cat1;    // alias cat1+cat2 (12.58 MB); dead before cat1/cat2 written
  float* z1     = cat2;          // alias: z1 dead (after Wg2 GEMM) before cat2 first written
  float* out    = (float*)d_out;

  hipMemsetAsync(colcnt, 0, (size_t)N_NODES*4, stream);
  hipMemsetAsync(ccnt,   0, (size_t)N_NODES*4, stream);

  adj_scan   <<<N_NODES, 256, 0, stream>>>(adj, nbr, nbrcnt, colcnt);
  xprep      <<<N_NODES, 128, 0, stream>>>(x, xbf, xninv);
  node_norms <<<(N_NODES+255)/256, 256, 0, stream>>>(nbrcnt, colcnt, d1inv, d2inv);
  tilemax    <<<dim3(N_NODES/32, 8), 256, 0, stream>>>(xbf, xninv, gmax);
  taukern    <<<N_NODES/32, 256, 0, stream>>>(gmax, tau);
  collect    <<<dim3(N_NODES/32, 8), 256, 0, stream>>>(xbf, xninv, tau, cand, ccnt);
  refine     <<<N_NODES, 256, 0, stream>>>(x, xninv, cand, ccnt, tval, tidx, dginv);

  // GCN branch -> hcat[:, 0:128]
  gemm_k<128><<<dim3(N_NODES/32, 2), 256, 0, stream>>>(x,  FDIM, Wg1, nullptr, T, FDIM, 128, 0);
  spmm_gcn   <<<N_NODES, 128, 0, stream>>>(T, nbr, nbrcnt, d1inv, d2inv, z1, FDIM);
  gemm_k<128><<<dim3(N_NODES/32, 2), 256, 0, stream>>>(z1, FDIM, Wg2, nullptr, T, FDIM, 128, 0);
  spmm_gcn   <<<N_NODES, 128, 0, stream>>>(T, nbr, nbrcnt, d1inv, d2inv, hcat, 256);

  // SAGE layer 1
  copy128    <<<N_NODES, 128, 0, stream>>>(x, cat1, 256);
  gemm_k<128><<<dim3(N_NODES/32, 2), 256, 0, stream>>>(x, FDIM, Wp1, b1, T, FDIM, 128, 1);
  spmm_sage  <<<N_NODES, 128, 0, stream>>>(T, tval, tidx, dginv, cat1 + 128, 256);
  gemm_k<128><<<dim3(N_NODES/32, 2), 256, 0, stream>>>(cat1, 256, Ws1, nullptr, cat2, 256, 256, 1);

  // SAGE layer 2
  gemm_k<128><<<dim3(N_NODES/32, 2), 256, 0, stream>>>(cat2, 256, Wp2, b2, T, FDIM, 128, 1);
  spmm_sage  <<<N_NODES, 128, 0, stream>>>(T, tval, tidx, dginv, cat2 + 128, 256);
  gemm_k<128><<<dim3(N_NODES/32, 2), 256, 0, stream>>>(cat2, 256, Ws2, nullptr, hcat + 128, 256, 256, 1);

  // predictor
  gemm_k<256><<<dim3(N_NODES/32, 4), 256, 0, stream>>>(hcat, 256, PredW, nullptr, cat1, 256, 256, 0);
  edge_loss  <<<EEDGES/4, 256, 0, stream>>>(src, dst, labels, cat1, hcat, PredB, out, partial);
  reduce_loss<<<1, 256, 0, stream>>>(partial, out);
}

// Round 11
// 648.862 us; speedup vs baseline: 2.5212x; 1.0786x over previous
//
#include <hip/hip_runtime.h>
#include <hip/hip_bf16.h>
#include <stdint.h>

#define N_NODES 6144
#define FDIM    128
#define EEDGES  16384
#define KTOP    32
#define KSEL    48
#define MAXNBR  64
#define MAXCAND 512
#define NTILES  96     // N_NODES/64
#define TPB     12     // tiles per block (NTILES / 8 grid.y)

typedef short bf16x8 __attribute__((ext_vector_type(8)));
typedef float f32x4  __attribute__((ext_vector_type(4)));

__device__ __forceinline__ float elu_f(float x){ return x > 0.f ? x : expm1f(x); }

__device__ __forceinline__ unsigned short f2bf(float f){
  unsigned int u = __float_as_uint(f);
  u += 0x7FFFu + ((u >> 16) & 1u);   // RNE
  return (unsigned short)(u >> 16);
}

// ---------------------------------------------------------------- adj scan
__global__ __launch_bounds__(256) void adj_scan(const float* __restrict__ adj,
    int* __restrict__ nbr, int* __restrict__ nbrcnt, int* __restrict__ colcnt){
  const int i = blockIdx.x, t = threadIdx.x;
  __shared__ int s_cnt;
  if (t == 0) s_cnt = 0;
  __syncthreads();
  const float4* row = (const float4*)(adj + (size_t)i * N_NODES);
  for (int v = t; v < N_NODES/4; v += 256){
    float4 f = row[v];
    int b = v * 4;
    if (f.x != 0.f){ int s = atomicAdd(&s_cnt,1); if (s < MAXNBR) nbr[i*MAXNBR+s] = b;   atomicAdd(&colcnt[b],1); }
    if (f.y != 0.f){ int s = atomicAdd(&s_cnt,1); if (s < MAXNBR) nbr[i*MAXNBR+s] = b+1; atomicAdd(&colcnt[b+1],1); }
    if (f.z != 0.f){ int s = atomicAdd(&s_cnt,1); if (s < MAXNBR) nbr[i*MAXNBR+s] = b+2; atomicAdd(&colcnt[b+2],1); }
    if (f.w != 0.f){ int s = atomicAdd(&s_cnt,1); if (s < MAXNBR) nbr[i*MAXNBR+s] = b+3; atomicAdd(&colcnt[b+3],1); }
  }
  __syncthreads();
  if (t == 0) nbrcnt[i] = min(s_cnt, MAXNBR);
}

// ---------------------------------------------------------------- x prep: bf16 copy + 1/||x_i||
__global__ __launch_bounds__(128) void xprep(const float* __restrict__ x,
    unsigned short* __restrict__ xbf, float* __restrict__ xninv){
  const int i = blockIdx.x, t = threadIdx.x;
  float v = x[(size_t)i*FDIM + t];
  xbf[(size_t)i*FDIM + t] = f2bf(v);
  float s = v * v;
  for (int o = 32; o > 0; o >>= 1) s += __shfl_down(s, o, 64);
  __shared__ float ws[2];
  if ((t & 63) == 0) ws[t >> 6] = s;
  __syncthreads();
  if (t == 0) xninv[i] = rsqrtf(ws[0] + ws[1]);
}

__global__ __launch_bounds__(256) void node_norms(const int* __restrict__ nbrcnt,
    const int* __restrict__ colcnt, float* __restrict__ d1inv, float* __restrict__ d2inv){
  int i = blockIdx.x*256 + threadIdx.x;
  if (i < N_NODES){
    d1inv[i] = rsqrtf((float)(nbrcnt[i] + 1));
    d2inv[i] = rsqrtf((float)(colcnt[i] + 1));
  }
}

// ---------------------------------------------------------------- tilemax: per (row, 64-col tile) max of bf16 cosine
// grid (192, 8): 32 rows x 12 tiles per block. Straight-line, no atomics.
__global__ __launch_bounds__(256) void tilemax(const unsigned short* __restrict__ xbf,
    const float* __restrict__ xninv, float* __restrict__ gmax){
  const int t    = threadIdx.x;
  const int R0   = blockIdx.x * 32;
  const int tb0  = blockIdx.y * TPB;
  const int lane = t & 63, w = t >> 6;
  const int lr   = lane & 15, q8 = (lane >> 4) * 8, quad = lane >> 4;

  __shared__ unsigned short Abf[32][136];
  __shared__ unsigned short Bbf[64][136];
  __shared__ float nrow[32];
  __shared__ float ncol[64];
  __shared__ float wmax[4][32];

  for (int e = t; e < 32*16; e += 256){
    int r = e >> 4, c8 = e & 15;
    *(uint4*)&Abf[r][c8*8] = ((const uint4*)(xbf + (size_t)(R0 + r)*FDIM))[c8];
  }
  if (t < 32) nrow[t] = xninv[R0 + t];

  for (int tb = tb0; tb < tb0 + TPB; ++tb){
    __syncthreads();                            // Bbf/wmax free
    for (int e = t; e < 64*16; e += 256){
      int r = e >> 4, c8 = e & 15;
      *(uint4*)&Bbf[r][c8*8] = ((const uint4*)(xbf + (size_t)(tb*64 + r)*FDIM))[c8];
    }
    if (t < 64) ncol[t] = xninv[tb*64 + t];
    __syncthreads();

    f32x4 acc[2] = {};
#pragma unroll
    for (int kb = 0; kb < 4; ++kb){
      bf16x8 a0 = *(const bf16x8*)&Abf[lr     ][kb*32 + q8];
      bf16x8 a1 = *(const bf16x8*)&Abf[16 + lr][kb*32 + q8];
      bf16x8 b0 = *(const bf16x8*)&Bbf[w*16 + lr][kb*32 + q8];
      acc[0] = __builtin_amdgcn_mfma_f32_16x16x32_bf16(a0, b0, acc[0], 0, 0, 0);
      acc[1] = __builtin_amdgcn_mfma_f32_16x16x32_bf16(a1, b0, acc[1], 0, 0, 0);
    }
    const int col  = w*16 + lr;                 // m89 C/D layout
    const int gcol = tb*64 + col;
    const float nc = ncol[col];
#pragma unroll
    for (int rf = 0; rf < 2; ++rf)
#pragma unroll
      for (int rg = 0; rg < 4; ++rg){
        int rrow = rf*16 + quad*4 + rg;
        float v = acc[rf][rg] * nrow[rrow] * nc;
        if (R0 + rrow == gcol) v = -2.0f;       // diag excluded
        v = fmaxf(v, __shfl_xor(v, 1, 64));     // max over the 16 cols in this quad
        v = fmaxf(v, __shfl_xor(v, 2, 64));
        v = fmaxf(v, __shfl_xor(v, 4, 64));
        v = fmaxf(v, __shfl_xor(v, 8, 64));
        if (lr == 0) wmax[w][rrow] = v;
      }
    __syncthreads();
    if (t < 32){
      float g = fmaxf(fmaxf(wmax[0][t], wmax[1][t]), fmaxf(wmax[2][t], wmax[3][t]));
      gmax[(size_t)(R0 + t)*NTILES + tb] = g;
    }
  }
}

// ---------------------------------------------------------------- tau: per row, 48th-largest tile-max
__global__ __launch_bounds__(256) void taukern(const float* __restrict__ gmax,
    float* __restrict__ tau){
  const int R0 = blockIdx.x * 32, t = threadIdx.x;
  __shared__ float tm[32][97];
  for (int e = t; e < 32*NTILES; e += 256){
    int r = e / NTILES, j = e % NTILES;
    tm[r][j] = gmax[(size_t)(R0 + r)*NTILES + j];
  }
  __syncthreads();
  if (t < 32){
    float m = 0.f;
    for (int k = 0; k < KSEL; ++k){             // 48 extraction passes
      m = -3.4e38f; int am = 0;
      for (int j = 0; j < NTILES; ++j){
        float u = tm[t][j];
        if (u > m){ m = u; am = j; }
      }
      tm[t][am] = -3.4e38f;
    }
    tau[R0 + t] = m;                            // 48th largest tile-max
  }
}

// ---------------------------------------------------------------- collect: emit cols with v >= tau[row]
__global__ __launch_bounds__(256) void collect(const unsigned short* __restrict__ xbf,
    const float* __restrict__ xninv, const float* __restrict__ tau,
    int* __restrict__ cand, int* __restrict__ ccnt){
  const int t    = threadIdx.x;
  const int R0   = blockIdx.x * 32;
  const int tb0  = blockIdx.y * TPB;
  const int lane = t & 63, w = t >> 6;
  const int lr   = lane & 15, q8 = (lane >> 4) * 8, quad = lane >> 4;

  __shared__ unsigned short Abf[32][136];
  __shared__ unsigned short Bbf[64][136];
  __shared__ float nrow[32];
  __shared__ float ncol[64];
  __shared__ float taus[32];

  for (int e = t; e < 32*16; e += 256){
    int r = e >> 4, c8 = e & 15;
    *(uint4*)&Abf[r][c8*8] = ((const uint4*)(xbf + (size_t)(R0 + r)*FDIM))[c8];
  }
  if (t < 32){ nrow[t] = xninv[R0 + t]; taus[t] = tau[R0 + t]; }

  for (int tb = tb0; tb < tb0 + TPB; ++tb){
    __syncthreads();
    for (int e = t; e < 64*16; e += 256){
      int r = e >> 4, c8 = e & 15;
      *(uint4*)&Bbf[r][c8*8] = ((const uint4*)(xbf + (size_t)(tb*64 + r)*FDIM))[c8];
    }
    if (t < 64) ncol[t] = xninv[tb*64 + t];
    __syncthreads();

    f32x4 acc[2] = {};
#pragma unroll
    for (int kb = 0; kb < 4; ++kb){
      bf16x8 a0 = *(const bf16x8*)&Abf[lr     ][kb*32 + q8];
      bf16x8 a1 = *(const bf16x8*)&Abf[16 + lr][kb*32 + q8];
      bf16x8 b0 = *(const bf16x8*)&Bbf[w*16 + lr][kb*32 + q8];
      acc[0] = __builtin_amdgcn_mfma_f32_16x16x32_bf16(a0, b0, acc[0], 0, 0, 0);
      acc[1] = __builtin_amdgcn_mfma_f32_16x16x32_bf16(a1, b0, acc[1], 0, 0, 0);
    }
    const int col  = w*16 + lr;
    const int gcol = tb*64 + col;
    const float nc = ncol[col];
#pragma unroll
    for (int rf = 0; rf < 2; ++rf)
#pragma unroll
      for (int rg = 0; rg < 4; ++rg){
        int rrow = rf*16 + quad*4 + rg;
        float v = acc[rf][rg] * nrow[rrow] * nc;
        if (R0 + rrow == gcol) v = -2.0f;
        if (v >= taus[rrow]){
          int s = atomicAdd(&ccnt[R0 + rrow], 1);
          if (s < MAXCAND) cand[(size_t)(R0 + rrow)*MAXCAND + s] = gcol;
        }
      }
  }
}

// ---------------------------------------------------------------- fp32 exact top-32 among candidates
// 4 lanes per candidate (refine48 pattern): 16-row address divergence per
// wave-instruction instead of 64, all lanes active for n>=64.
__global__ __launch_bounds__(256) void refine(const float* __restrict__ x,
    const float* __restrict__ xninv, const int* __restrict__ cand,
    const int* __restrict__ ccnt, float* __restrict__ tval, int* __restrict__ tidx,
    float* __restrict__ deginv){
  const int i = blockIdx.x, t = threadIdx.x;
  __shared__ float xi[128];
  __shared__ float cv[MAXCAND];
  __shared__ int   ci[MAXCAND];
  __shared__ float sel[KTOP];
  if (t < 32) *(float4*)&xi[t*4] = *(const float4*)(x + (size_t)i*FDIM + t*4);
  int n = ccnt[i]; if (n > MAXCAND) n = MAXCAND;
  for (int c = t; c < n; c += 256) ci[c] = cand[(size_t)i*MAXCAND + c];
  __syncthreads();
  const float ni = xninv[i];
  const int part = t & 3, cb = t >> 2;        // 64 candidates per pass
  for (int c0 = 0; c0 < n; c0 += 64){
    const int c = c0 + cb;
    float acc = 0.f;
    int idx = 0;
    if (c < n){
      idx = ci[c];
      const float* xc = x + (size_t)idx*FDIM + part*32;
#pragma unroll
      for (int q = 0; q < 8; ++q){
        float4 f = *(const float4*)(xc + q*4);
        const float* a = &xi[part*32 + q*4];
        acc += a[0]*f.x + a[1]*f.y + a[2]*f.z + a[3]*f.w;
      }
    }
    acc += __shfl_xor(acc, 1, 64);
    acc += __shfl_xor(acc, 2, 64);
    if (c < n && part == 0) cv[c] = acc * ni * xninv[idx];
  }
  __syncthreads();
  for (int c = t; c < n; c += 256){
    float v = cv[c]; int id = ci[c];
    int rank = 0;
    for (int j = 0; j < n; ++j){
      float u = cv[j];
      if (u > v || (u == v && ci[j] < id)) rank++;   // top_k tie-break: lower index
    }
    if (rank < KTOP){
      tval[(size_t)i*KTOP + rank] = v;
      tidx[(size_t)i*KTOP + rank] = id;
      sel[rank] = v;
    }
  }
  __syncthreads();
  if (t == 0){
    float s = 0.f;
    for (int q = 0; q < KTOP; ++q) s += sel[q];
    deginv[i] = 1.0f / fmaxf(s, 1e-5f);
  }
}

// ---------------------------------------------------------------- fp32 GEMM  C[N x M] = act(A@B + bias)
template<int M>
__global__ __launch_bounds__(256) void gemm_k(const float* __restrict__ A, int lda,
    const float* __restrict__ B, const float* __restrict__ bias,
    float* __restrict__ C, int ldc, int K, int act){
  const int t = threadIdx.x;
  const int R0 = blockIdx.x * 32, C0 = blockIdx.y * 64;
  const int rg = t >> 4, cg = t & 15;
  __shared__ float Alds[32][34];     // [k][r] transposed
  __shared__ float Blds[32][68];
  float4 acc0 = {0,0,0,0}, acc1 = {0,0,0,0};
  for (int kc = 0; kc < K; kc += 32){
    __syncthreads();
    { int r = t >> 3, k0 = (t & 7) * 4;
      float4 f = *(const float4*)(A + (size_t)(R0 + r)*lda + kc + k0);
      Alds[k0+0][r] = f.x; Alds[k0+1][r] = f.y; Alds[k0+2][r] = f.z; Alds[k0+3][r] = f.w; }
#pragma unroll
    for (int e = 0; e < 2; ++e){
      int idx = t + e*256;
      int k = idx >> 4, m4 = idx & 15;
      *(float4*)&Blds[k][m4*4] = *(const float4*)(B + (size_t)(kc + k)*M + C0 + m4*4);
    }
    __syncthreads();
#pragma unroll
    for (int k = 0; k < 32; ++k){
      float2 a = *(const float2*)&Alds[k][rg*2];
      float4 b = *(const float4*)&Blds[k][cg*4];
      acc0.x += a.x*b.x; acc0.y += a.x*b.y; acc0.z += a.x*b.z; acc0.w += a.x*b.w;
      acc1.x += a.y*b.x; acc1.y += a.y*b.y; acc1.z += a.y*b.z; acc1.w += a.y*b.w;
    }
  }
  const int r0 = R0 + rg*2, c0 = C0 + cg*4;
  float4 bb = {0,0,0,0};
  if (bias) bb = *(const float4*)&bias[c0];
  acc0.x += bb.x; acc0.y += bb.y; acc0.z += bb.z; acc0.w += bb.w;
  acc1.x += bb.x; acc1.y += bb.y; acc1.z += bb.z; acc1.w += bb.w;
  if (act){
    acc0.x = elu_f(acc0.x); acc0.y = elu_f(acc0.y); acc0.z = elu_f(acc0.z); acc0.w = elu_f(acc0.w);
    acc1.x = elu_f(acc1.x); acc1.y = elu_f(acc1.y); acc1.z = elu_f(acc1.z); acc1.w = elu_f(acc1.w);
  }
  *(float4*)&C[(size_t)r0*ldc + c0] = acc0;
  *(float4*)&C[(size_t)(r0+1)*ldc + c0] = acc1;
}

// ---------------------------------------------------------------- GCN SpMM
__global__ __launch_bounds__(128) void spmm_gcn(const float* __restrict__ T,
    const int* __restrict__ nbr, const int* __restrict__ nbrcnt,
    const float* __restrict__ d1inv, const float* __restrict__ d2inv,
    float* __restrict__ C, int ldc){
  const int i = blockIdx.x, t = threadIdx.x;
  float acc = T[(size_t)i*FDIM + t] * d2inv[i];     // +I diagonal term
  const int cnt = nbrcnt[i];
  const int* nb = nbr + (size_t)i*MAXNBR;
  for (int s = 0; s < cnt; ++s){
    int j = nb[s];
    acc += T[(size_t)j*FDIM + t] * d2inv[j];
  }
  C[(size_t)i*ldc + t] = elu_f(acc * d1inv[i]);
}

// ---------------------------------------------------------------- SAGE SpMM
__global__ __launch_bounds__(128) void spmm_sage(const float* __restrict__ P,
    const float* __restrict__ tval, const int* __restrict__ tidx,
    const float* __restrict__ deginv, float* __restrict__ C, int ldc){
  const int i = blockIdx.x, t = threadIdx.x;
  float acc = 0.f;
  const float* vv = tval + (size_t)i*KTOP;
  const int*   ii = tidx + (size_t)i*KTOP;
  for (int s = 0; s < KTOP; ++s)
    acc += vv[s] * P[(size_t)ii[s]*FDIM + t];
  C[(size_t)i*ldc + t] = acc * deginv[i];
}

__global__ __launch_bounds__(128) void copy128(const float* __restrict__ X,
    float* __restrict__ C, int ldc){
  const int i = blockIdx.x, t = threadIdx.x;
  C[(size_t)i*ldc + t] = X[(size_t)i*FDIM + t];
}

// ---------------------------------------------------------------- edges: logits + per-block partial BCE (no global atomics)
__global__ __launch_bounds__(256) void edge_loss(const int* __restrict__ src,
    const int* __restrict__ dst, const float* __restrict__ labels,
    const float* __restrict__ HP, const float* __restrict__ hcat,
    const float* __restrict__ predB, float* __restrict__ out,
    float* __restrict__ partial){
  const int t = threadIdx.x;
  const int e = blockIdx.x*4 + (t >> 6);
  const int lane = t & 63;
  const int s = src[e], d = dst[e];
  const float* hp = HP   + (size_t)s*256;
  const float* hc = hcat + (size_t)d*256;
  float acc = 0.f;
  for (int k = lane; k < 256; k += 64) acc += hp[k] * hc[k];
  for (int o = 32; o > 0; o >>= 1) acc += __shfl_down(acc, o, 64);
  __shared__ float terms[4];
  if (lane == 0){
    float l = acc + predB[0];
    out[1 + e] = l;
    float y = labels[e];
    terms[t >> 6] = fmaxf(l, 0.f) - l*y + log1pf(expf(-fabsf(l)));
  }
  __syncthreads();
  if (t == 0) partial[blockIdx.x] = terms[0] + terms[1] + terms[2] + terms[3];
}

__global__ __launch_bounds__(256) void reduce_loss(const float* __restrict__ partial,
    float* __restrict__ out){
  const int t = threadIdx.x, lane = t & 63, w = t >> 6;
  float s = 0.f;
  for (int i = t; i < EEDGES/4; i += 256) s += partial[i];
  for (int o = 32; o > 0; o >>= 1) s += __shfl_down(s, o, 64);
  __shared__ float ws[4];
  if (lane == 0) ws[w] = s;
  __syncthreads();
  if (t == 0) out[0] = (ws[0] + ws[1] + ws[2] + ws[3]) * (1.0f / EEDGES);
}

// ---------------------------------------------------------------- launcher
extern "C" void kernel_launch(void* const* d_in, const int* in_sizes, int n_in,
                              void* d_out, int out_size, void* d_ws, size_t ws_size,
                              hipStream_t stream){
  (void)in_sizes; (void)n_in; (void)out_size; (void)ws_size;
  const int*   src    = (const int*)d_in[0];
  const int*   dst    = (const int*)d_in[1];
  const float* labels = (const float*)d_in[2];
  const float* adj    = (const float*)d_in[3];
  const float* x      = (const float*)d_in[4];
  const float* Wg1    = (const float*)d_in[5];
  const float* Wg2    = (const float*)d_in[6];
  const float* Wp1    = (const float*)d_in[7];
  const float* b1     = (const float*)d_in[8];
  const float* Ws1    = (const float*)d_in[9];
  const float* Wp2    = (const float*)d_in[10];
  const float* b2     = (const float*)d_in[11];
  const float* Ws2    = (const float*)d_in[12];
  const float* PredW  = (const float*)d_in[13];
  const float* PredB  = (const float*)d_in[14];

  char* ws = (char*)d_ws;
  size_t off = 0;
  auto alloc = [&](size_t bytes)->void*{
    void* p = ws + off; off += (bytes + 255) & ~(size_t)255; return p; };

  // total ws footprint ~29.3 MB (kept below the ~31 MB proven-safe line)
  int*   colcnt = (int*)  alloc((size_t)N_NODES*4);
  int*   nbrcnt = (int*)  alloc((size_t)N_NODES*4);
  int*   nbr    = (int*)  alloc((size_t)N_NODES*MAXNBR*4);
  float* d1inv  = (float*)alloc((size_t)N_NODES*4);
  float* d2inv  = (float*)alloc((size_t)N_NODES*4);
  float* xninv  = (float*)alloc((size_t)N_NODES*4);
  unsigned short* xbf = (unsigned short*)alloc((size_t)N_NODES*FDIM*2);
  int*   ccnt   = (int*)  alloc((size_t)N_NODES*4);
  float* tval   = (float*)alloc((size_t)N_NODES*KTOP*4);
  int*   tidx   = (int*)  alloc((size_t)N_NODES*KTOP*4);
  float* dginv  = (float*)alloc((size_t)N_NODES*4);
  float* gmax   = (float*)alloc((size_t)N_NODES*NTILES*4);
  float* tau    = (float*)alloc((size_t)N_NODES*4);
  float* partial= (float*)alloc((size_t)(EEDGES/4)*4);
  float* T      = (float*)alloc((size_t)N_NODES*FDIM*4);
  float* cat1   = (float*)alloc((size_t)N_NODES*256*4);
  float* cat2   = (float*)alloc((size_t)N_NODES*256*4);
  float* hcat   = (float*)alloc((size_t)N_NODES*256*4);
  int*   cand   = (int*)cat1;    // alias cat1+cat2 (12.58 MB); dead before cat1/cat2 written
  float* z1     = cat2;          // alias: z1 dead (after Wg2 GEMM) before cat2 first written
  float* out    = (float*)d_out;

  hipMemsetAsync(colcnt, 0, (size_t)N_NODES*4, stream);
  hipMemsetAsync(ccnt,   0, (size_t)N_NODES*4, stream);

  adj_scan   <<<N_NODES, 256, 0, stream>>>(adj, nbr, nbrcnt, colcnt);
  xprep      <<<N_NODES, 128, 0, stream>>>(x, xbf, xninv);
  node_norms <<<(N_NODES+255)/256, 256, 0, stream>>>(nbrcnt, colcnt, d1inv, d2inv);
  tilemax    <<<dim3(N_NODES/32, 8), 256, 0, stream>>>(xbf, xninv, gmax);
  taukern    <<<N_NODES/32, 256, 0, stream>>>(gmax, tau);
  collect    <<<dim3(N_NODES/32, 8), 256, 0, stream>>>(xbf, xninv, tau, cand, ccnt);
  refine     <<<N_NODES, 256, 0, stream>>>(x, xninv, cand, ccnt, tval, tidx, dginv);

  // GCN branch -> hcat[:, 0:128]
  gemm_k<128><<<dim3(N_NODES/32, 2), 256, 0, stream>>>(x,  FDIM, Wg1, nullptr, T, FDIM, 128, 0);
  spmm_gcn   <<<N_NODES, 128, 0, stream>>>(T, nbr, nbrcnt, d1inv, d2inv, z1, FDIM);
  gemm_k<128><<<dim3(N_NODES/32, 2), 256, 0, stream>>>(z1, FDIM, Wg2, nullptr, T, FDIM, 128, 0);
  spmm_gcn   <<<N_NODES, 128, 0, stream>>>(T, nbr, nbrcnt, d1inv, d2inv, hcat, 256);

  // SAGE layer 1
  copy128    <<<N_NODES, 128, 0, stream>>>(x, cat1, 256);
  gemm_k<128><<<dim3(N_NODES/32, 2), 256, 0, stream>>>(x, FDIM, Wp1, b1, T, FDIM, 128, 1);
  spmm_sage  <<<N_NODES, 128, 0, stream>>>(T, tval, tidx, dginv, cat1 + 128, 256);
  gemm_k<128><<<dim3(N_NODES/32, 2), 256, 0, stream>>>(cat1, 256, Ws1, nullptr, cat2, 256, 256, 1);

  // SAGE layer 2
  gemm_k<128><<<dim3(N_NODES/32, 2), 256, 0, stream>>>(cat2, 256, Wp2, b2, T, FDIM, 128, 1);
  spmm_sage  <<<N_NODES, 128, 0, stream>>>(T, tval, tidx, dginv, cat2 + 128, 256);
  gemm_k<128><<<dim3(N_NODES/32, 2), 256, 0, stream>>>(cat2, 256, Ws2, nullptr, hcat + 128, 256, 256, 1);

  // predictor
  gemm_k<256><<<dim3(N_NODES/32, 4), 256, 0, stream>>>(hcat, 256, PredW, nullptr, cat1, 256, 256, 0);
  edge_loss  <<<EEDGES/4, 256, 0, stream>>>(src, dst, labels, cat1, hcat, PredB, out, partial);
  reduce_loss<<<1, 256, 0, stream>>>(partial, out);
}

// Round 12
// 593.057 us; speedup vs baseline: 2.7585x; 1.0941x over previous
//
#include <hip/hip_runtime.h>
#include <hip/hip_bf16.h>
#include <stdint.h>

#define N_NODES 6144
#define FDIM    128
#define EEDGES  16384
#define KTOP    32
#define KSEL    48
#define MAXNBR  64
#define MAXCAND 512
#define NTILES  96     // N_NODES/64
#define TPB     12     // tiles per block (NTILES / 8 grid.y)

typedef short bf16x8 __attribute__((ext_vector_type(8)));
typedef float f32x4  __attribute__((ext_vector_type(4)));

__device__ __forceinline__ float elu_f(float x){ return x > 0.f ? x : expm1f(x); }

__device__ __forceinline__ unsigned short f2bf(float f){
  unsigned int u = __float_as_uint(f);
  u += 0x7FFFu + ((u >> 16) & 1u);   // RNE
  return (unsigned short)(u >> 16);
}
__device__ __forceinline__ float bf2f(unsigned short h){
  return __uint_as_float(((unsigned int)h) << 16);
}

// ---------------------------------------------------------------- adj scan
__global__ __launch_bounds__(256) void adj_scan(const float* __restrict__ adj,
    int* __restrict__ nbr, int* __restrict__ nbrcnt, int* __restrict__ colcnt){
  const int i = blockIdx.x, t = threadIdx.x;
  __shared__ int s_cnt;
  if (t == 0) s_cnt = 0;
  __syncthreads();
  const float4* row = (const float4*)(adj + (size_t)i * N_NODES);
  for (int v = t; v < N_NODES/4; v += 256){
    float4 f = row[v];
    int b = v * 4;
    if (f.x != 0.f){ int s = atomicAdd(&s_cnt,1); if (s < MAXNBR) nbr[i*MAXNBR+s] = b;   atomicAdd(&colcnt[b],1); }
    if (f.y != 0.f){ int s = atomicAdd(&s_cnt,1); if (s < MAXNBR) nbr[i*MAXNBR+s] = b+1; atomicAdd(&colcnt[b+1],1); }
    if (f.z != 0.f){ int s = atomicAdd(&s_cnt,1); if (s < MAXNBR) nbr[i*MAXNBR+s] = b+2; atomicAdd(&colcnt[b+2],1); }
    if (f.w != 0.f){ int s = atomicAdd(&s_cnt,1); if (s < MAXNBR) nbr[i*MAXNBR+s] = b+3; atomicAdd(&colcnt[b+3],1); }
  }
  __syncthreads();
  if (t == 0) nbrcnt[i] = min(s_cnt, MAXNBR);
}

// ---------------------------------------------------------------- x prep: bf16 copy + 1/||x_i|| + copy into cat1[:,0:128]
__global__ __launch_bounds__(128) void xprep(const float* __restrict__ x,
    unsigned short* __restrict__ xbf, float* __restrict__ xninv,
    float* __restrict__ cat1){
  const int i = blockIdx.x, t = threadIdx.x;
  float v = x[(size_t)i*FDIM + t];
  xbf[(size_t)i*FDIM + t] = f2bf(v);
  cat1[(size_t)i*256 + t] = v;              // folded copy128
  float s = v * v;
  for (int o = 32; o > 0; o >>= 1) s += __shfl_down(s, o, 64);
  __shared__ float ws[2];
  if ((t & 63) == 0) ws[t >> 6] = s;
  __syncthreads();
  if (t == 0) xninv[i] = rsqrtf(ws[0] + ws[1]);
}

// ---------------------------------------------------------------- simgemm: bf16 cosine tiles -> sim (stored) + per-tile row maxes
// grid (192, 8): 32 rows x 12 tiles of 64 cols per block. gmax reduced over
// the bf16-ROUNDED values so tau is consistent with the stored matrix.
__global__ __launch_bounds__(256) void simgemm(const unsigned short* __restrict__ xbf,
    const float* __restrict__ xninv, unsigned short* __restrict__ sim,
    float* __restrict__ gmax){
  const int t    = threadIdx.x;
  const int R0   = blockIdx.x * 32;
  const int tb0  = blockIdx.y * TPB;
  const int lane = t & 63, w = t >> 6;
  const int lr   = lane & 15, q8 = (lane >> 4) * 8, quad = lane >> 4;

  __shared__ unsigned short Abf[32][136];
  __shared__ unsigned short Bbf[64][136];
  __shared__ unsigned short Stile[32][72];    // bf16 64 cols + pad
  __shared__ float nrow[32];
  __shared__ float ncol[64];
  __shared__ float wmax[4][32];

  for (int e = t; e < 32*16; e += 256){
    int r = e >> 4, c8 = e & 15;
    *(uint4*)&Abf[r][c8*8] = ((const uint4*)(xbf + (size_t)(R0 + r)*FDIM))[c8];
  }
  if (t < 32) nrow[t] = xninv[R0 + t];

  for (int tb = tb0; tb < tb0 + TPB; ++tb){
    __syncthreads();                          // prev Stile/wmax consumed; Bbf free
    for (int e = t; e < 64*16; e += 256){
      int r = e >> 4, c8 = e & 15;
      *(uint4*)&Bbf[r][c8*8] = ((const uint4*)(xbf + (size_t)(tb*64 + r)*FDIM))[c8];
    }
    if (t < 64) ncol[t] = xninv[tb*64 + t];
    __syncthreads();

    f32x4 acc[2] = {};
#pragma unroll
    for (int kb = 0; kb < 4; ++kb){
      bf16x8 a0 = *(const bf16x8*)&Abf[lr     ][kb*32 + q8];
      bf16x8 a1 = *(const bf16x8*)&Abf[16 + lr][kb*32 + q8];
      bf16x8 b0 = *(const bf16x8*)&Bbf[w*16 + lr][kb*32 + q8];
      acc[0] = __builtin_amdgcn_mfma_f32_16x16x32_bf16(a0, b0, acc[0], 0, 0, 0);
      acc[1] = __builtin_amdgcn_mfma_f32_16x16x32_bf16(a1, b0, acc[1], 0, 0, 0);
    }
    const int col  = w*16 + lr;               // m89 C/D layout
    const int gcol = tb*64 + col;
    const float nc = ncol[col];
#pragma unroll
    for (int rf = 0; rf < 2; ++rf)
#pragma unroll
      for (int rg = 0; rg < 4; ++rg){
        int rrow = rf*16 + quad*4 + rg;
        float v = acc[rf][rg] * nrow[rrow] * nc;
        if (R0 + rrow == gcol) v = -2.0f;     // diag excluded
        unsigned short h = f2bf(v);
        Stile[rrow][col] = h;
        float vr = bf2f(h);                   // rounded domain for max/tau
        vr = fmaxf(vr, __shfl_xor(vr, 1, 64));
        vr = fmaxf(vr, __shfl_xor(vr, 2, 64));
        vr = fmaxf(vr, __shfl_xor(vr, 4, 64));
        vr = fmaxf(vr, __shfl_xor(vr, 8, 64));
        if (lr == 0) wmax[w][rrow] = vr;
      }
    __syncthreads();                          // Stile/wmax complete
    {
      int r = t >> 3, c8 = t & 7;             // 32 rows x 8 uint4 = 256 stores
      *(uint4*)&sim[(size_t)(R0 + r)*N_NODES + tb*64 + c8*8] = *(uint4*)&Stile[r][c8*8];
    }
    if (t < 32){
      float g = fmaxf(fmaxf(wmax[0][t], wmax[1][t]), fmaxf(wmax[2][t], wmax[3][t]));
      gmax[(size_t)(R0 + t)*NTILES + tb] = g;
    }
  }
}

// ---------------------------------------------------------------- tau (48th-largest tile-max) + node_norms (folded)
__global__ __launch_bounds__(256) void taukern(const float* __restrict__ gmax,
    float* __restrict__ tau, const int* __restrict__ nbrcnt,
    const int* __restrict__ colcnt, float* __restrict__ d1inv,
    float* __restrict__ d2inv){
  const int R0 = blockIdx.x * 32, t = threadIdx.x;
  {                                           // folded node_norms
    int i = blockIdx.x*256 + t;
    if (i < N_NODES){
      d1inv[i] = rsqrtf((float)(nbrcnt[i] + 1));
      d2inv[i] = rsqrtf((float)(colcnt[i] + 1));
    }
  }
  __shared__ float tm[32][97];
  for (int e = t; e < 32*NTILES; e += 256){
    int r = e / NTILES, j = e % NTILES;
    tm[r][j] = gmax[(size_t)(R0 + r)*NTILES + j];
  }
  __syncthreads();
  if (t < 32){
    float m = 0.f;
    for (int k = 0; k < KSEL; ++k){           // 48 extraction passes
      m = -3.4e38f; int am = 0;
      for (int j = 0; j < NTILES; ++j){
        float u = tm[t][j];
        if (u > m){ m = u; am = j; }
      }
      tm[t][am] = -3.4e38f;
    }
    tau[R0 + t] = m;                          // 48th largest tile-max (rounded domain)
  }
}

// ---------------------------------------------------------------- refine_scan: scan stored sim row, filter >= tau, exact fp32 top-32
__global__ __launch_bounds__(256) void refine_scan(const float* __restrict__ x,
    const float* __restrict__ xninv, const unsigned short* __restrict__ sim,
    const float* __restrict__ tau, float* __restrict__ tval, int* __restrict__ tidx,
    float* __restrict__ deginv){
  const int i = blockIdx.x, t = threadIdx.x;
  __shared__ float xi[128];
  __shared__ float cv[MAXCAND];
  __shared__ int   ci[MAXCAND];
  __shared__ float sel[KTOP];
  __shared__ int   cnt;
  if (t == 0) cnt = 0;
  if (t < 32) *(float4*)&xi[t*4] = *(const float4*)(x + (size_t)i*FDIM + t*4);
  __syncthreads();
  const float taui = tau[i];
  const uint4* srow = (const uint4*)(sim + (size_t)i*N_NODES);
  for (int v8 = t; v8 < N_NODES/8; v8 += 256){
    uint4 u = srow[v8];
    const unsigned short* h = (const unsigned short*)&u;
#pragma unroll
    for (int q = 0; q < 8; ++q){
      if (bf2f(h[q]) >= taui){                // diag stored as -2 -> never passes
        int s = atomicAdd(&cnt, 1);
        if (s < MAXCAND) ci[s] = v8*8 + q;
      }
    }
  }
  __syncthreads();
  int n = cnt; if (n > MAXCAND) n = MAXCAND;
  const float ni = xninv[i];
  const int part = t & 3, cb = t >> 2;        // 4 lanes per candidate
  for (int c0 = 0; c0 < n; c0 += 64){
    const int c = c0 + cb;
    float acc = 0.f;
    int idx = 0;
    if (c < n){
      idx = ci[c];
      const float* xc = x + (size_t)idx*FDIM + part*32;
#pragma unroll
      for (int q = 0; q < 8; ++q){
        float4 f = *(const float4*)(xc + q*4);
        const float* a = &xi[part*32 + q*4];
        acc += a[0]*f.x + a[1]*f.y + a[2]*f.z + a[3]*f.w;
      }
    }
    acc += __shfl_xor(acc, 1, 64);
    acc += __shfl_xor(acc, 2, 64);
    if (c < n && part == 0) cv[c] = acc * ni * xninv[idx];
  }
  __syncthreads();
  for (int c = t; c < n; c += 256){
    float v = cv[c]; int id = ci[c];
    int rank = 0;
    for (int j = 0; j < n; ++j){
      float u = cv[j];
      if (u > v || (u == v && ci[j] < id)) rank++;   // top_k tie-break: lower index
    }
    if (rank < KTOP){
      tval[(size_t)i*KTOP + rank] = v;
      tidx[(size_t)i*KTOP + rank] = id;
      sel[rank] = v;
    }
  }
  __syncthreads();
  if (t == 0){
    float s = 0.f;
    for (int q = 0; q < KTOP; ++q) s += sel[q];
    deginv[i] = 1.0f / fmaxf(s, 1e-5f);
  }
}

// ---------------------------------------------------------------- fp32 GEMM  C[N x M] = act(A@B + bias)
template<int M>
__global__ __launch_bounds__(256) void gemm_k(const float* __restrict__ A, int lda,
    const float* __restrict__ B, const float* __restrict__ bias,
    float* __restrict__ C, int ldc, int K, int act){
  const int t = threadIdx.x;
  const int R0 = blockIdx.x * 32, C0 = blockIdx.y * 64;
  const int rg = t >> 4, cg = t & 15;
  __shared__ float Alds[32][34];     // [k][r] transposed
  __shared__ float Blds[32][68];
  float4 acc0 = {0,0,0,0}, acc1 = {0,0,0,0};
  for (int kc = 0; kc < K; kc += 32){
    __syncthreads();
    { int r = t >> 3, k0 = (t & 7) * 4;
      float4 f = *(const float4*)(A + (size_t)(R0 + r)*lda + kc + k0);
      Alds[k0+0][r] = f.x; Alds[k0+1][r] = f.y; Alds[k0+2][r] = f.z; Alds[k0+3][r] = f.w; }
#pragma unroll
    for (int e = 0; e < 2; ++e){
      int idx = t + e*256;
      int k = idx >> 4, m4 = idx & 15;
      *(float4*)&Blds[k][m4*4] = *(const float4*)(B + (size_t)(kc + k)*M + C0 + m4*4);
    }
    __syncthreads();
#pragma unroll
    for (int k = 0; k < 32; ++k){
      float2 a = *(const float2*)&Alds[k][rg*2];
      float4 b = *(const float4*)&Blds[k][cg*4];
      acc0.x += a.x*b.x; acc0.y += a.x*b.y; acc0.z += a.x*b.z; acc0.w += a.x*b.w;
      acc1.x += a.y*b.x; acc1.y += a.y*b.y; acc1.z += a.y*b.z; acc1.w += a.y*b.w;
    }
  }
  const int r0 = R0 + rg*2, c0 = C0 + cg*4;
  float4 bb = {0,0,0,0};
  if (bias) bb = *(const float4*)&bias[c0];
  acc0.x += bb.x; acc0.y += bb.y; acc0.z += bb.z; acc0.w += bb.w;
  acc1.x += bb.x; acc1.y += bb.y; acc1.z += bb.z; acc1.w += bb.w;
  if (act){
    acc0.x = elu_f(acc0.x); acc0.y = elu_f(acc0.y); acc0.z = elu_f(acc0.z); acc0.w = elu_f(acc0.w);
    acc1.x = elu_f(acc1.x); acc1.y = elu_f(acc1.y); acc1.z = elu_f(acc1.z); acc1.w = elu_f(acc1.w);
  }
  *(float4*)&C[(size_t)r0*ldc + c0] = acc0;
  *(float4*)&C[(size_t)(r0+1)*ldc + c0] = acc1;
}

// ---------------------------------------------------------------- GCN SpMM
__global__ __launch_bounds__(128) void spmm_gcn(const float* __restrict__ T,
    const int* __restrict__ nbr, const int* __restrict__ nbrcnt,
    const float* __restrict__ d1inv, const float* __restrict__ d2inv,
    float* __restrict__ C, int ldc){
  const int i = blockIdx.x, t = threadIdx.x;
  float acc = T[(size_t)i*FDIM + t] * d2inv[i];     // +I diagonal term
  const int cnt = nbrcnt[i];
  const int* nb = nbr + (size_t)i*MAXNBR;
  for (int s = 0; s < cnt; ++s){
    int j = nb[s];
    acc += T[(size_t)j*FDIM + t] * d2inv[j];
  }
  C[(size_t)i*ldc + t] = elu_f(acc * d1inv[i]);
}

// ---------------------------------------------------------------- SAGE SpMM
__global__ __launch_bounds__(128) void spmm_sage(const float* __restrict__ P,
    const float* __restrict__ tval, const int* __restrict__ tidx,
    const float* __restrict__ deginv, float* __restrict__ C, int ldc){
  const int i = blockIdx.x, t = threadIdx.x;
  float acc = 0.f;
  const float* vv = tval + (size_t)i*KTOP;
  const int*   ii = tidx + (size_t)i*KTOP;
  for (int s = 0; s < KTOP; ++s)
    acc += vv[s] * P[(size_t)ii[s]*FDIM + t];
  C[(size_t)i*ldc + t] = acc * deginv[i];
}

// ---------------------------------------------------------------- edges: logits + per-block partial BCE (no global atomics)
__global__ __launch_bounds__(256) void edge_loss(const int* __restrict__ src,
    const int* __restrict__ dst, const float* __restrict__ labels,
    const float* __restrict__ HP, const float* __restrict__ hcat,
    const float* __restrict__ predB, float* __restrict__ out,
    float* __restrict__ partial){
  const int t = threadIdx.x;
  const int e = blockIdx.x*4 + (t >> 6);
  const int lane = t & 63;
  const int s = src[e], d = dst[e];
  const float* hp = HP   + (size_t)s*256;
  const float* hc = hcat + (size_t)d*256;
  float acc = 0.f;
  for (int k = lane; k < 256; k += 64) acc += hp[k] * hc[k];
  for (int o = 32; o > 0; o >>= 1) acc += __shfl_down(acc, o, 64);
  __shared__ float terms[4];
  if (lane == 0){
    float l = acc + predB[0];
    out[1 + e] = l;
    float y = labels[e];
    terms[t >> 6] = fmaxf(l, 0.f) - l*y + log1pf(expf(-fabsf(l)));
  }
  __syncthreads();
  if (t == 0) partial[blockIdx.x] = terms[0] + terms[1] + terms[2] + terms[3];
}

__global__ __launch_bounds__(256) void reduce_loss(const float* __restrict__ partial,
    float* __restrict__ out){
  const int t = threadIdx.x, lane = t & 63, w = t >> 6;
  float s = 0.f;
  for (int i = t; i < EEDGES/4; i += 256) s += partial[i];
  for (int o = 32; o > 0; o >>= 1) s += __shfl_down(s, o, 64);
  __shared__ float ws[4];
  if (lane == 0) ws[w] = s;
  __syncthreads();
  if (t == 0) out[0] = (ws[0] + ws[1] + ws[2] + ws[3]) * (1.0f / EEDGES);
}

// ---------------------------------------------------------------- launcher
extern "C" void kernel_launch(void* const* d_in, const int* in_sizes, int n_in,
                              void* d_out, int out_size, void* d_ws, size_t ws_size,
                              hipStream_t stream){
  (void)in_sizes; (void)n_in; (void)out_size; (void)ws_size;
  const int*   src    = (const int*)d_in[0];
  const int*   dst    = (const int*)d_in[1];
  const float* labels = (const float*)d_in[2];
  const float* adj    = (const float*)d_in[3];
  const float* x      = (const float*)d_in[4];
  const float* Wg1    = (const float*)d_in[5];
  const float* Wg2    = (const float*)d_in[6];
  const float* Wp1    = (const float*)d_in[7];
  const float* b1     = (const float*)d_in[8];
  const float* Ws1    = (const float*)d_in[9];
  const float* Wp2    = (const float*)d_in[10];
  const float* b2     = (const float*)d_in[11];
  const float* Ws2    = (const float*)d_in[12];
  const float* PredW  = (const float*)d_in[13];
  const float* PredB  = (const float*)d_in[14];

  char* ws = (char*)d_ws;
  size_t off = 0;
  auto alloc = [&](size_t bytes)->void*{
    void* p = ws + off; off += (bytes + 255) & ~(size_t)255; return p; };

  // total ws footprint ~105 MB (ws_size measured 576 MiB via harness 0xAA fill)
  int*   colcnt = (int*)  alloc((size_t)N_NODES*4);
  int*   nbrcnt = (int*)  alloc((size_t)N_NODES*4);
  int*   nbr    = (int*)  alloc((size_t)N_NODES*MAXNBR*4);
  float* d1inv  = (float*)alloc((size_t)N_NODES*4);
  float* d2inv  = (float*)alloc((size_t)N_NODES*4);
  float* xninv  = (float*)alloc((size_t)N_NODES*4);
  unsigned short* xbf = (unsigned short*)alloc((size_t)N_NODES*FDIM*2);
  float* tval   = (float*)alloc((size_t)N_NODES*KTOP*4);
  int*   tidx   = (int*)  alloc((size_t)N_NODES*KTOP*4);
  float* dginv  = (float*)alloc((size_t)N_NODES*4);
  float* gmax   = (float*)alloc((size_t)N_NODES*NTILES*4);
  float* tau    = (float*)alloc((size_t)N_NODES*4);
  float* partial= (float*)alloc((size_t)(EEDGES/4)*4);
  float* T      = (float*)alloc((size_t)N_NODES*FDIM*4);
  float* cat1   = (float*)alloc((size_t)N_NODES*256*4);
  float* cat2   = (float*)alloc((size_t)N_NODES*256*4);
  float* hcat   = (float*)alloc((size_t)N_NODES*256*4);
  unsigned short* sim = (unsigned short*)alloc((size_t)N_NODES*N_NODES*2);
  float* z1     = cat2;          // alias: z1 dead (after Wg2 GEMM) before cat2 first written
  float* out    = (float*)d_out;

  hipMemsetAsync(colcnt, 0, (size_t)N_NODES*4, stream);

  adj_scan   <<<N_NODES, 256, 0, stream>>>(adj, nbr, nbrcnt, colcnt);
  xprep      <<<N_NODES, 128, 0, stream>>>(x, xbf, xninv, cat1);
  simgemm    <<<dim3(N_NODES/32, 8), 256, 0, stream>>>(xbf, xninv, sim, gmax);
  taukern    <<<N_NODES/32, 256, 0, stream>>>(gmax, tau, nbrcnt, colcnt, d1inv, d2inv);
  refine_scan<<<N_NODES, 256, 0, stream>>>(x, xninv, sim, tau, tval, tidx, dginv);

  // GCN branch -> hcat[:, 0:128]
  gemm_k<128><<<dim3(N_NODES/32, 2), 256, 0, stream>>>(x,  FDIM, Wg1, nullptr, T, FDIM, 128, 0);
  spmm_gcn   <<<N_NODES, 128, 0, stream>>>(T, nbr, nbrcnt, d1inv, d2inv, z1, FDIM);
  gemm_k<128><<<dim3(N_NODES/32, 2), 256, 0, stream>>>(z1, FDIM, Wg2, nullptr, T, FDIM, 128, 0);
  spmm_gcn   <<<N_NODES, 128, 0, stream>>>(T, nbr, nbrcnt, d1inv, d2inv, hcat, 256);

  // SAGE layer 1 (cat1[:,0:128] = x, written by xprep)
  gemm_k<128><<<dim3(N_NODES/32, 2), 256, 0, stream>>>(x, FDIM, Wp1, b1, T, FDIM, 128, 1);
  spmm_sage  <<<N_NODES, 128, 0, stream>>>(T, tval, tidx, dginv, cat1 + 128, 256);
  gemm_k<128><<<dim3(N_NODES/32, 2), 256, 0, stream>>>(cat1, 256, Ws1, nullptr, cat2, 256, 256, 1);

  // SAGE layer 2
  gemm_k<128><<<dim3(N_NODES/32, 2), 256, 0, stream>>>(cat2, 256, Wp2, b2, T, FDIM, 128, 1);
  spmm_sage  <<<N_NODES, 128, 0, stream>>>(T, tval, tidx, dginv, cat2 + 128, 256);
  gemm_k<128><<<dim3(N_NODES/32, 2), 256, 0, stream>>>(cat2, 256, Ws2, nullptr, hcat + 128, 256, 256, 1);

  // predictor
  gemm_k<256><<<dim3(N_NODES/32, 4), 256, 0, stream>>>(hcat, 256, PredW, nullptr, cat1, 256, 256, 0);
  edge_loss  <<<EEDGES/4, 256, 0, stream>>>(src, dst, labels, cat1, hcat, PredB, out, partial);
  reduce_loss<<<1, 256, 0, stream>>>(partial, out);
}

// Round 13
// 558.028 us; speedup vs baseline: 2.9316x; 1.0628x over previous
//
#include <hip/hip_runtime.h>
#include <hip/hip_bf16.h>
#include <stdint.h>

#define N_NODES 6144
#define FDIM    128
#define EEDGES  16384
#define KTOP    32
#define KSEL    48
#define MAXNBR  64
#define MAXCAND 512
#define NTILES  96     // N_NODES/64
#define GRIDY   16
#define TPB     (NTILES/GRIDY)   // 6 tiles per block

typedef short bf16x8 __attribute__((ext_vector_type(8)));
typedef float f32x4  __attribute__((ext_vector_type(4)));

__device__ __forceinline__ float elu_f(float x){ return x > 0.f ? x : expm1f(x); }

__device__ __forceinline__ unsigned short f2bf(float f){
  unsigned int u = __float_as_uint(f);
  u += 0x7FFFu + ((u >> 16) & 1u);   // RNE
  return (unsigned short)(u >> 16);
}
__device__ __forceinline__ float bf2f(unsigned short h){
  return __uint_as_float(((unsigned int)h) << 16);
}

// ---------------------------------------------------------------- adj scan
__global__ __launch_bounds__(256) void adj_scan(const float* __restrict__ adj,
    int* __restrict__ nbr, int* __restrict__ nbrcnt, int* __restrict__ colcnt){
  const int i = blockIdx.x, t = threadIdx.x;
  __shared__ int s_cnt;
  if (t == 0) s_cnt = 0;
  __syncthreads();
  const float4* row = (const float4*)(adj + (size_t)i * N_NODES);
  for (int v = t; v < N_NODES/4; v += 256){
    float4 f = row[v];
    int b = v * 4;
    if (f.x != 0.f){ int s = atomicAdd(&s_cnt,1); if (s < MAXNBR) nbr[i*MAXNBR+s] = b;   atomicAdd(&colcnt[b],1); }
    if (f.y != 0.f){ int s = atomicAdd(&s_cnt,1); if (s < MAXNBR) nbr[i*MAXNBR+s] = b+1; atomicAdd(&colcnt[b+1],1); }
    if (f.z != 0.f){ int s = atomicAdd(&s_cnt,1); if (s < MAXNBR) nbr[i*MAXNBR+s] = b+2; atomicAdd(&colcnt[b+2],1); }
    if (f.w != 0.f){ int s = atomicAdd(&s_cnt,1); if (s < MAXNBR) nbr[i*MAXNBR+s] = b+3; atomicAdd(&colcnt[b+3],1); }
  }
  __syncthreads();
  if (t == 0) nbrcnt[i] = min(s_cnt, MAXNBR);
}

// ---------------------------------------------------------------- x prep: bf16 copy + 1/||x_i|| + copy into cat1[:,0:128]
__global__ __launch_bounds__(128) void xprep(const float* __restrict__ x,
    unsigned short* __restrict__ xbf, float* __restrict__ xninv,
    float* __restrict__ cat1){
  const int i = blockIdx.x, t = threadIdx.x;
  float v = x[(size_t)i*FDIM + t];
  xbf[(size_t)i*FDIM + t] = f2bf(v);
  cat1[(size_t)i*256 + t] = v;              // folded copy128
  float s = v * v;
  for (int o = 32; o > 0; o >>= 1) s += __shfl_down(s, o, 64);
  __shared__ float ws[2];
  if ((t & 63) == 0) ws[t >> 6] = s;
  __syncthreads();
  if (t == 0) xninv[i] = rsqrtf(ws[0] + ws[1]);
}

// ---------------------------------------------------------------- simgemm: bf16 cosine tiles -> sim (stored) + per-tile row maxes
// grid (192, 16): 32 rows x 6 tiles of 64 cols per block.
// Operand-SWAPPED MFMA: D reg axis = sim cols -> each lane holds 4
// consecutive cols of ONE row: b64 LDS write + cheap quad-shfl row max.
__global__ __launch_bounds__(256) void simgemm(const unsigned short* __restrict__ xbf,
    const float* __restrict__ xninv, unsigned short* __restrict__ sim,
    float* __restrict__ gmax){
  const int t    = threadIdx.x;
  const int R0   = blockIdx.x * 32;
  const int tb0  = blockIdx.y * TPB;
  const int lane = t & 63, w = t >> 6;
  const int lr   = lane & 15, q8 = (lane >> 4) * 8, quad = lane >> 4;

  __shared__ unsigned short Abf[32][136];
  __shared__ unsigned short Bbf[64][136];
  __shared__ unsigned short Stile[32][72];    // row stride 144 B (16B-aligned)
  __shared__ float nrow[32];
  __shared__ float ncol[64];
  __shared__ float wmax[4][32];

  for (int e = t; e < 32*16; e += 256){
    int r = e >> 4, c8 = e & 15;
    *(uint4*)&Abf[r][c8*8] = ((const uint4*)(xbf + (size_t)(R0 + r)*FDIM))[c8];
  }
  if (t < 32) nrow[t] = xninv[R0 + t];

  for (int tb = tb0; tb < tb0 + TPB; ++tb){
    __syncthreads();                          // prev Stile/wmax consumed; Bbf free
    for (int e = t; e < 64*16; e += 256){
      int r = e >> 4, c8 = e & 15;
      *(uint4*)&Bbf[r][c8*8] = ((const uint4*)(xbf + (size_t)(tb*64 + r)*FDIM))[c8];
    }
    if (t < 64) ncol[t] = xninv[tb*64 + t];
    __syncthreads();

    // swapped: first operand (m) = sim cols (B rows), second (n) = sim rows
    f32x4 acc[2] = {};
#pragma unroll
    for (int kb = 0; kb < 4; ++kb){
      bf16x8 bcol  = *(const bf16x8*)&Bbf[w*16 + lr][kb*32 + q8];
      bf16x8 arow0 = *(const bf16x8*)&Abf[lr      ][kb*32 + q8];
      bf16x8 arow1 = *(const bf16x8*)&Abf[16 + lr ][kb*32 + q8];
      acc[0] = __builtin_amdgcn_mfma_f32_16x16x32_bf16(bcol, arow0, acc[0], 0, 0, 0);
      acc[1] = __builtin_amdgcn_mfma_f32_16x16x32_bf16(bcol, arow1, acc[1], 0, 0, 0);
    }
    // D[row=quad*4+rg = sim col within strip][col=lr = sim row within frag]
    const int scol0 = w*16 + quad*4;          // 4 consecutive sim cols
    const float nc0 = ncol[scol0], nc1 = ncol[scol0+1],
                nc2 = ncol[scol0+2], nc3 = ncol[scol0+3];
#pragma unroll
    for (int f = 0; f < 2; ++f){
      const int srow = f*16 + lr;
      const float nr = nrow[srow];
      const int grow = R0 + srow, gcol0 = tb*64 + scol0;
      float v0 = acc[f][0]*nr*nc0, v1 = acc[f][1]*nr*nc1,
            v2 = acc[f][2]*nr*nc2, v3 = acc[f][3]*nr*nc3;
      if (grow == gcol0    ) v0 = -2.0f;
      if (grow == gcol0 + 1) v1 = -2.0f;
      if (grow == gcol0 + 2) v2 = -2.0f;
      if (grow == gcol0 + 3) v3 = -2.0f;
      unsigned int h0 = f2bf(v0), h1 = f2bf(v1), h2 = f2bf(v2), h3 = f2bf(v3);
      uint2 p; p.x = h0 | (h1 << 16); p.y = h2 | (h3 << 16);
      *(uint2*)&Stile[srow][scol0] = p;
      float rmax = fmaxf(fmaxf(bf2f(h0), bf2f(h1)), fmaxf(bf2f(h2), bf2f(h3)));
      rmax = fmaxf(rmax, __shfl_xor(rmax, 16, 64));   // combine quads
      rmax = fmaxf(rmax, __shfl_xor(rmax, 32, 64));
      if (quad == 0) wmax[w][srow] = rmax;            // strip max for this row
    }
    __syncthreads();                          // Stile/wmax complete
    {
      int r = t >> 3, c8 = t & 7;             // coalesced 32x8 uint4 stores
      *(uint4*)&sim[(size_t)(R0 + r)*N_NODES + tb*64 + c8*8] = *(uint4*)&Stile[r][c8*8];
    }
    if (t < 32){
      float g = fmaxf(fmaxf(wmax[0][t], wmax[1][t]), fmaxf(wmax[2][t], wmax[3][t]));
      gmax[(size_t)(R0 + t)*NTILES + tb] = g;
    }
  }
}

// ---------------------------------------------------------------- tau (48th-largest tile-max) + node_norms (folded)
__global__ __launch_bounds__(256) void taukern(const float* __restrict__ gmax,
    float* __restrict__ tau, const int* __restrict__ nbrcnt,
    const int* __restrict__ colcnt, float* __restrict__ d1inv,
    float* __restrict__ d2inv){
  const int R0 = blockIdx.x * 32, t = threadIdx.x;
  {                                           // folded node_norms
    int i = blockIdx.x*256 + t;
    if (i < N_NODES){
      d1inv[i] = rsqrtf((float)(nbrcnt[i] + 1));
      d2inv[i] = rsqrtf((float)(colcnt[i] + 1));
    }
  }
  __shared__ float tm[32][97];
  for (int e = t; e < 32*NTILES; e += 256){
    int r = e / NTILES, j = e % NTILES;
    tm[r][j] = gmax[(size_t)(R0 + r)*NTILES + j];
  }
  __syncthreads();
  if (t < 32){
    float m = 0.f;
    for (int k = 0; k < KSEL; ++k){           // 48 extraction passes
      m = -3.4e38f; int am = 0;
      for (int j = 0; j < NTILES; ++j){
        float u = tm[t][j];
        if (u > m){ m = u; am = j; }
      }
      tm[t][am] = -3.4e38f;
    }
    tau[R0 + t] = m;                          // 48th largest tile-max (rounded domain)
  }
}

// ---------------------------------------------------------------- refine_scan: scan stored sim row, filter >= tau, exact fp32 top-32
__global__ __launch_bounds__(256) void refine_scan(const float* __restrict__ x,
    const float* __restrict__ xninv, const unsigned short* __restrict__ sim,
    const float* __restrict__ tau, float* __restrict__ tval, int* __restrict__ tidx,
    float* __restrict__ deginv){
  const int i = blockIdx.x, t = threadIdx.x;
  __shared__ float xi[128];
  __shared__ float cv[MAXCAND];
  __shared__ int   ci[MAXCAND];
  __shared__ float sel[KTOP];
  __shared__ int   cnt;
  if (t == 0) cnt = 0;
  if (t < 32) *(float4*)&xi[t*4] = *(const float4*)(x + (size_t)i*FDIM + t*4);
  __syncthreads();
  const float taui = tau[i];
  const uint4* srow = (const uint4*)(sim + (size_t)i*N_NODES);
  for (int v8 = t; v8 < N_NODES/8; v8 += 256){
    uint4 u = srow[v8];
    const unsigned short* h = (const unsigned short*)&u;
#pragma unroll
    for (int q = 0; q < 8; ++q){
      if (bf2f(h[q]) >= taui){                // diag stored as -2 -> never passes
        int s = atomicAdd(&cnt, 1);
        if (s < MAXCAND) ci[s] = v8*8 + q;
      }
    }
  }
  __syncthreads();
  int n = cnt; if (n > MAXCAND) n = MAXCAND;
  const float ni = xninv[i];
  const int part = t & 3, cb = t >> 2;        // 4 lanes per candidate
  for (int c0 = 0; c0 < n; c0 += 64){
    const int c = c0 + cb;
    float acc = 0.f;
    int idx = 0;
    if (c < n){
      idx = ci[c];
      const float* xc = x + (size_t)idx*FDIM + part*32;
#pragma unroll
      for (int q = 0; q < 8; ++q){
        float4 f = *(const float4*)(xc + q*4);
        const float* a = &xi[part*32 + q*4];
        acc += a[0]*f.x + a[1]*f.y + a[2]*f.z + a[3]*f.w;
      }
    }
    acc += __shfl_xor(acc, 1, 64);
    acc += __shfl_xor(acc, 2, 64);
    if (c < n && part == 0) cv[c] = acc * ni * xninv[idx];
  }
  __syncthreads();
  for (int c = t; c < n; c += 256){
    float v = cv[c]; int id = ci[c];
    int rank = 0;
    for (int j = 0; j < n; ++j){
      float u = cv[j];
      if (u > v || (u == v && ci[j] < id)) rank++;   // top_k tie-break: lower index
    }
    if (rank < KTOP){
      tval[(size_t)i*KTOP + rank] = v;
      tidx[(size_t)i*KTOP + rank] = id;
      sel[rank] = v;
    }
  }
  __syncthreads();
  if (t == 0){
    float s = 0.f;
    for (int q = 0; q < KTOP; ++q) s += sel[q];
    deginv[i] = 1.0f / fmaxf(s, 1e-5f);
  }
}

// ---------------------------------------------------------------- fp32 GEMM  C[N x M] = act(A@B + bias)
template<int M>
__global__ __launch_bounds__(256) void gemm_k(const float* __restrict__ A, int lda,
    const float* __restrict__ B, const float* __restrict__ bias,
    float* __restrict__ C, int ldc, int K, int act){
  const int t = threadIdx.x;
  const int R0 = blockIdx.x * 32, C0 = blockIdx.y * 64;
  const int rg = t >> 4, cg = t & 15;
  __shared__ float Alds[32][34];     // [k][r] transposed
  __shared__ float Blds[32][68];
  float4 acc0 = {0,0,0,0}, acc1 = {0,0,0,0};
  for (int kc = 0; kc < K; kc += 32){
    __syncthreads();
    { int r = t >> 3, k0 = (t & 7) * 4;
      float4 f = *(const float4*)(A + (size_t)(R0 + r)*lda + kc + k0);
      Alds[k0+0][r] = f.x; Alds[k0+1][r] = f.y; Alds[k0+2][r] = f.z; Alds[k0+3][r] = f.w; }
#pragma unroll
    for (int e = 0; e < 2; ++e){
      int idx = t + e*256;
      int k = idx >> 4, m4 = idx & 15;
      *(float4*)&Blds[k][m4*4] = *(const float4*)(B + (size_t)(kc + k)*M + C0 + m4*4);
    }
    __syncthreads();
#pragma unroll
    for (int k = 0; k < 32; ++k){
      float2 a = *(const float2*)&Alds[k][rg*2];
      float4 b = *(const float4*)&Blds[k][cg*4];
      acc0.x += a.x*b.x; acc0.y += a.x*b.y; acc0.z += a.x*b.z; acc0.w += a.x*b.w;
      acc1.x += a.y*b.x; acc1.y += a.y*b.y; acc1.z += a.y*b.z; acc1.w += a.y*b.w;
    }
  }
  const int r0 = R0 + rg*2, c0 = C0 + cg*4;
  float4 bb = {0,0,0,0};
  if (bias) bb = *(const float4*)&bias[c0];
  acc0.x += bb.x; acc0.y += bb.y; acc0.z += bb.z; acc0.w += bb.w;
  acc1.x += bb.x; acc1.y += bb.y; acc1.z += bb.z; acc1.w += bb.w;
  if (act){
    acc0.x = elu_f(acc0.x); acc0.y = elu_f(acc0.y); acc0.z = elu_f(acc0.z); acc0.w = elu_f(acc0.w);
    acc1.x = elu_f(acc1.x); acc1.y = elu_f(acc1.y); acc1.z = elu_f(acc1.z); acc1.w = elu_f(acc1.w);
  }
  *(float4*)&C[(size_t)r0*ldc + c0] = acc0;
  *(float4*)&C[(size_t)(r0+1)*ldc + c0] = acc1;
}

// ---------------------------------------------------------------- GCN SpMM
__global__ __launch_bounds__(128) void spmm_gcn(const float* __restrict__ T,
    const int* __restrict__ nbr, const int* __restrict__ nbrcnt,
    const float* __restrict__ d1inv, const float* __restrict__ d2inv,
    float* __restrict__ C, int ldc){
  const int i = blockIdx.x, t = threadIdx.x;
  float acc = T[(size_t)i*FDIM + t] * d2inv[i];     // +I diagonal term
  const int cnt = nbrcnt[i];
  const int* nb = nbr + (size_t)i*MAXNBR;
  for (int s = 0; s < cnt; ++s){
    int j = nb[s];
    acc += T[(size_t)j*FDIM + t] * d2inv[j];
  }
  C[(size_t)i*ldc + t] = elu_f(acc * d1inv[i]);
}

// ---------------------------------------------------------------- SAGE SpMM
__global__ __launch_bounds__(128) void spmm_sage(const float* __restrict__ P,
    const float* __restrict__ tval, const int* __restrict__ tidx,
    const float* __restrict__ deginv, float* __restrict__ C, int ldc){
  const int i = blockIdx.x, t = threadIdx.x;
  float acc = 0.f;
  const float* vv = tval + (size_t)i*KTOP;
  const int*   ii = tidx + (size_t)i*KTOP;
  for (int s = 0; s < KTOP; ++s)
    acc += vv[s] * P[(size_t)ii[s]*FDIM + t];
  C[(size_t)i*ldc + t] = acc * deginv[i];
}

// ---------------------------------------------------------------- edges: logits + per-block partial BCE (no global atomics)
__global__ __launch_bounds__(256) void edge_loss(const int* __restrict__ src,
    const int* __restrict__ dst, const float* __restrict__ labels,
    const float* __restrict__ HP, const float* __restrict__ hcat,
    const float* __restrict__ predB, float* __restrict__ out,
    float* __restrict__ partial){
  const int t = threadIdx.x;
  const int e = blockIdx.x*4 + (t >> 6);
  const int lane = t & 63;
  const int s = src[e], d = dst[e];
  const float* hp = HP   + (size_t)s*256;
  const float* hc = hcat + (size_t)d*256;
  float acc = 0.f;
  for (int k = lane; k < 256; k += 64) acc += hp[k] * hc[k];
  for (int o = 32; o > 0; o >>= 1) acc += __shfl_down(acc, o, 64);
  __shared__ float terms[4];
  if (lane == 0){
    float l = acc + predB[0];
    out[1 + e] = l;
    float y = labels[e];
    terms[t >> 6] = fmaxf(l, 0.f) - l*y + log1pf(expf(-fabsf(l)));
  }
  __syncthreads();
  if (t == 0) partial[blockIdx.x] = terms[0] + terms[1] + terms[2] + terms[3];
}

__global__ __launch_bounds__(256) void reduce_loss(const float* __restrict__ partial,
    float* __restrict__ out){
  const int t = threadIdx.x, lane = t & 63, w = t >> 6;
  float s = 0.f;
  for (int i = t; i < EEDGES/4; i += 256) s += partial[i];
  for (int o = 32; o > 0; o >>= 1) s += __shfl_down(s, o, 64);
  __shared__ float ws[4];
  if (lane == 0) ws[w] = s;
  __syncthreads();
  if (t == 0) out[0] = (ws[0] + ws[1] + ws[2] + ws[3]) * (1.0f / EEDGES);
}

// ---------------------------------------------------------------- launcher
extern "C" void kernel_launch(void* const* d_in, const int* in_sizes, int n_in,
                              void* d_out, int out_size, void* d_ws, size_t ws_size,
                              hipStream_t stream){
  (void)in_sizes; (void)n_in; (void)out_size; (void)ws_size;
  const int*   src    = (const int*)d_in[0];
  const int*   dst    = (const int*)d_in[1];
  const float* labels = (const float*)d_in[2];
  const float* adj    = (const float*)d_in[3];
  const float* x      = (const float*)d_in[4];
  const float* Wg1    = (const float*)d_in[5];
  const float* Wg2    = (const float*)d_in[6];
  const float* Wp1    = (const float*)d_in[7];
  const float* b1     = (const float*)d_in[8];
  const float* Ws1    = (const float*)d_in[9];
  const float* Wp2    = (const float*)d_in[10];
  const float* b2     = (const float*)d_in[11];
  const float* Ws2    = (const float*)d_in[12];
  const float* PredW  = (const float*)d_in[13];
  const float* PredB  = (const float*)d_in[14];

  char* ws = (char*)d_ws;
  size_t off = 0;
  auto alloc = [&](size_t bytes)->void*{
    void* p = ws + off; off += (bytes + 255) & ~(size_t)255; return p; };

  // total ws footprint ~105 MB (ws_size measured 576 MiB via harness 0xAA fill)
  int*   colcnt = (int*)  alloc((size_t)N_NODES*4);
  int*   nbrcnt = (int*)  alloc((size_t)N_NODES*4);
  int*   nbr    = (int*)  alloc((size_t)N_NODES*MAXNBR*4);
  float* d1inv  = (float*)alloc((size_t)N_NODES*4);
  float* d2inv  = (float*)alloc((size_t)N_NODES*4);
  float* xninv  = (float*)alloc((size_t)N_NODES*4);
  unsigned short* xbf = (unsigned short*)alloc((size_t)N_NODES*FDIM*2);
  float* tval   = (float*)alloc((size_t)N_NODES*KTOP*4);
  int*   tidx   = (int*)  alloc((size_t)N_NODES*KTOP*4);
  float* dginv  = (float*)alloc((size_t)N_NODES*4);
  float* gmax   = (float*)alloc((size_t)N_NODES*NTILES*4);
  float* tau    = (float*)alloc((size_t)N_NODES*4);
  float* partial= (float*)alloc((size_t)(EEDGES/4)*4);
  float* T      = (float*)alloc((size_t)N_NODES*FDIM*4);
  float* cat1   = (float*)alloc((size_t)N_NODES*256*4);
  float* cat2   = (float*)alloc((size_t)N_NODES*256*4);
  float* hcat   = (float*)alloc((size_t)N_NODES*256*4);
  unsigned short* sim = (unsigned short*)alloc((size_t)N_NODES*N_NODES*2);
  float* z1     = cat2;          // alias: z1 dead (after Wg2 GEMM) before cat2 first written
  float* out    = (float*)d_out;

  hipMemsetAsync(colcnt, 0, (size_t)N_NODES*4, stream);

  adj_scan   <<<N_NODES, 256, 0, stream>>>(adj, nbr, nbrcnt, colcnt);
  xprep      <<<N_NODES, 128, 0, stream>>>(x, xbf, xninv, cat1);
  simgemm    <<<dim3(N_NODES/32, GRIDY), 256, 0, stream>>>(xbf, xninv, sim, gmax);
  taukern    <<<N_NODES/32, 256, 0, stream>>>(gmax, tau, nbrcnt, colcnt, d1inv, d2inv);
  refine_scan<<<N_NODES, 256, 0, stream>>>(x, xninv, sim, tau, tval, tidx, dginv);

  // GCN branch -> hcat[:, 0:128]
  gemm_k<128><<<dim3(N_NODES/32, 2), 256, 0, stream>>>(x,  FDIM, Wg1, nullptr, T, FDIM, 128, 0);
  spmm_gcn   <<<N_NODES, 128, 0, stream>>>(T, nbr, nbrcnt, d1inv, d2inv, z1, FDIM);
  gemm_k<128><<<dim3(N_NODES/32, 2), 256, 0, stream>>>(z1, FDIM, Wg2, nullptr, T, FDIM, 128, 0);
  spmm_gcn   <<<N_NODES, 128, 0, stream>>>(T, nbr, nbrcnt, d1inv, d2inv, hcat, 256);

  // SAGE layer 1 (cat1[:,0:128] = x, written by xprep)
  gemm_k<128><<<dim3(N_NODES/32, 2), 256, 0, stream>>>(x, FDIM, Wp1, b1, T, FDIM, 128, 1);
  spmm_sage  <<<N_NODES, 128, 0, stream>>>(T, tval, tidx, dginv, cat1 + 128, 256);
  gemm_k<128><<<dim3(N_NODES/32, 2), 256, 0, stream>>>(cat1, 256, Ws1, nullptr, cat2, 256, 256, 1);

  // SAGE layer 2
  gemm_k<128><<<dim3(N_NODES/32, 2), 256, 0, stream>>>(cat2, 256, Wp2, b2, T, FDIM, 128, 1);
  spmm_sage  <<<N_NODES, 128, 0, stream>>>(T, tval, tidx, dginv, cat2 + 128, 256);
  gemm_k<128><<<dim3(N_NODES/32, 2), 256, 0, stream>>>(cat2, 256, Ws2, nullptr, hcat + 128, 256, 256, 1);

  // predictor
  gemm_k<256><<<dim3(N_NODES/32, 4), 256, 0, stream>>>(hcat, 256, PredW, nullptr, cat1, 256, 256, 0);
  edge_loss  <<<EEDGES/4, 256, 0, stream>>>(src, dst, labels, cat1, hcat, PredB, out, partial);
  reduce_loss<<<1, 256, 0, stream>>>(partial, out);
}

// Round 14
// 483.766 us; speedup vs baseline: 3.3817x; 1.1535x over previous
//
#include <hip/hip_runtime.h>
#include <hip/hip_bf16.h>
#include <stdint.h>

#define N_NODES 6144
#define FDIM    128
#define EEDGES  16384
#define KTOP    32
#define KSEL    48
#define MAXNBR  64
#define MAXCAND 512
#define NTILES  96     // N_NODES/64
#define GRIDY   16
#define TPB     (NTILES/GRIDY)   // 6 tiles per block

typedef short bf16x8 __attribute__((ext_vector_type(8)));
typedef float f32x4  __attribute__((ext_vector_type(4)));

__device__ __forceinline__ float elu_f(float x){ return x > 0.f ? x : expm1f(x); }

__device__ __forceinline__ unsigned short f2bf(float f){
  unsigned int u = __float_as_uint(f);
  u += 0x7FFFu + ((u >> 16) & 1u);   // RNE
  return (unsigned short)(u >> 16);
}
__device__ __forceinline__ float bf2f(unsigned short h){
  return __uint_as_float(((unsigned int)h) << 16);
}

// ---------------------------------------------------------------- prep: adj_scan (blocks 0..6143) + xprep x2 rows (blocks 6144..9215)
__global__ __launch_bounds__(256) void prep(const float* __restrict__ adj,
    const float* __restrict__ x, int* __restrict__ nbr, int* __restrict__ nbrcnt,
    int* __restrict__ colcnt, unsigned short* __restrict__ xbf,
    float* __restrict__ xninv, float* __restrict__ cat1){
  const int b = blockIdx.x, t = threadIdx.x;
  if (b < N_NODES){                         // ---- adj_scan row
    const int i = b;
    __shared__ int s_cnt;
    if (t == 0) s_cnt = 0;
    __syncthreads();
    const float4* row = (const float4*)(adj + (size_t)i * N_NODES);
    for (int v = t; v < N_NODES/4; v += 256){
      float4 f = row[v];
      int c = v * 4;
      if (f.x != 0.f){ int s = atomicAdd(&s_cnt,1); if (s < MAXNBR) nbr[i*MAXNBR+s] = c;   atomicAdd(&colcnt[c],1); }
      if (f.y != 0.f){ int s = atomicAdd(&s_cnt,1); if (s < MAXNBR) nbr[i*MAXNBR+s] = c+1; atomicAdd(&colcnt[c+1],1); }
      if (f.z != 0.f){ int s = atomicAdd(&s_cnt,1); if (s < MAXNBR) nbr[i*MAXNBR+s] = c+2; atomicAdd(&colcnt[c+2],1); }
      if (f.w != 0.f){ int s = atomicAdd(&s_cnt,1); if (s < MAXNBR) nbr[i*MAXNBR+s] = c+3; atomicAdd(&colcnt[c+3],1); }
    }
    __syncthreads();
    if (t == 0) nbrcnt[i] = min(s_cnt, MAXNBR);
  } else {                                  // ---- xprep, 2 rows per block
    const int i = (b - N_NODES)*2 + (t >> 7);
    const int tl = t & 127;
    float v = x[(size_t)i*FDIM + tl];
    xbf[(size_t)i*FDIM + tl] = f2bf(v);
    cat1[(size_t)i*256 + tl] = v;           // folded copy128
    float s = v * v;
    for (int o = 32; o > 0; o >>= 1) s += __shfl_down(s, o, 64);
    __shared__ float ws[4];
    if ((t & 63) == 0) ws[t >> 6] = s;
    __syncthreads();
    if (tl == 0) xninv[i] = rsqrtf(ws[(t>>7)*2] + ws[(t>>7)*2 + 1]);
  }
}

// ---------------------------------------------------------------- simgemm: bf16 cosine tiles -> sim (stored) + per-tile row maxes
// grid (192, 16): 32 rows x 6 tiles of 64 cols per block. Operand-swapped
// MFMA: each lane holds 4 consecutive cols of ONE row.
__global__ __launch_bounds__(256) void simgemm(const unsigned short* __restrict__ xbf,
    const float* __restrict__ xninv, unsigned short* __restrict__ sim,
    float* __restrict__ gmax){
  const int t    = threadIdx.x;
  const int R0   = blockIdx.x * 32;
  const int tb0  = blockIdx.y * TPB;
  const int lane = t & 63, w = t >> 6;
  const int lr   = lane & 15, q8 = (lane >> 4) * 8, quad = lane >> 4;

  __shared__ unsigned short Abf[32][136];
  __shared__ unsigned short Bbf[64][136];
  __shared__ unsigned short Stile[32][72];
  __shared__ float nrow[32];
  __shared__ float ncol[64];
  __shared__ float wmax[4][32];

  for (int e = t; e < 32*16; e += 256){
    int r = e >> 4, c8 = e & 15;
    *(uint4*)&Abf[r][c8*8] = ((const uint4*)(xbf + (size_t)(R0 + r)*FDIM))[c8];
  }
  if (t < 32) nrow[t] = xninv[R0 + t];

  for (int tb = tb0; tb < tb0 + TPB; ++tb){
    __syncthreads();
    for (int e = t; e < 64*16; e += 256){
      int r = e >> 4, c8 = e & 15;
      *(uint4*)&Bbf[r][c8*8] = ((const uint4*)(xbf + (size_t)(tb*64 + r)*FDIM))[c8];
    }
    if (t < 64) ncol[t] = xninv[tb*64 + t];
    __syncthreads();

    f32x4 acc[2] = {};
#pragma unroll
    for (int kb = 0; kb < 4; ++kb){
      bf16x8 bcol  = *(const bf16x8*)&Bbf[w*16 + lr][kb*32 + q8];
      bf16x8 arow0 = *(const bf16x8*)&Abf[lr      ][kb*32 + q8];
      bf16x8 arow1 = *(const bf16x8*)&Abf[16 + lr ][kb*32 + q8];
      acc[0] = __builtin_amdgcn_mfma_f32_16x16x32_bf16(bcol, arow0, acc[0], 0, 0, 0);
      acc[1] = __builtin_amdgcn_mfma_f32_16x16x32_bf16(bcol, arow1, acc[1], 0, 0, 0);
    }
    const int scol0 = w*16 + quad*4;
    const float nc0 = ncol[scol0], nc1 = ncol[scol0+1],
                nc2 = ncol[scol0+2], nc3 = ncol[scol0+3];
#pragma unroll
    for (int f = 0; f < 2; ++f){
      const int srow = f*16 + lr;
      const float nr = nrow[srow];
      const int grow = R0 + srow, gcol0 = tb*64 + scol0;
      float v0 = acc[f][0]*nr*nc0, v1 = acc[f][1]*nr*nc1,
            v2 = acc[f][2]*nr*nc2, v3 = acc[f][3]*nr*nc3;
      if (grow == gcol0    ) v0 = -2.0f;
      if (grow == gcol0 + 1) v1 = -2.0f;
      if (grow == gcol0 + 2) v2 = -2.0f;
      if (grow == gcol0 + 3) v3 = -2.0f;
      unsigned int h0 = f2bf(v0), h1 = f2bf(v1), h2 = f2bf(v2), h3 = f2bf(v3);
      uint2 p; p.x = h0 | (h1 << 16); p.y = h2 | (h3 << 16);
      *(uint2*)&Stile[srow][scol0] = p;
      float rmax = fmaxf(fmaxf(bf2f(h0), bf2f(h1)), fmaxf(bf2f(h2), bf2f(h3)));
      rmax = fmaxf(rmax, __shfl_xor(rmax, 16, 64));
      rmax = fmaxf(rmax, __shfl_xor(rmax, 32, 64));
      if (quad == 0) wmax[w][srow] = rmax;
    }
    __syncthreads();
    {
      int r = t >> 3, c8 = t & 7;
      *(uint4*)&sim[(size_t)(R0 + r)*N_NODES + tb*64 + c8*8] = *(uint4*)&Stile[r][c8*8];
    }
    if (t < 32){
      float g = fmaxf(fmaxf(wmax[0][t], wmax[1][t]), fmaxf(wmax[2][t], wmax[3][t]));
      gmax[(size_t)(R0 + t)*NTILES + tb] = g;
    }
  }
}

// ---------------------------------------------------------------- refine_scan: inline tau + scan sim row + exact fp32 top-32
__global__ __launch_bounds__(256) void refine_scan(const float* __restrict__ x,
    const float* __restrict__ xninv, const unsigned short* __restrict__ sim,
    const float* __restrict__ gmax, float* __restrict__ tval, int* __restrict__ tidx,
    float* __restrict__ deginv){
  const int i = blockIdx.x, t = threadIdx.x;
  __shared__ float xi[128];
  __shared__ float gm[NTILES];
  __shared__ float tauv;
  __shared__ float cv[MAXCAND];
  __shared__ int   ci[MAXCAND];
  __shared__ float sel[KTOP];
  __shared__ int   cnt;
  if (t == 0) cnt = 0;
  if (t < 32) *(float4*)&xi[t*4] = *(const float4*)(x + (size_t)i*FDIM + t*4);
  if (t < NTILES) gm[t] = gmax[(size_t)i*NTILES + t];
  __syncthreads();
  if (t < NTILES){                          // rank-select 48th-largest tile-max
    float v = gm[t]; int rank = 0;
    for (int j = 0; j < NTILES; ++j){
      float u = gm[j];
      if (u > v || (u == v && j < t)) rank++;
    }
    if (rank == KSEL-1) tauv = v;
  }
  __syncthreads();
  const float taui = tauv;
  const uint4* srow = (const uint4*)(sim + (size_t)i*N_NODES);
  for (int v8 = t; v8 < N_NODES/8; v8 += 256){
    uint4 u = srow[v8];
    const unsigned short* h = (const unsigned short*)&u;
#pragma unroll
    for (int q = 0; q < 8; ++q){
      if (bf2f(h[q]) >= taui){              // diag stored as -2 -> never passes
        int s = atomicAdd(&cnt, 1);
        if (s < MAXCAND) ci[s] = v8*8 + q;
      }
    }
  }
  __syncthreads();
  int n = cnt; if (n > MAXCAND) n = MAXCAND;
  const float ni = xninv[i];
  const int part = t & 3, cb = t >> 2;      // 4 lanes per candidate
  for (int c0 = 0; c0 < n; c0 += 64){
    const int c = c0 + cb;
    float acc = 0.f;
    int idx = 0;
    if (c < n){
      idx = ci[c];
      const float* xc = x + (size_t)idx*FDIM + part*32;
#pragma unroll
      for (int q = 0; q < 8; ++q){
        float4 f = *(const float4*)(xc + q*4);
        const float* a = &xi[part*32 + q*4];
        acc += a[0]*f.x + a[1]*f.y + a[2]*f.z + a[3]*f.w;
      }
    }
    acc += __shfl_xor(acc, 1, 64);
    acc += __shfl_xor(acc, 2, 64);
    if (c < n && part == 0) cv[c] = acc * ni * xninv[idx];
  }
  __syncthreads();
  for (int c = t; c < n; c += 256){
    float v = cv[c]; int id = ci[c];
    int rank = 0;
    for (int j = 0; j < n; ++j){
      float u = cv[j];
      if (u > v || (u == v && ci[j] < id)) rank++;   // top_k tie-break: lower index
    }
    if (rank < KTOP){
      tval[(size_t)i*KTOP + rank] = v;
      tidx[(size_t)i*KTOP + rank] = id;
      sel[rank] = v;
    }
  }
  __syncthreads();
  if (t == 0){
    float s = 0.f;
    for (int q = 0; q < KTOP; ++q) s += sel[q];
    deginv[i] = 1.0f / fmaxf(s, 1e-5f);
  }
}

// ---------------------------------------------------------------- dual GEMM: T1 = x@Wg1, T2 = elu(x@Wp1 + b1); + node_norms fold
__global__ __launch_bounds__(256) void gemm_dual(const float* __restrict__ A,
    const float* __restrict__ B1, const float* __restrict__ B2,
    const float* __restrict__ bias2, float* __restrict__ C1, float* __restrict__ C2,
    const int* __restrict__ nbrcnt, const int* __restrict__ colcnt,
    float* __restrict__ d1inv, float* __restrict__ d2inv){
  const int t = threadIdx.x;
  const int R0 = blockIdx.x * 32, C0 = blockIdx.y * 64;
  if (blockIdx.y == 0 && t < 32){           // folded node_norms (192*32 = 6144)
    int i = R0 + t;
    d1inv[i] = rsqrtf((float)(nbrcnt[i] + 1));
    d2inv[i] = rsqrtf((float)(colcnt[i] + 1));
  }
  const int rg = t >> 4, cg = t & 15;
  __shared__ float Alds[32][34];
  __shared__ float B1lds[32][68];
  __shared__ float B2lds[32][68];
  float4 p0 = {0,0,0,0}, p1 = {0,0,0,0};    // B1 accs
  float4 q0 = {0,0,0,0}, q1 = {0,0,0,0};    // B2 accs
  for (int kc = 0; kc < FDIM; kc += 32){
    __syncthreads();
    { int r = t >> 3, k0 = (t & 7) * 4;
      float4 f = *(const float4*)(A + (size_t)(R0 + r)*FDIM + kc + k0);
      Alds[k0+0][r] = f.x; Alds[k0+1][r] = f.y; Alds[k0+2][r] = f.z; Alds[k0+3][r] = f.w; }
#pragma unroll
    for (int e = 0; e < 2; ++e){
      int idx = t + e*256;
      int k = idx >> 4, m4 = idx & 15;
      *(float4*)&B1lds[k][m4*4] = *(const float4*)(B1 + (size_t)(kc + k)*FDIM + C0 + m4*4);
      *(float4*)&B2lds[k][m4*4] = *(const float4*)(B2 + (size_t)(kc + k)*FDIM + C0 + m4*4);
    }
    __syncthreads();
#pragma unroll
    for (int k = 0; k < 32; ++k){
      float2 a = *(const float2*)&Alds[k][rg*2];
      float4 b = *(const float4*)&B1lds[k][cg*4];
      float4 c = *(const float4*)&B2lds[k][cg*4];
      p0.x += a.x*b.x; p0.y += a.x*b.y; p0.z += a.x*b.z; p0.w += a.x*b.w;
      p1.x += a.y*b.x; p1.y += a.y*b.y; p1.z += a.y*b.z; p1.w += a.y*b.w;
      q0.x += a.x*c.x; q0.y += a.x*c.y; q0.z += a.x*c.z; q0.w += a.x*c.w;
      q1.x += a.y*c.x; q1.y += a.y*c.y; q1.z += a.y*c.z; q1.w += a.y*c.w;
    }
  }
  const int r0 = R0 + rg*2, c0 = C0 + cg*4;
  *(float4*)&C1[(size_t)r0*FDIM + c0] = p0;
  *(float4*)&C1[(size_t)(r0+1)*FDIM + c0] = p1;
  float4 bb = *(const float4*)&bias2[c0];
  q0.x = elu_f(q0.x + bb.x); q0.y = elu_f(q0.y + bb.y); q0.z = elu_f(q0.z + bb.z); q0.w = elu_f(q0.w + bb.w);
  q1.x = elu_f(q1.x + bb.x); q1.y = elu_f(q1.y + bb.y); q1.z = elu_f(q1.z + bb.z); q1.w = elu_f(q1.w + bb.w);
  *(float4*)&C2[(size_t)r0*FDIM + c0] = q0;
  *(float4*)&C2[(size_t)(r0+1)*FDIM + c0] = q1;
}

// ---------------------------------------------------------------- fp32 GEMM  C[N x M] = act(A@B + bias)
template<int M>
__global__ __launch_bounds__(256) void gemm_k(const float* __restrict__ A, int lda,
    const float* __restrict__ B, const float* __restrict__ bias,
    float* __restrict__ C, int ldc, int K, int act){
  const int t = threadIdx.x;
  const int R0 = blockIdx.x * 32, C0 = blockIdx.y * 64;
  const int rg = t >> 4, cg = t & 15;
  __shared__ float Alds[32][34];
  __shared__ float Blds[32][68];
  float4 acc0 = {0,0,0,0}, acc1 = {0,0,0,0};
  for (int kc = 0; kc < K; kc += 32){
    __syncthreads();
    { int r = t >> 3, k0 = (t & 7) * 4;
      float4 f = *(const float4*)(A + (size_t)(R0 + r)*lda + kc + k0);
      Alds[k0+0][r] = f.x; Alds[k0+1][r] = f.y; Alds[k0+2][r] = f.z; Alds[k0+3][r] = f.w; }
#pragma unroll
    for (int e = 0; e < 2; ++e){
      int idx = t + e*256;
      int k = idx >> 4, m4 = idx & 15;
      *(float4*)&Blds[k][m4*4] = *(const float4*)(B + (size_t)(kc + k)*M + C0 + m4*4);
    }
    __syncthreads();
#pragma unroll
    for (int k = 0; k < 32; ++k){
      float2 a = *(const float2*)&Alds[k][rg*2];
      float4 b = *(const float4*)&Blds[k][cg*4];
      acc0.x += a.x*b.x; acc0.y += a.x*b.y; acc0.z += a.x*b.z; acc0.w += a.x*b.w;
      acc1.x += a.y*b.x; acc1.y += a.y*b.y; acc1.z += a.y*b.z; acc1.w += a.y*b.w;
    }
  }
  const int r0 = R0 + rg*2, c0 = C0 + cg*4;
  float4 bb = {0,0,0,0};
  if (bias) bb = *(const float4*)&bias[c0];
  acc0.x += bb.x; acc0.y += bb.y; acc0.z += bb.z; acc0.w += bb.w;
  acc1.x += bb.x; acc1.y += bb.y; acc1.z += bb.z; acc1.w += bb.w;
  if (act){
    acc0.x = elu_f(acc0.x); acc0.y = elu_f(acc0.y); acc0.z = elu_f(acc0.z); acc0.w = elu_f(acc0.w);
    acc1.x = elu_f(acc1.x); acc1.y = elu_f(acc1.y); acc1.z = elu_f(acc1.z); acc1.w = elu_f(acc1.w);
  }
  *(float4*)&C[(size_t)r0*ldc + c0] = acc0;
  *(float4*)&C[(size_t)(r0+1)*ldc + c0] = acc1;
}

// ---------------------------------------------------------------- GCN SpMM
__global__ __launch_bounds__(128) void spmm_gcn(const float* __restrict__ T,
    const int* __restrict__ nbr, const int* __restrict__ nbrcnt,
    const float* __restrict__ d1inv, const float* __restrict__ d2inv,
    float* __restrict__ C, int ldc){
  const int i = blockIdx.x, t = threadIdx.x;
  float acc = T[(size_t)i*FDIM + t] * d2inv[i];
  const int cnt = nbrcnt[i];
  const int* nb = nbr + (size_t)i*MAXNBR;
  for (int s = 0; s < cnt; ++s){
    int j = nb[s];
    acc += T[(size_t)j*FDIM + t] * d2inv[j];
  }
  C[(size_t)i*ldc + t] = elu_f(acc * d1inv[i]);
}

// ---------------------------------------------------------------- SAGE SpMM
__global__ __launch_bounds__(128) void spmm_sage(const float* __restrict__ P,
    const float* __restrict__ tval, const int* __restrict__ tidx,
    const float* __restrict__ deginv, float* __restrict__ C, int ldc){
  const int i = blockIdx.x, t = threadIdx.x;
  float acc = 0.f;
  const float* vv = tval + (size_t)i*KTOP;
  const int*   ii = tidx + (size_t)i*KTOP;
  for (int s = 0; s < KTOP; ++s)
    acc += vv[s] * P[(size_t)ii[s]*FDIM + t];
  C[(size_t)i*ldc + t] = acc * deginv[i];
}

// ---------------------------------------------------------------- spmm_pair: gcn layer-1 (blocks 0..6143) + sage layer-1 (6144..12287)
__global__ __launch_bounds__(128) void spmm_pair(const float* __restrict__ T1,
    const int* __restrict__ nbr, const int* __restrict__ nbrcnt,
    const float* __restrict__ d1inv, const float* __restrict__ d2inv,
    float* __restrict__ z1,
    const float* __restrict__ T2, const float* __restrict__ tval,
    const int* __restrict__ tidx, const float* __restrict__ deginv,
    float* __restrict__ cat1r){
  const int b = blockIdx.x, t = threadIdx.x;
  if (b < N_NODES){
    const int i = b;
    float acc = T1[(size_t)i*FDIM + t] * d2inv[i];
    const int cnt = nbrcnt[i];
    const int* nb = nbr + (size_t)i*MAXNBR;
    for (int s = 0; s < cnt; ++s){
      int j = nb[s];
      acc += T1[(size_t)j*FDIM + t] * d2inv[j];
    }
    z1[(size_t)i*FDIM + t] = elu_f(acc * d1inv[i]);
  } else {
    const int i = b - N_NODES;
    float acc = 0.f;
    const float* vv = tval + (size_t)i*KTOP;
    const int*   ii = tidx + (size_t)i*KTOP;
    for (int s = 0; s < KTOP; ++s)
      acc += vv[s] * T2[(size_t)ii[s]*FDIM + t];
    cat1r[(size_t)i*256 + t] = acc * deginv[i];
  }
}

// ---------------------------------------------------------------- edges: logits + per-block partial BCE (no global atomics)
__global__ __launch_bounds__(256) void edge_loss(const int* __restrict__ src,
    const int* __restrict__ dst, const float* __restrict__ labels,
    const float* __restrict__ HP, const float* __restrict__ hcat,
    const float* __restrict__ predB, float* __restrict__ out,
    float* __restrict__ partial){
  const int t = threadIdx.x;
  const int e = blockIdx.x*4 + (t >> 6);
  const int lane = t & 63;
  const int s = src[e], d = dst[e];
  const float* hp = HP   + (size_t)s*256;
  const float* hc = hcat + (size_t)d*256;
  float acc = 0.f;
  for (int k = lane; k < 256; k += 64) acc += hp[k] * hc[k];
  for (int o = 32; o > 0; o >>= 1) acc += __shfl_down(acc, o, 64);
  __shared__ float terms[4];
  if (lane == 0){
    float l = acc + predB[0];
    out[1 + e] = l;
    float y = labels[e];
    terms[t >> 6] = fmaxf(l, 0.f) - l*y + log1pf(expf(-fabsf(l)));
  }
  __syncthreads();
  if (t == 0) partial[blockIdx.x] = terms[0] + terms[1] + terms[2] + terms[3];
}

__global__ __launch_bounds__(256) void reduce_loss(const float* __restrict__ partial,
    float* __restrict__ out){
  const int t = threadIdx.x, lane = t & 63, w = t >> 6;
  float s = 0.f;
  for (int i = t; i < EEDGES/4; i += 256) s += partial[i];
  for (int o = 32; o > 0; o >>= 1) s += __shfl_down(s, o, 64);
  __shared__ float ws[4];
  if (lane == 0) ws[w] = s;
  __syncthreads();
  if (t == 0) out[0] = (ws[0] + ws[1] + ws[2] + ws[3]) * (1.0f / EEDGES);
}

// ---------------------------------------------------------------- launcher
extern "C" void kernel_launch(void* const* d_in, const int* in_sizes, int n_in,
                              void* d_out, int out_size, void* d_ws, size_t ws_size,
                              hipStream_t stream){
  (void)in_sizes; (void)n_in; (void)out_size; (void)ws_size;
  const int*   src    = (const int*)d_in[0];
  const int*   dst    = (const int*)d_in[1];
  const float* labels = (const float*)d_in[2];
  const float* adj    = (const float*)d_in[3];
  const float* x      = (const float*)d_in[4];
  const float* Wg1    = (const float*)d_in[5];
  const float* Wg2    = (const float*)d_in[6];
  const float* Wp1    = (const float*)d_in[7];
  const float* b1     = (const float*)d_in[8];
  const float* Ws1    = (const float*)d_in[9];
  const float* Wp2    = (const float*)d_in[10];
  const float* b2     = (const float*)d_in[11];
  const float* Ws2    = (const float*)d_in[12];
  const float* PredW  = (const float*)d_in[13];
  const float* PredB  = (const float*)d_in[14];

  char* ws = (char*)d_ws;
  size_t off = 0;
  auto alloc = [&](size_t bytes)->void*{
    void* p = ws + off; off += (bytes + 255) & ~(size_t)255; return p; };

  // total ws footprint ~105 MB (ws_size measured 576 MiB via harness 0xAA fill)
  int*   colcnt = (int*)  alloc((size_t)N_NODES*4);
  int*   nbrcnt = (int*)  alloc((size_t)N_NODES*4);
  int*   nbr    = (int*)  alloc((size_t)N_NODES*MAXNBR*4);
  float* d1inv  = (float*)alloc((size_t)N_NODES*4);
  float* d2inv  = (float*)alloc((size_t)N_NODES*4);
  float* xninv  = (float*)alloc((size_t)N_NODES*4);
  unsigned short* xbf = (unsigned short*)alloc((size_t)N_NODES*FDIM*2);
  float* tval   = (float*)alloc((size_t)N_NODES*KTOP*4);
  int*   tidx   = (int*)  alloc((size_t)N_NODES*KTOP*4);
  float* dginv  = (float*)alloc((size_t)N_NODES*4);
  float* gmax   = (float*)alloc((size_t)N_NODES*NTILES*4);
  float* partial= (float*)alloc((size_t)(EEDGES/4)*4);
  float* T1     = (float*)alloc((size_t)N_NODES*FDIM*4);
  float* T2     = (float*)alloc((size_t)N_NODES*FDIM*4);
  float* cat1   = (float*)alloc((size_t)N_NODES*256*4);
  float* cat2   = (float*)alloc((size_t)N_NODES*256*4);
  float* hcat   = (float*)alloc((size_t)N_NODES*256*4);
  unsigned short* sim = (unsigned short*)alloc((size_t)N_NODES*N_NODES*2);
  float* z1     = cat2;          // alias: z1 dead (after Wg2 GEMM) before cat2 first written
  float* out    = (float*)d_out;

  hipMemsetAsync(colcnt, 0, (size_t)N_NODES*4, stream);

  prep       <<<N_NODES + N_NODES/2, 256, 0, stream>>>(adj, x, nbr, nbrcnt, colcnt, xbf, xninv, cat1);
  simgemm    <<<dim3(N_NODES/32, GRIDY), 256, 0, stream>>>(xbf, xninv, sim, gmax);
  refine_scan<<<N_NODES, 256, 0, stream>>>(x, xninv, sim, gmax, tval, tidx, dginv);

  // T1 = x@Wg1, T2 = elu(x@Wp1+b1); node_norms folded
  gemm_dual  <<<dim3(N_NODES/32, 2), 256, 0, stream>>>(x, Wg1, Wp1, b1, T1, T2,
                                                       nbrcnt, colcnt, d1inv, d2inv);
  // GCN layer-1 spmm + SAGE layer-1 spmm in one launch
  spmm_pair  <<<2*N_NODES, 128, 0, stream>>>(T1, nbr, nbrcnt, d1inv, d2inv, z1,
                                             T2, tval, tidx, dginv, cat1 + 128);

  // GCN layer 2 -> hcat[:,0:128]
  gemm_k<128><<<dim3(N_NODES/32, 2), 256, 0, stream>>>(z1, FDIM, Wg2, nullptr, T1, FDIM, 128, 0);
  spmm_gcn   <<<N_NODES, 128, 0, stream>>>(T1, nbr, nbrcnt, d1inv, d2inv, hcat, 256);

  // SAGE layer 1 combine: cat2[:,0:128] = elu(cat1@Ws1)
  gemm_k<128><<<dim3(N_NODES/32, 2), 256, 0, stream>>>(cat1, 256, Ws1, nullptr, cat2, 256, 256, 1);

  // SAGE layer 2
  gemm_k<128><<<dim3(N_NODES/32, 2), 256, 0, stream>>>(cat2, 256, Wp2, b2, T1, FDIM, 128, 1);
  spmm_sage  <<<N_NODES, 128, 0, stream>>>(T1, tval, tidx, dginv, cat2 + 128, 256);
  gemm_k<128><<<dim3(N_NODES/32, 2), 256, 0, stream>>>(cat2, 256, Ws2, nullptr, hcat + 128, 256, 256, 1);

  // predictor
  gemm_k<256><<<dim3(N_NODES/32, 4), 256, 0, stream>>>(hcat, 256, PredW, nullptr, cat1, 256, 256, 0);
  edge_loss  <<<EEDGES/4, 256, 0, stream>>>(src, dst, labels, cat1, hcat, PredB, out, partial);
  reduce_loss<<<1, 256, 0, stream>>>(partial, out);
}

// Round 15
// 471.155 us; speedup vs baseline: 3.4722x; 1.0268x over previous
//
#include <hip/hip_runtime.h>
#include <hip/hip_bf16.h>
#include <stdint.h>

#define N_NODES 6144
#define FDIM    128
#define EEDGES  16384
#define KTOP    32
#define KSEL    48
#define MAXNBR  64
#define MAXCAND 512
#define NTILES  96     // N_NODES/64
#define GRIDY   16
#define TPB     (NTILES/GRIDY)   // 6 tiles per block

typedef short bf16x8 __attribute__((ext_vector_type(8)));
typedef float f32x4  __attribute__((ext_vector_type(4)));

__device__ __forceinline__ float elu_f(float x){ return x > 0.f ? x : expm1f(x); }

__device__ __forceinline__ unsigned short f2bf(float f){
  unsigned int u = __float_as_uint(f);
  u += 0x7FFFu + ((u >> 16) & 1u);   // RNE
  return (unsigned short)(u >> 16);
}
__device__ __forceinline__ float bf2f(unsigned short h){
  return __uint_as_float(((unsigned int)h) << 16);
}

// ---------------------------------------------------------------- prep: adj_scan (blocks 0..6143) + xprep x2 rows (6144..9215)
__global__ __launch_bounds__(256) void prep(const float* __restrict__ adj,
    const float* __restrict__ x, int* __restrict__ nbr, int* __restrict__ nbrcnt,
    int* __restrict__ colcnt, unsigned short* __restrict__ xbf,
    float* __restrict__ xninv, float* __restrict__ cat1){
  const int b = blockIdx.x, t = threadIdx.x;
  if (b < N_NODES){                         // ---- adj_scan row
    const int i = b;
    __shared__ int s_cnt;
    if (t == 0) s_cnt = 0;
    __syncthreads();
    const float4* row = (const float4*)(adj + (size_t)i * N_NODES);
    for (int v = t; v < N_NODES/4; v += 256){
      float4 f = row[v];
      int c = v * 4;
      if (f.x != 0.f){ int s = atomicAdd(&s_cnt,1); if (s < MAXNBR) nbr[i*MAXNBR+s] = c;   atomicAdd(&colcnt[c],1); }
      if (f.y != 0.f){ int s = atomicAdd(&s_cnt,1); if (s < MAXNBR) nbr[i*MAXNBR+s] = c+1; atomicAdd(&colcnt[c+1],1); }
      if (f.z != 0.f){ int s = atomicAdd(&s_cnt,1); if (s < MAXNBR) nbr[i*MAXNBR+s] = c+2; atomicAdd(&colcnt[c+2],1); }
      if (f.w != 0.f){ int s = atomicAdd(&s_cnt,1); if (s < MAXNBR) nbr[i*MAXNBR+s] = c+3; atomicAdd(&colcnt[c+3],1); }
    }
    __syncthreads();
    if (t == 0) nbrcnt[i] = min(s_cnt, MAXNBR);
  } else {                                  // ---- xprep, 2 rows per block
    const int i = (b - N_NODES)*2 + (t >> 7);
    const int tl = t & 127;
    float v = x[(size_t)i*FDIM + tl];
    xbf[(size_t)i*FDIM + tl] = f2bf(v);
    cat1[(size_t)i*256 + tl] = v;           // folded copy128
    float s = v * v;
    for (int o = 32; o > 0; o >>= 1) s += __shfl_down(s, o, 64);
    __shared__ float ws[4];
    if ((t & 63) == 0) ws[t >> 6] = s;
    __syncthreads();
    if (tl == 0) xninv[i] = rsqrtf(ws[(t>>7)*2] + ws[(t>>7)*2 + 1]);
  }
}

// ---------------------------------------------------------------- simgemm: 64 rows x 6 tiles of 64 cols per block, grid (96,16)
// Operand-swapped MFMA: each lane holds 4 consecutive cols of ONE row.
__global__ __launch_bounds__(256) void simgemm(const unsigned short* __restrict__ xbf,
    const float* __restrict__ xninv, unsigned short* __restrict__ sim,
    float* __restrict__ gmax){
  const int t    = threadIdx.x;
  const int R0   = blockIdx.x * 64;
  const int tb0  = blockIdx.y * TPB;
  const int lane = t & 63, w = t >> 6;
  const int lr   = lane & 15, q8 = (lane >> 4) * 8, quad = lane >> 4;

  __shared__ unsigned short Abf[64][136];
  __shared__ unsigned short Bbf[64][136];
  __shared__ unsigned short Stile[64][72];
  __shared__ float nrow[64];
  __shared__ float ncol[64];
  __shared__ float wmax[4][64];

  for (int e = t; e < 64*16; e += 256){
    int r = e >> 4, c8 = e & 15;
    *(uint4*)&Abf[r][c8*8] = ((const uint4*)(xbf + (size_t)(R0 + r)*FDIM))[c8];
  }
  if (t < 64) nrow[t] = xninv[R0 + t];

  for (int tb = tb0; tb < tb0 + TPB; ++tb){
    __syncthreads();
    for (int e = t; e < 64*16; e += 256){
      int r = e >> 4, c8 = e & 15;
      *(uint4*)&Bbf[r][c8*8] = ((const uint4*)(xbf + (size_t)(tb*64 + r)*FDIM))[c8];
    }
    if (t < 64) ncol[t] = xninv[tb*64 + t];
    __syncthreads();

    f32x4 acc[4] = {};
#pragma unroll
    for (int kb = 0; kb < 4; ++kb){
      bf16x8 bcol = *(const bf16x8*)&Bbf[w*16 + lr][kb*32 + q8];
#pragma unroll
      for (int f = 0; f < 4; ++f){
        bf16x8 arow = *(const bf16x8*)&Abf[f*16 + lr][kb*32 + q8];
        acc[f] = __builtin_amdgcn_mfma_f32_16x16x32_bf16(bcol, arow, acc[f], 0, 0, 0);
      }
    }
    const int scol0 = w*16 + quad*4;
    const float nc0 = ncol[scol0], nc1 = ncol[scol0+1],
                nc2 = ncol[scol0+2], nc3 = ncol[scol0+3];
#pragma unroll
    for (int f = 0; f < 4; ++f){
      const int srow = f*16 + lr;
      const float nr = nrow[srow];
      const int grow = R0 + srow, gcol0 = tb*64 + scol0;
      float v0 = acc[f][0]*nr*nc0, v1 = acc[f][1]*nr*nc1,
            v2 = acc[f][2]*nr*nc2, v3 = acc[f][3]*nr*nc3;
      if (grow == gcol0    ) v0 = -2.0f;
      if (grow == gcol0 + 1) v1 = -2.0f;
      if (grow == gcol0 + 2) v2 = -2.0f;
      if (grow == gcol0 + 3) v3 = -2.0f;
      unsigned int h0 = f2bf(v0), h1 = f2bf(v1), h2 = f2bf(v2), h3 = f2bf(v3);
      uint2 p; p.x = h0 | (h1 << 16); p.y = h2 | (h3 << 16);
      *(uint2*)&Stile[srow][scol0] = p;
      float rmax = fmaxf(fmaxf(bf2f(h0), bf2f(h1)), fmaxf(bf2f(h2), bf2f(h3)));
      rmax = fmaxf(rmax, __shfl_xor(rmax, 16, 64));
      rmax = fmaxf(rmax, __shfl_xor(rmax, 32, 64));
      if (quad == 0) wmax[w][srow] = rmax;
    }
    __syncthreads();
#pragma unroll
    for (int e0 = 0; e0 < 2; ++e0){
      int e = t + e0*256;
      int r = e >> 3, c8 = e & 7;
      *(uint4*)&sim[(size_t)(R0 + r)*N_NODES + tb*64 + c8*8] = *(uint4*)&Stile[r][c8*8];
    }
    if (t < 64){
      float g = fmaxf(fmaxf(wmax[0][t], wmax[1][t]), fmaxf(wmax[2][t], wmax[3][t]));
      gmax[(size_t)(R0 + t)*NTILES + tb] = g;
    }
  }
}

// ---------------------------------------------------------------- refine_scan: inline tau + scan sim row + exact fp32 top-32
__global__ __launch_bounds__(256) void refine_scan(const float* __restrict__ x,
    const float* __restrict__ xninv, const unsigned short* __restrict__ sim,
    const float* __restrict__ gmax, float* __restrict__ tval, int* __restrict__ tidx,
    float* __restrict__ deginv){
  const int i = blockIdx.x, t = threadIdx.x;
  __shared__ float xi[128];
  __shared__ float gm[NTILES];
  __shared__ float tauv;
  __shared__ float cv[MAXCAND];
  __shared__ int   ci[MAXCAND];
  __shared__ float sel[KTOP];
  __shared__ int   cnt;
  if (t == 0) cnt = 0;
  if (t < 32) *(float4*)&xi[t*4] = *(const float4*)(x + (size_t)i*FDIM + t*4);
  if (t < NTILES) gm[t] = gmax[(size_t)i*NTILES + t];
  __syncthreads();
  if (t < NTILES){                          // rank-select 48th-largest tile-max
    float v = gm[t]; int rank = 0;
    for (int j = 0; j < NTILES; ++j){
      float u = gm[j];
      if (u > v || (u == v && j < t)) rank++;
    }
    if (rank == KSEL-1) tauv = v;
  }
  __syncthreads();
  const float taui = tauv;
  const uint4* srow = (const uint4*)(sim + (size_t)i*N_NODES);
  for (int v8 = t; v8 < N_NODES/8; v8 += 256){
    uint4 u = srow[v8];
    const unsigned short* h = (const unsigned short*)&u;
#pragma unroll
    for (int q = 0; q < 8; ++q){
      if (bf2f(h[q]) >= taui){              // diag stored as -2 -> never passes
        int s = atomicAdd(&cnt, 1);
        if (s < MAXCAND) ci[s] = v8*8 + q;
      }
    }
  }
  __syncthreads();
  int n = cnt; if (n > MAXCAND) n = MAXCAND;
  const float ni = xninv[i];
  const int part = t & 3, cb = t >> 2;      // 4 lanes per candidate
  for (int c0 = 0; c0 < n; c0 += 64){
    const int c = c0 + cb;
    float acc = 0.f;
    int idx = 0;
    if (c < n){
      idx = ci[c];
      const float* xc = x + (size_t)idx*FDIM + part*32;
#pragma unroll
      for (int q = 0; q < 8; ++q){
        float4 f = *(const float4*)(xc + q*4);
        const float* a = &xi[part*32 + q*4];
        acc += a[0]*f.x + a[1]*f.y + a[2]*f.z + a[3]*f.w;
      }
    }
    acc += __shfl_xor(acc, 1, 64);
    acc += __shfl_xor(acc, 2, 64);
    if (c < n && part == 0) cv[c] = acc * ni * xninv[idx];
  }
  __syncthreads();
  for (int c = t; c < n; c += 256){
    float v = cv[c]; int id = ci[c];
    int rank = 0;
    for (int j = 0; j < n; ++j){
      float u = cv[j];
      if (u > v || (u == v && ci[j] < id)) rank++;   // top_k tie-break: lower index
    }
    if (rank < KTOP){
      tval[(size_t)i*KTOP + rank] = v;
      tidx[(size_t)i*KTOP + rank] = id;
      sel[rank] = v;
    }
  }
  __syncthreads();
  if (t == 0){
    float s = 0.f;
    for (int q = 0; q < KTOP; ++q) s += sel[q];
    deginv[i] = 1.0f / fmaxf(s, 1e-5f);
  }
}

// ---------------------------------------------------------------- generic 32x64 gemm body (B pitch = ldb), runtime K
__device__ __forceinline__ void gemm_body(const float* __restrict__ A, int lda,
    const float* __restrict__ B, int ldb, const float* __restrict__ bias,
    float* __restrict__ C, int ldc, int K, int act, int R0, int C0){
  const int t = threadIdx.x;
  const int rg = t >> 4, cg = t & 15;
  __shared__ float Alds[32][34];
  __shared__ float Blds[32][68];
  float4 acc0 = {0,0,0,0}, acc1 = {0,0,0,0};
  for (int kc = 0; kc < K; kc += 32){
    __syncthreads();
    { int r = t >> 3, k0 = (t & 7) * 4;
      float4 f = *(const float4*)(A + (size_t)(R0 + r)*lda + kc + k0);
      Alds[k0+0][r] = f.x; Alds[k0+1][r] = f.y; Alds[k0+2][r] = f.z; Alds[k0+3][r] = f.w; }
#pragma unroll
    for (int e = 0; e < 2; ++e){
      int idx = t + e*256;
      int k = idx >> 4, m4 = idx & 15;
      *(float4*)&Blds[k][m4*4] = *(const float4*)(B + (size_t)(kc + k)*ldb + C0 + m4*4);
    }
    __syncthreads();
#pragma unroll
    for (int k = 0; k < 32; ++k){
      float2 a = *(const float2*)&Alds[k][rg*2];
      float4 b = *(const float4*)&Blds[k][cg*4];
      acc0.x += a.x*b.x; acc0.y += a.x*b.y; acc0.z += a.x*b.z; acc0.w += a.x*b.w;
      acc1.x += a.y*b.x; acc1.y += a.y*b.y; acc1.z += a.y*b.z; acc1.w += a.y*b.w;
    }
  }
  const int r0 = R0 + rg*2, c0 = C0 + cg*4;
  float4 bb = {0,0,0,0};
  if (bias) bb = *(const float4*)&bias[c0];
  acc0.x += bb.x; acc0.y += bb.y; acc0.z += bb.z; acc0.w += bb.w;
  acc1.x += bb.x; acc1.y += bb.y; acc1.z += bb.z; acc1.w += bb.w;
  if (act){
    acc0.x = elu_f(acc0.x); acc0.y = elu_f(acc0.y); acc0.z = elu_f(acc0.z); acc0.w = elu_f(acc0.w);
    acc1.x = elu_f(acc1.x); acc1.y = elu_f(acc1.y); acc1.z = elu_f(acc1.z); acc1.w = elu_f(acc1.w);
  }
  *(float4*)&C[(size_t)r0*ldc + c0] = acc0;
  *(float4*)&C[(size_t)(r0+1)*ldc + c0] = acc1;
}

// ---------------------------------------------------------------- dual GEMM: T1 = x@Wg1, T2 = elu(x@Wp1 + b1); + node_norms fold
__global__ __launch_bounds__(256) void gemm_dual(const float* __restrict__ A,
    const float* __restrict__ B1, const float* __restrict__ B2,
    const float* __restrict__ bias2, float* __restrict__ C1, float* __restrict__ C2,
    const int* __restrict__ nbrcnt, const int* __restrict__ colcnt,
    float* __restrict__ d1inv, float* __restrict__ d2inv){
  const int t = threadIdx.x;
  const int R0 = blockIdx.x * 32, C0 = blockIdx.y * 64;
  if (blockIdx.y == 0 && t < 32){           // folded node_norms
    int i = R0 + t;
    d1inv[i] = rsqrtf((float)(nbrcnt[i] + 1));
    d2inv[i] = rsqrtf((float)(colcnt[i] + 1));
  }
  const int rg = t >> 4, cg = t & 15;
  __shared__ float Alds[32][34];
  __shared__ float B1lds[32][68];
  __shared__ float B2lds[32][68];
  float4 p0 = {0,0,0,0}, p1 = {0,0,0,0};
  float4 q0 = {0,0,0,0}, q1 = {0,0,0,0};
  for (int kc = 0; kc < FDIM; kc += 32){
    __syncthreads();
    { int r = t >> 3, k0 = (t & 7) * 4;
      float4 f = *(const float4*)(A + (size_t)(R0 + r)*FDIM + kc + k0);
      Alds[k0+0][r] = f.x; Alds[k0+1][r] = f.y; Alds[k0+2][r] = f.z; Alds[k0+3][r] = f.w; }
#pragma unroll
    for (int e = 0; e < 2; ++e){
      int idx = t + e*256;
      int k = idx >> 4, m4 = idx & 15;
      *(float4*)&B1lds[k][m4*4] = *(const float4*)(B1 + (size_t)(kc + k)*FDIM + C0 + m4*4);
      *(float4*)&B2lds[k][m4*4] = *(const float4*)(B2 + (size_t)(kc + k)*FDIM + C0 + m4*4);
    }
    __syncthreads();
#pragma unroll
    for (int k = 0; k < 32; ++k){
      float2 a = *(const float2*)&Alds[k][rg*2];
      float4 b = *(const float4*)&B1lds[k][cg*4];
      float4 c = *(const float4*)&B2lds[k][cg*4];
      p0.x += a.x*b.x; p0.y += a.x*b.y; p0.z += a.x*b.z; p0.w += a.x*b.w;
      p1.x += a.y*b.x; p1.y += a.y*b.y; p1.z += a.y*b.z; p1.w += a.y*b.w;
      q0.x += a.x*c.x; q0.y += a.x*c.y; q0.z += a.x*c.z; q0.w += a.x*c.w;
      q1.x += a.y*c.x; q1.y += a.y*c.y; q1.z += a.y*c.z; q1.w += a.y*c.w;
    }
  }
  const int r0 = R0 + rg*2, c0 = C0 + cg*4;
  *(float4*)&C1[(size_t)r0*FDIM + c0] = p0;
  *(float4*)&C1[(size_t)(r0+1)*FDIM + c0] = p1;
  float4 bb = *(const float4*)&bias2[c0];
  q0.x = elu_f(q0.x + bb.x); q0.y = elu_f(q0.y + bb.y); q0.z = elu_f(q0.z + bb.z); q0.w = elu_f(q0.w + bb.w);
  q1.x = elu_f(q1.x + bb.x); q1.y = elu_f(q1.y + bb.y); q1.z = elu_f(q1.z + bb.z); q1.w = elu_f(q1.w + bb.w);
  *(float4*)&C2[(size_t)r0*FDIM + c0] = q0;
  *(float4*)&C2[(size_t)(r0+1)*FDIM + c0] = q1;
}

// ---------------------------------------------------------------- fp32 GEMM  C[N x M] = act(A@B + bias)  (B pitch = M)
template<int M>
__global__ __launch_bounds__(256) void gemm_k(const float* __restrict__ A, int lda,
    const float* __restrict__ B, const float* __restrict__ bias,
    float* __restrict__ C, int ldc, int K, int act){
  gemm_body(A, lda, B, M, bias, C, ldc, K, act, blockIdx.x*32, blockIdx.y*64);
}

// ---------------------------------------------------------------- spmm_pair: gcn layer-1 (blocks 0..6143) + sage layer-1 (6144..12287)
__global__ __launch_bounds__(128) void spmm_pair(const float* __restrict__ T1,
    const int* __restrict__ nbr, const int* __restrict__ nbrcnt,
    const float* __restrict__ d1inv, const float* __restrict__ d2inv,
    float* __restrict__ z1,
    const float* __restrict__ T2, const float* __restrict__ tval,
    const int* __restrict__ tidx, const float* __restrict__ deginv,
    float* __restrict__ cat1r){
  const int b = blockIdx.x, t = threadIdx.x;
  if (b < N_NODES){
    const int i = b;
    float acc = T1[(size_t)i*FDIM + t] * d2inv[i];
    const int cnt = nbrcnt[i];
    const int* nb = nbr + (size_t)i*MAXNBR;
    for (int s = 0; s < cnt; ++s){
      int j = nb[s];
      acc += T1[(size_t)j*FDIM + t] * d2inv[j];
    }
    z1[(size_t)i*FDIM + t] = elu_f(acc * d1inv[i]);
  } else {
    const int i = b - N_NODES;
    float acc = 0.f;
    const float* vv = tval + (size_t)i*KTOP;
    const int*   ii = tidx + (size_t)i*KTOP;
    for (int s = 0; s < KTOP; ++s)
      acc += vv[s] * T2[(size_t)ii[s]*FDIM + t];
    cat1r[(size_t)i*256 + t] = acc * deginv[i];
  }
}

// ---------------------------------------------------------------- dual_stage1: [0,384) T1 = z1@Wg2 ; [384,768) cat2[:,0:128] = elu(cat1@Ws1)
__global__ __launch_bounds__(256) void dual_stage1(const float* __restrict__ z1,
    const float* __restrict__ Wg2, float* __restrict__ T1,
    const float* __restrict__ cat1, const float* __restrict__ Ws1,
    float* __restrict__ cat2){
  const int b = blockIdx.x;
  if (b < 384){
    gemm_body(z1, FDIM, Wg2, FDIM, nullptr, T1, FDIM, FDIM, 0,
              (b % 192)*32, (b / 192)*64);
  } else {
    const int bb = b - 384;
    gemm_body(cat1, 256, Ws1, FDIM, nullptr, cat2, 256, 256, 1,
              (bb % 192)*32, (bb / 192)*64);
  }
}

// ---------------------------------------------------------------- dual_stage2: [0,3072) GCN-L2 spmm (2 rows/block) ; [3072,3456) T2 = elu(cat2@Wp2+b2)
__global__ __launch_bounds__(256) void dual_stage2(const float* __restrict__ T1,
    const int* __restrict__ nbr, const int* __restrict__ nbrcnt,
    const float* __restrict__ d1inv, const float* __restrict__ d2inv,
    float* __restrict__ hcat,
    const float* __restrict__ cat2, const float* __restrict__ Wp2,
    const float* __restrict__ b2, float* __restrict__ T2){
  const int b = blockIdx.x, t = threadIdx.x;
  if (b < 3072){
    const int i = b*2 + (t >> 7);
    const int tl = t & 127;
    float acc = T1[(size_t)i*FDIM + tl] * d2inv[i];
    const int cnt = nbrcnt[i];
    const int* nb = nbr + (size_t)i*MAXNBR;
    for (int s = 0; s < cnt; ++s){
      int j = nb[s];
      acc += T1[(size_t)j*FDIM + tl] * d2inv[j];
    }
    hcat[(size_t)i*256 + tl] = elu_f(acc * d1inv[i]);
  } else {
    const int bb = b - 3072;
    gemm_body(cat2, 256, Wp2, FDIM, b2, T2, FDIM, FDIM, 1,
              (bb % 192)*32, (bb / 192)*64);
  }
}

// ---------------------------------------------------------------- SAGE SpMM
__global__ __launch_bounds__(128) void spmm_sage(const float* __restrict__ P,
    const float* __restrict__ tval, const int* __restrict__ tidx,
    const float* __restrict__ deginv, float* __restrict__ C, int ldc){
  const int i = blockIdx.x, t = threadIdx.x;
  float acc = 0.f;
  const float* vv = tval + (size_t)i*KTOP;
  const int*   ii = tidx + (size_t)i*KTOP;
  for (int s = 0; s < KTOP; ++s)
    acc += vv[s] * P[(size_t)ii[s]*FDIM + t];
  C[(size_t)i*ldc + t] = acc * deginv[i];
}

// ---------------------------------------------------------------- edges: logits + per-block partial BCE (no global atomics)
__global__ __launch_bounds__(256) void edge_loss(const int* __restrict__ src,
    const int* __restrict__ dst, const float* __restrict__ labels,
    const float* __restrict__ HP, const float* __restrict__ hcat,
    const float* __restrict__ predB, float* __restrict__ out,
    float* __restrict__ partial){
  const int t = threadIdx.x;
  const int e = blockIdx.x*4 + (t >> 6);
  const int lane = t & 63;
  const int s = src[e], d = dst[e];
  const float* hp = HP   + (size_t)s*256;
  const float* hc = hcat + (size_t)d*256;
  float acc = 0.f;
  for (int k = lane; k < 256; k += 64) acc += hp[k] * hc[k];
  for (int o = 32; o > 0; o >>= 1) acc += __shfl_down(acc, o, 64);
  __shared__ float terms[4];
  if (lane == 0){
    float l = acc + predB[0];
    out[1 + e] = l;
    float y = labels[e];
    terms[t >> 6] = fmaxf(l, 0.f) - l*y + log1pf(expf(-fabsf(l)));
  }
  __syncthreads();
  if (t == 0) partial[blockIdx.x] = terms[0] + terms[1] + terms[2] + terms[3];
}

__global__ __launch_bounds__(256) void reduce_loss(const float* __restrict__ partial,
    float* __restrict__ out){
  const int t = threadIdx.x, lane = t & 63, w = t >> 6;
  float s = 0.f;
  for (int i = t; i < EEDGES/4; i += 256) s += partial[i];
  for (int o = 32; o > 0; o >>= 1) s += __shfl_down(s, o, 64);
  __shared__ float ws[4];
  if (lane == 0) ws[w] = s;
  __syncthreads();
  if (t == 0) out[0] = (ws[0] + ws[1] + ws[2] + ws[3]) * (1.0f / EEDGES);
}

// ---------------------------------------------------------------- launcher
extern "C" void kernel_launch(void* const* d_in, const int* in_sizes, int n_in,
                              void* d_out, int out_size, void* d_ws, size_t ws_size,
                              hipStream_t stream){
  (void)in_sizes; (void)n_in; (void)out_size; (void)ws_size;
  const int*   src    = (const int*)d_in[0];
  const int*   dst    = (const int*)d_in[1];
  const float* labels = (const float*)d_in[2];
  const float* adj    = (const float*)d_in[3];
  const float* x      = (const float*)d_in[4];
  const float* Wg1    = (const float*)d_in[5];
  const float* Wg2    = (const float*)d_in[6];
  const float* Wp1    = (const float*)d_in[7];
  const float* b1     = (const float*)d_in[8];
  const float* Ws1    = (const float*)d_in[9];
  const float* Wp2    = (const float*)d_in[10];
  const float* b2     = (const float*)d_in[11];
  const float* Ws2    = (const float*)d_in[12];
  const float* PredW  = (const float*)d_in[13];
  const float* PredB  = (const float*)d_in[14];

  char* ws = (char*)d_ws;
  size_t off = 0;
  auto alloc = [&](size_t bytes)->void*{
    void* p = ws + off; off += (bytes + 255) & ~(size_t)255; return p; };

  // total ws footprint ~109 MB (ws_size = 576 MiB)
  int*   colcnt = (int*)  alloc((size_t)N_NODES*4);
  int*   nbrcnt = (int*)  alloc((size_t)N_NODES*4);
  int*   nbr    = (int*)  alloc((size_t)N_NODES*MAXNBR*4);
  float* d1inv  = (float*)alloc((size_t)N_NODES*4);
  float* d2inv  = (float*)alloc((size_t)N_NODES*4);
  float* xninv  = (float*)alloc((size_t)N_NODES*4);
  unsigned short* xbf = (unsigned short*)alloc((size_t)N_NODES*FDIM*2);
  float* tval   = (float*)alloc((size_t)N_NODES*KTOP*4);
  int*   tidx   = (int*)  alloc((size_t)N_NODES*KTOP*4);
  float* dginv  = (float*)alloc((size_t)N_NODES*4);
  float* gmax   = (float*)alloc((size_t)N_NODES*NTILES*4);
  float* partial= (float*)alloc((size_t)(EEDGES/4)*4);
  float* T1     = (float*)alloc((size_t)N_NODES*FDIM*4);
  float* T2     = (float*)alloc((size_t)N_NODES*FDIM*4);
  float* z1     = (float*)alloc((size_t)N_NODES*FDIM*4);
  float* cat1   = (float*)alloc((size_t)N_NODES*256*4);
  float* cat2   = (float*)alloc((size_t)N_NODES*256*4);
  float* hcat   = (float*)alloc((size_t)N_NODES*256*4);
  unsigned short* sim = (unsigned short*)alloc((size_t)N_NODES*N_NODES*2);
  float* out    = (float*)d_out;

  hipMemsetAsync(colcnt, 0, (size_t)N_NODES*4, stream);

  prep       <<<N_NODES + N_NODES/2, 256, 0, stream>>>(adj, x, nbr, nbrcnt, colcnt, xbf, xninv, cat1);
  simgemm    <<<dim3(N_NODES/64, GRIDY), 256, 0, stream>>>(xbf, xninv, sim, gmax);
  refine_scan<<<N_NODES, 256, 0, stream>>>(x, xninv, sim, gmax, tval, tidx, dginv);

  // T1 = x@Wg1, T2 = elu(x@Wp1+b1); node_norms folded
  gemm_dual  <<<dim3(N_NODES/32, 2), 256, 0, stream>>>(x, Wg1, Wp1, b1, T1, T2,
                                                       nbrcnt, colcnt, d1inv, d2inv);
  // GCN layer-1 spmm + SAGE layer-1 spmm
  spmm_pair  <<<2*N_NODES, 128, 0, stream>>>(T1, nbr, nbrcnt, d1inv, d2inv, z1,
                                             T2, tval, tidx, dginv, cat1 + 128);
  // T1 = z1@Wg2  ||  cat2[:,0:128] = elu(cat1@Ws1)
  dual_stage1<<<768, 256, 0, stream>>>(z1, Wg2, T1, cat1, Ws1, cat2);
  // hcat[:,0:128] = GCN-L2 spmm(T1)  ||  T2 = elu(cat2@Wp2+b2)
  dual_stage2<<<3072 + 384, 256, 0, stream>>>(T1, nbr, nbrcnt, d1inv, d2inv, hcat,
                                              cat2, Wp2, b2, T2);
  // SAGE layer-2 spmm + combine
  spmm_sage  <<<N_NODES, 128, 0, stream>>>(T2, tval, tidx, dginv, cat2 + 128, 256);
  gemm_k<128><<<dim3(N_NODES/32, 2), 256, 0, stream>>>(cat2, 256, Ws2, nullptr, hcat + 128, 256, 256, 1);

  // predictor
  gemm_k<256><<<dim3(N_NODES/32, 4), 256, 0, stream>>>(hcat, 256, PredW, nullptr, cat1, 256, 256, 0);
  edge_loss  <<<EEDGES/4, 256, 0, stream>>>(src, dst, labels, cat1, hcat, PredB, out, partial);
  reduce_loss<<<1, 256, 0, stream>>>(partial, out);
}